// Round 6
// baseline (1099.082 us; speedup 1.0000x reference)
//
#include <hip/hip_runtime.h>
#include <hip/hip_bf16.h>

using bf16 = __hip_bfloat16;
typedef __attribute__((ext_vector_type(8))) short short8;
typedef __attribute__((ext_vector_type(4))) float float4v;
typedef __attribute__((ext_vector_type(16))) float f32x16;
typedef __attribute__((ext_vector_type(4))) unsigned uint4v;

__device__ __forceinline__ float b2f(bf16 x){ return __bfloat162float(x); }
__device__ __forceinline__ bf16  f2b(float x){ return __float2bfloat16(x); }
__device__ __forceinline__ bf16  tob(float x){ return f2b(x); }
__device__ __forceinline__ bf16  tob(bf16 x){ return x; }
__device__ __forceinline__ float frcp(float x){ return __builtin_amdgcn_rcpf(x); }
__device__ __forceinline__ float bs2f(short s){
  unsigned u = ((unsigned)(unsigned short)s) << 16;
  return __builtin_bit_cast(float, u);
}
__device__ __forceinline__ unsigned cvt_pk_bf16(float lo, float hi){
  unsigned r; asm("v_cvt_pk_bf16_f32 %0, %1, %2" : "=v"(r) : "v"(lo), "v"(hi)); return r;
}
__device__ __forceinline__ void plswap(unsigned &a, unsigned &b){
  asm("v_permlane32_swap_b32 %0, %1" : "+v"(a), "+v"(b));
}

#define EPSV 1e-5f
#define Z16 {0.f,0.f,0.f,0.f,0.f,0.f,0.f,0.f,0.f,0.f,0.f,0.f,0.f,0.f,0.f,0.f}

// ------------------------------------------------------------------
// pos prep: posf[r] = {x,y,z,|p|^2} fp32
// ------------------------------------------------------------------
__global__ __launch_bounds__(256) void pos_kernel(const float* __restrict__ pos,
                                                  float* __restrict__ posf, int rows){
  int r = blockIdx.x*256 + threadIdx.x;
  if (r >= rows) return;
  float x = pos[3*r], y = pos[3*r+1], z = pos[3*r+2];
  posf[4*r] = x; posf[4*r+1] = y; posf[4*r+2] = z; posf[4*r+3] = x*x + y*y + z*z;
}

// ------------------------------------------------------------------
// all 10 weight transposes (fp32 -> bf16) in ONE launch.
// ------------------------------------------------------------------
struct WTDesc { const float* src; bf16* dst; int rows, cols; };
struct WTPack { WTDesc d[10]; };

__global__ __launch_bounds__(256) void wtrans_kernel(WTPack p){
  WTDesc w = p.d[blockIdx.z];
  long r0 = (long)blockIdx.y*32, c0 = (long)blockIdx.x*32;
  if (r0 >= w.rows || c0 >= w.cols) return;
  __shared__ bf16 tile[32][33];
  int tx = threadIdx.x & 31, ty = threadIdx.x >> 5;
#pragma unroll
  for (int i = ty; i < 32; i += 8) tile[i][tx] = f2b(w.src[(r0+i)*w.cols + c0 + tx]);
  __syncthreads();
#pragma unroll
  for (int i = ty; i < 32; i += 8) w.dst[(c0+i)*w.rows + r0 + tx] = tile[tx][i];
}

// ------------------------------------------------------------------
// batched 32x32-tiled transpose (+ cast to bf16)
// ------------------------------------------------------------------
template<typename TI>
__global__ __launch_bounds__(256) void transpose_kernel(
    const TI* __restrict__ in, long ldin, long is1, long is2,
    bf16* __restrict__ out, long ldout, long os1, long os2, int Z2)
{
  int z = blockIdx.z, z1 = z / Z2, z2 = z - z1*Z2;
  in  += (long)z1*is1 + (long)z2*is2;
  out += (long)z1*os1 + (long)z2*os2;
  __shared__ bf16 tile[32][33];
  int tx = threadIdx.x & 31, ty = threadIdx.x >> 5;
  long r0 = (long)blockIdx.y*32, c0 = (long)blockIdx.x*32;
#pragma unroll
  for (int i = ty; i < 32; i += 8) tile[i][tx] = tob(in[(r0+i)*ldin + c0 + tx]);
  __syncthreads();
#pragma unroll
  for (int i = ty; i < 32; i += 8) out[(c0+i)*ldout + r0 + tx] = tile[tx][i];
}

// ------------------------------------------------------------------
// bias concat for fused QKV (+ zero the kmax accumulator)
// ------------------------------------------------------------------
__global__ __launch_bounds__(256) void bcat_kernel(const float* __restrict__ bq,
                                                   const float* __restrict__ bk,
                                                   const float* __restrict__ bv,
                                                   float* __restrict__ bqkv,
                                                   float* __restrict__ kmax){
  int j = blockIdx.x*256 + threadIdx.x;
  if (blockIdx.x == 0 && threadIdx.x < 16) kmax[threadIdx.x] = 0.f;
  if (j >= 768) return;
  bqkv[j] = (j < 256) ? bq[j] : (j < 512) ? bk[j-256] : bv[j-512];
}

// ------------------------------------------------------------------
// LayerNorm over S=256 per row (fp32 in -> bf16 out)
// ------------------------------------------------------------------
__global__ __launch_bounds__(256) void ln_kernel(const float* __restrict__ x,
                                                 const float* __restrict__ g,
                                                 const float* __restrict__ be,
                                                 bf16* __restrict__ out){
  const long row = blockIdx.x;
  const int t = threadIdx.x;
  __shared__ float r1[256], r2[256];
  float v = x[(row<<8) + t];
  r1[t] = v; r2[t] = v*v; __syncthreads();
  for (int s=128;s>0;s>>=1){
    if (t<s){ r1[t] += r1[t+s]; r2[t] += r2[t+s]; }
    __syncthreads();
  }
  const float mu = r1[0] * (1.f/256.f);
  const float var = r2[0] * (1.f/256.f) - mu*mu;
  const float rstd = rsqrtf(fmaxf(var, 0.f) + EPSV);
  out[(row<<8)+t] = f2b((v-mu)*rstd*g[t] + be[t]);
}

// ------------------------------------------------------------------
// eq-norm 1: v (b,n,c,x) fp32 -> vnX[(b,n,x), c] bf16
// ------------------------------------------------------------------
__global__ __launch_bounds__(192) void vnorm1_kernel(const float* __restrict__ vin,
                                                     const float* __restrict__ vs1,
                                                     bf16* __restrict__ vnX){
  const long row = blockIdx.x;
  const int t = threadIdx.x;
  __shared__ float vv[192], nrm[64];
  __shared__ float smean;
  vv[t] = vin[row*192 + t];
  __syncthreads();
  if (t < 64){
    float a = vv[3*t], b = vv[3*t+1], c = vv[3*t+2];
    nrm[t] = sqrtf(a*a + b*b + c*c);
  }
  __syncthreads();
  if (t == 0){ float s = 0.f; for (int i=0;i<64;i++) s += nrm[i]; smean = s*(1.f/64.f); }
  __syncthreads();
  const int c = t/3, x = t - 3*c;
  const float val = vv[t] / (nrm[c] + EPSV) * smean * vs1[c];
  vnX[row*192 + x*64 + c] = f2b(val);
}

// ------------------------------------------------------------------
// eq-norm 2: v2X[(b,n), x*64+c] fp32 -> vn2X same layout bf16
// ------------------------------------------------------------------
__global__ __launch_bounds__(192) void vnorm2_kernel(const float* __restrict__ v2X,
                                                     const float* __restrict__ vs2,
                                                     bf16* __restrict__ vn2X){
  const long row = blockIdx.x;
  const int t = threadIdx.x;
  __shared__ float vv[192], nrm[64];
  __shared__ float smean;
  vv[t] = v2X[row*192 + t];
  __syncthreads();
  if (t < 64){
    float a = vv[t], b = vv[t+64], c = vv[t+128];
    nrm[t] = sqrtf(a*a + b*b + c*c);
  }
  __syncthreads();
  if (t == 0){ float s = 0.f; for (int i=0;i<64;i++) s += nrm[i]; smean = s*(1.f/64.f); }
  __syncthreads();
  const int c = t & 63;
  vn2X[row*192 + t] = f2b(vv[t] / (nrm[c] + EPSV) * smean * vs2[c]);
}

// ------------------------------------------------------------------
// per-(b,h) max ||k||^2 via atomicMax (uint order == float order for >=0).
// grid (16 bh, 8 chunks of 256 rows); bcat_kernel zeroes kmax first.
// ------------------------------------------------------------------
__global__ __launch_bounds__(256) void knorm_kernel(const bf16* __restrict__ qkv,
                                                    float* __restrict__ kmax){
  const int bh = blockIdx.x, b = bh>>2, h = bh&3;
  const int t = threadIdx.x;
  __shared__ float red[256];
  long row = (long)b*2048 + (long)blockIdx.y*256 + t;
  const short8* kp = (const short8*)(qkv + row*768 + 256 + h*64);
  float ss = 0.f;
#pragma unroll
  for (int c=0;c<8;c++){
    short8 v = kp[c];
#pragma unroll
    for (int j=0;j<8;j++){ float f = bs2f(v[j]); ss = fmaf(f,f,ss); }
  }
  red[t] = ss; __syncthreads();
  for (int s=128;s>0;s>>=1){ if (t<s) red[t] = fmaxf(red[t], red[t+s]); __syncthreads(); }
  if (t==0) atomicMax((unsigned*)&kmax[bh], __float_as_uint(red[0]));
}

// ------------------------------------------------------------------
// FUSED ATTENTION, 512 blocks x 256 thr (2 q-waves x 2 m-groups):
//   block = (qb 0..31, bh): 64 q rows. Group g handles m-tiles g,g+2,...
//   single-buffered LDS stage (25088 B per group) -> 51200 B/block ->
//   3 blocks/CU = 12 waves/CU = 3 waves/SIMD (TLP replaces dbuf).
//   Combine O/VM/l across groups via LDS (odd strides 33/49).
//   NOTE: 768-thr 3-group variant spills (round 4); 256-block grids cap
//   at 1 block/CU (rounds 2-5). This shape is the occupancy sweet spot.
// ------------------------------------------------------------------
#define ATT_K_OFF   0
#define ATT_V_OFF   4096
#define ATT_X_OFF   9216
#define ATT_P_OFF   24576
#define ATT_TILE    25088
#define ATT_LACC    50176          // 4*64 floats = 1024 B
#define ATT_SMEM    51200

__global__ __launch_bounds__(256, 3) void attn_kernel(
    const bf16* __restrict__ qkv,    // [8192][768] (Q|K|V, 4 heads x 64)
    const bf16* __restrict__ vsT,    // [b][h][64][2048]
    const bf16* __restrict__ vmixT,  // [b][192][2048]
    const float* __restrict__ posf,  // [b][2048][4]
    const float* __restrict__ kmaxA, // [16] max ||k||^2
    const float* __restrict__ w_dist, const float* __restrict__ b_dist,
    bf16* __restrict__ sA,           // [8192][256]
    bf16* __restrict__ slab)         // [4][8192][192]
{
  __shared__ __align__(16) char smem[ATT_SMEM];
  const int qb = blockIdx.x;         // 0..31 (64 q rows each)
  const int bh = blockIdx.y;         // 0..15
  const int b  = bh >> 2, h = bh & 3;
  const int tid = threadIdx.x;
  const int w = tid >> 6, lane = tid & 63;
  const int g = w >> 1, qw = w & 1;
  const int lq = lane & 31, hi = lane >> 5;
  const int gt = tid & 127;          // thread id within group (2 waves)

  const int qloc = qb*64 + qw*32 + lq;
  const long rowQ = (long)b*2048 + qloc;

  // Q fragments (B operand): col=q (lane&31), k=d = kc*16 + hi*8 + j
  short8 qf[4];
  {
    const bf16* qp = qkv + rowQ*768 + h*64 + hi*8;
#pragma unroll
    for (int kc=0;kc<4;kc++) qf[kc] = *(const short8*)(qp + kc*16);
  }
  // stabilizer: sqrt(|q|^2 * max|k|^2) / 8  (>= max_m qk/8)
  float q2 = 0.f;
#pragma unroll
  for (int kc=0;kc<4;kc++)
#pragma unroll
    for (int j=0;j<8;j++){ float qv = bs2f(qf[kc][j]); q2 = fmaf(qv,qv,q2); }
  q2 += __shfl_xor(q2, 32);
  const float mxs = sqrtf(q2 * kmaxA[bh]) * 0.125f;
  const float wh = w_dist[h], bhd = b_dist[h];
  const float4v pn = *(const float4v*)(posf + (long)b*8192 + (long)qloc*4);
  const float m2x = -2.f*pn[0], m2y = -2.f*pn[1], m2z = -2.f*pn[2], pnw = pn[3];

  f32x16 O[2]  = {Z16, Z16};
  f32x16 VM[6] = {Z16, Z16, Z16, Z16, Z16, Z16};
  float lacc = 0.f;

  // per-group staging: 128 threads, 20.5 KB/tile
  short8 stK[2], stV[2], stX[6]; float4v stP;
  const bf16* Kg = qkv + (long)b*2048*768 + 256 + h*64;
  const bf16* Vg = vsT + (long)b*524288 + (long)h*131072;
  const bf16* Xg = vmixT + (long)b*393216;
  const float* Pg = posf + (long)b*8192;
  char* gbase = smem + g*ATT_TILE;

  auto LOADT = [&](int m0){
#pragma unroll
    for (int c=0;c<2;c++)
      stK[c] = *(const short8*)(Kg + (long)(m0 + (gt>>3) + 16*c)*768 + (gt&7)*8);
#pragma unroll
    for (int c=0;c<2;c++)
      stV[c] = *(const short8*)(Vg + (long)((gt>>2) + 32*c)*2048 + m0 + (gt&3)*8);
#pragma unroll
    for (int c=0;c<6;c++)
      stX[c] = *(const short8*)(Xg + (long)((gt>>2) + 32*c)*2048 + m0 + (gt&3)*8);
    if (gt < 32) stP = *(const float4v*)(Pg + (long)(m0+gt)*4);
  };
  auto WRITET = [&](char* buf){
#pragma unroll
    for (int c=0;c<2;c++){
      const int r = (gt>>3) + 16*c;
      *(short8*)(buf + ATT_K_OFF + r*128 + (((gt&7) ^ (r&7))<<4)) = stK[c];  // XOR-swizzle
    }
#pragma unroll
    for (int c=0;c<2;c++)
      *(short8*)(buf + ATT_V_OFF + ((gt>>2)+32*c)*80 + (gt&3)*16) = stV[c];
#pragma unroll
    for (int c=0;c<6;c++)
      *(short8*)(buf + ATT_X_OFF + ((gt>>2)+32*c)*80 + (gt&3)*16) = stX[c];
    if (gt < 32) *(float4v*)(buf + ATT_P_OFF + gt*16) = stP;
  };

  auto COMPUTE = [&](const char* buf){
    const char* Kb = buf + ATT_K_OFF;
    const char* Vb = buf + ATT_V_OFF;
    const char* Xb = buf + ATT_X_OFF;
    const float4v* pmb = (const float4v*)(buf + ATT_P_OFF);
    // swapped QK^T: S[m][q], col = lane&31 = q
    f32x16 S = Z16;
#pragma unroll
    for (int kc=0;kc<4;kc++){
      short8 kf = *(const short8*)(Kb + lq*128 + (((kc*2+hi) ^ (lq&7))<<4));
      S = __builtin_amdgcn_mfma_f32_32x32x16_bf16(kf, qf[kc], S, 0, 0, 0);
    }
    // dist bias + exp (unnormalized, fixed stabilizer); m = i + 8gg + 4hi
    float P[16];
#pragma unroll
    for (int gg=0; gg<4; gg++){
#pragma unroll
      for (int i=0;i<4;i++){
        float4v pm = pmb[gg*8 + hi*4 + i];
        float d2 = fmaf(m2x, pm[0], fmaf(m2y, pm[1], fmaf(m2z, pm[2], pnw + pm[3])));
        float dist = sqrtf(fmaxf(d2, 1e-12f));
        float sig = frcp(1.f + __expf(fmaf(dist, wh, bhd)));
        float p = __expf(fmaf(S[gg*4+i], 0.125f, -mxs)) * sig;
        lacc += p;
        P[gg*4+i] = p;
      }
    }
    // P -> bf16 B-operand (col=q, k=m) via cvt_pk + permlane32_swap
    unsigned pk[8];
#pragma unroll
    for (int t=0;t<8;t++) pk[t] = cvt_pk_bf16(P[2*t], P[2*t+1]);
    plswap(pk[0], pk[2]); plswap(pk[1], pk[3]);   // chunk0: m 0..15
    plswap(pk[4], pk[6]); plswap(pk[5], pk[7]);   // chunk1: m 16..31
    uint4v y0v = {pk[0], pk[1], pk[2], pk[3]};
    uint4v y1v = {pk[4], pk[5], pk[6], pk[7]};
    short8 Y0 = __builtin_bit_cast(short8, y0v);
    short8 Y1 = __builtin_bit_cast(short8, y1v);
    // PV: O^T[d][q] += V^T[d][m] * P[q][m]
#pragma unroll
    for (int dblk=0; dblk<2; dblk++){
      short8 v0 = *(const short8*)(Vb + (dblk*32+lq)*80 + hi*16);
      short8 v1 = *(const short8*)(Vb + (dblk*32+lq)*80 + 32 + hi*16);
      O[dblk] = __builtin_amdgcn_mfma_f32_32x32x16_bf16(v0, Y0, O[dblk], 0,0,0);
      O[dblk] = __builtin_amdgcn_mfma_f32_32x32x16_bf16(v1, Y1, O[dblk], 0,0,0);
    }
    // vmix: VM^T[e][q] += vmix^T[e][m] * P[q][m]
#pragma unroll
    for (int eblk=0; eblk<6; eblk++){
      short8 x0 = *(const short8*)(Xb + (eblk*32+lq)*80 + hi*16);
      short8 x1 = *(const short8*)(Xb + (eblk*32+lq)*80 + 32 + hi*16);
      VM[eblk] = __builtin_amdgcn_mfma_f32_32x32x16_bf16(x0, Y0, VM[eblk], 0,0,0);
      VM[eblk] = __builtin_amdgcn_mfma_f32_32x32x16_bf16(x1, Y1, VM[eblk], 0,0,0);
    }
  };

  // group g computes tiles g, g+2, ..., g+62 (32 tiles each), single-buffered
  LOADT(g*32);
  WRITET(gbase);
  __syncthreads();
#pragma unroll 1
  for (int i=0; i<32; ++i){
    if (i < 31) LOADT((2*(i+1)+g)*32);   // global->reg overlapped with compute
    COMPUTE(gbase);
    __syncthreads();                     // all reads of buf done
    if (i < 31){
      WRITET(gbase);
      __syncthreads();                   // buf ready for next tile
    }
  }

  // ---------------- cross-group combine (odd strides: conflict-free) ----------------
  float* laccT = (float*)(smem + ATT_LACC);
  laccT[w*64 + lane] = lacc;
  if (g == 1){                       // group 1 exports O (stride 33 floats)
    float* Od = (float*)smem + (qw*64+lane)*33;
#pragma unroll
    for (int r=0;r<16;r++){ Od[r] = O[0][r]; Od[16+r] = O[1][r]; }
  }
  __syncthreads();
  const float lsum = laccT[qw*64+lq] + laccT[qw*64+32+lq]
                   + laccT[(2+qw)*64+lq] + laccT[(2+qw)*64+32+lq];
  if (g == 0){                       // group 0 accumulates full O
    const float* Od = (const float*)smem + (qw*64+lane)*33;
#pragma unroll
    for (int r=0;r<16;r++){ O[0][r] += Od[r]; O[1][r] += Od[16+r]; }
  }
  __syncthreads();
  // VM in two halves (stride 49 floats; 128*49*4 = 25088 B fits group-0 area)
#pragma unroll
  for (int hf=0; hf<2; hf++){
    if (g == 0){                     // group 0 exports VM half
      float* Vd = (float*)smem + (qw*64+lane)*49;
#pragma unroll
      for (int e=0;e<3;e++)
#pragma unroll
        for (int r=0;r<16;r++) Vd[e*16+r] = VM[hf*3+e][r];
    }
    __syncthreads();
    if (g == 1){                     // group 1 accumulates full VM
      const float* Vd = (const float*)smem + (qw*64+lane)*49;
#pragma unroll
      for (int e=0;e<3;e++)
#pragma unroll
        for (int r=0;r<16;r++) VM[hf*3+e][r] += Vd[e*16+r];
    }
    __syncthreads();
  }

  // ---------------- parallel epilogue ----------------
  // O-scr: [0, 8704) (2 x 4352); VM-scr: [8704, 33792) (2 x 12544)
  const float sinv = frcp(lsum);
  if (g == 0){
    char* scr = smem + qw*4352;
#pragma unroll
    for (int dblk=0; dblk<2; dblk++)
#pragma unroll
      for (int pp=0; pp<8; pp++){
        const int r = 2*pp;
        const int d = dblk*32 + (r&3) + 8*(r>>2) + 4*hi;
        unsigned u = cvt_pk_bf16(O[dblk][r]*sinv, O[dblk][r+1]*sinv);
        *(unsigned*)(scr + lq*136 + d*2) = u;
      }
  } else {
    const float vinv = 0.25f * sinv;
    char* scr = smem + 8704 + qw*12544;
#pragma unroll
    for (int eblk=0; eblk<6; eblk++)
#pragma unroll
      for (int pp=0; pp<8; pp++){
        const int r = 2*pp;
        const int e = eblk*32 + (r&3) + 8*(r>>2) + 4*hi;
        unsigned u = cvt_pk_bf16(VM[eblk][r]*vinv, VM[eblk][r+1]*vinv);
        *(unsigned*)(scr + lq*392 + e*2) = u;
      }
  }
  __syncthreads();
  if (g == 0){
    const char* scr = smem + qw*4352;
    const int q = lane >> 1, half = lane & 1;
    const char* src = scr + q*136 + half*64;
    char* dst = (char*)(sA + (long)(b*2048 + qb*64 + qw*32 + q)*256 + h*64 + half*32);
#pragma unroll
    for (int i=0;i<8;i++)
      *(unsigned long long*)(dst + i*8) = *(const unsigned long long*)(src + i*8);
  } else {
    const char* scr = smem + 8704 + qw*12544;
    const int q = lane >> 1, half = lane & 1;
    const char* src = scr + q*392 + half*192;
    char* dst = (char*)(slab + (long)h*1572864
                        + (long)(b*2048 + qb*64 + qw*32 + q)*192 + half*96);
#pragma unroll
    for (int i=0;i<24;i++)
      *(unsigned long long*)(dst + i*8) = *(const unsigned long long*)(src + i*8);
  }
}

// ------------------------------------------------------------------
// reduce 4 per-head slabs (already scaled by 1/(4 l_h)) -> tvXb bf16
// ------------------------------------------------------------------
__global__ __launch_bounds__(256) void hred_kernel(const bf16* __restrict__ slab,
                                                   bf16* __restrict__ out){
  long i = (long)blockIdx.x*256 + threadIdx.x;   // over 196608 short8s
  if (i >= 196608) return;
  const short8* s0 = (const short8*)slab + i;
  short8 a = s0[0], b = s0[196608], c = s0[2*196608], d = s0[3*196608];
  short8 o;
#pragma unroll
  for (int j=0;j<8;j++){
    float f = bs2f(a[j]) + bs2f(b[j]) + bs2f(c[j]) + bs2f(d[j]);
    bf16 hv = f2b(f); o[j] = *(short*)&hv;
  }
  ((short8*)out)[i] = o;
}

// ------------------------------------------------------------------
// MFMA GEMM. SWZ=1: XCD-ownership swizzle (requires gridDim.y % 8 == 0).
// ------------------------------------------------------------------
template<int MT, int NT, int ACT, int OUTM, int RXIL, int CXIL, int SWZ>
__global__ __launch_bounds__(64) void gemm_kernel(
    const bf16* __restrict__ A, long lda, long As1, long As2,
    const bf16* __restrict__ BT, long ldb, long Bs1, long Bs2,
    const float* __restrict__ bias,
    const float* __restrict__ resid, long ldr, long Rs1, long Rs2,
    void* __restrict__ Cv, long ldc, long Cs1, long Cs2,
    int K, int Z2, int KS)
{
  int z = blockIdx.z;
  int zz = z / KS, ks = z - zz*KS;
  int z1 = zz / Z2, z2 = zz - z1*Z2;
  A  += (long)z1*As1 + (long)z2*As2 + (long)ks*K;
  BT += (long)z1*Bs1 + (long)z2*Bs2 + (long)ks*K;
  if (resid) resid += (long)z1*Rs1 + (long)z2*Rs2;
  const long cbase = (long)z1*Cs1 + (long)z2*Cs2;

  int bx = blockIdx.x, by = blockIdx.y;
  if (SWZ){
    const int nx = gridDim.x, ny = gridDim.y;
    long lin = (long)by*nx + bx;
    const int xcd = (int)(lin & 7);
    long idx = lin >> 3;
    const int rpx = ny >> 3;
    by = xcd*rpx + (int)(idx / nx);
    bx = (int)(idx % nx);
  }

  const int lane = threadIdx.x;
  const int col = lane & 15, quad = lane >> 4;
  const long rowA0 = (long)by*(16*MT);
  const long colB0 = (long)bx*(16*NT);

  float4v acc[MT][NT];
#pragma unroll
  for (int m=0;m<MT;m++)
#pragma unroll
    for (int n=0;n<NT;n++) acc[m][n] = (float4v){0.f,0.f,0.f,0.f};

  const bf16* ap[MT];
  const bf16* bp[NT];
#pragma unroll
  for (int m=0;m<MT;m++) ap[m] = A + (rowA0 + m*16 + col)*lda + quad*8;
#pragma unroll
  for (int n=0;n<NT;n++) bp[n] = BT + (colB0 + n*16 + col)*ldb + quad*8;

  for (int k0 = 0; k0 < K; k0 += 32){
    short8 a[MT], bb[NT];
#pragma unroll
    for (int m=0;m<MT;m++){ a[m] = *(const short8*)ap[m]; ap[m] += 32; }
#pragma unroll
    for (int n=0;n<NT;n++){ bb[n] = *(const short8*)bp[n]; bp[n] += 32; }
#pragma unroll
    for (int m=0;m<MT;m++)
#pragma unroll
      for (int n=0;n<NT;n++)
        acc[m][n] = __builtin_amdgcn_mfma_f32_16x16x32_bf16(a[m], bb[n], acc[m][n], 0, 0, 0);
  }

#pragma unroll
  for (int m=0;m<MT;m++){
    const long ri = rowA0 + m*16 + quad*4;
#pragma unroll
    for (int n=0;n<NT;n++){
      const long cj = colB0 + n*16 + col;
      const float bbias = bias ? bias[cj] : 0.f;
#pragma unroll
      for (int r=0;r<4;r++){
        const long ci = ri + r;
        float val = acc[m][n][r] + bbias;
        if (ACT == 1) val = 0.5f*val*(1.f + erff(val*0.70710678118654752f));
        if (resid){
          const long raddr = RXIL ? ((ci/3)*192 + cj*3 + (ci%3)) : (ci*ldr + cj);
          val += resid[raddr];
        }
        const long caddr = CXIL ? (cbase + (ci/3)*192 + cj*3 + (ci%3))
                                : (cbase + ci*ldc + cj);
        if (OUTM == 0)      ((bf16*)Cv)[caddr] = f2b(val);
        else if (OUTM == 1) ((float*)Cv)[caddr] = val;
        else                unsafeAtomicAdd(&((float*)Cv)[caddr], val);
      }
    }
  }
}

// ------------------------------------------------------------------
extern "C" void kernel_launch(void* const* d_in, const int* in_sizes, int n_in,
                              void* d_out, int out_size, void* d_ws, size_t ws_size,
                              hipStream_t stream)
{
  const float* s    = (const float*)d_in[0];
  const float* v    = (const float*)d_in[1];
  const float* pos  = (const float*)d_in[2];
  const float* Wq   = (const float*)d_in[3];
  const float* bq   = (const float*)d_in[4];
  const float* Wk   = (const float*)d_in[5];
  const float* bk   = (const float*)d_in[6];
  const float* Wv   = (const float*)d_in[7];
  const float* bv   = (const float*)d_in[8];
  const float* Wo   = (const float*)d_in[9];
  const float* bo   = (const float*)d_in[10];
  const float* w_d  = (const float*)d_in[11];
  const float* b_d  = (const float*)d_in[12];
  const float* Wvv  = (const float*)d_in[13];
  const float* Wvo  = (const float*)d_in[14];
  const float* g1   = (const float*)d_in[15];
  const float* be1  = (const float*)d_in[16];
  const float* vs1  = (const float*)d_in[17];
  const float* g2   = (const float*)d_in[18];
  const float* be2  = (const float*)d_in[19];
  const float* vs2  = (const float*)d_in[20];
  const float* Wf1  = (const float*)d_in[21];
  const float* bf1  = (const float*)d_in[22];
  const float* Wf2  = (const float*)d_in[23];
  const float* bf2  = (const float*)d_in[24];
  const float* Wfv1 = (const float*)d_in[25];
  const float* Wfv2 = (const float*)d_in[26];

  float* outS = (float*)d_out;
  float* outV = outS + (size_t)4*2048*256;

  char* w = (char*)d_ws;
  size_t o = 0;
  auto alloc = [&](size_t bytes)->char* {
    char* p = w + o;
    o = (o + bytes + 255) & ~(size_t)255;
    return p;
  };
  float* posf  = (float*)alloc(131072);
  bf16* WqkvT = (bf16*)alloc(393216);       // 768 x 256
  bf16* WoT   = (bf16*)alloc(131072);
  bf16* Wf1T  = (bf16*)alloc(524288);
  bf16* Wf2T  = (bf16*)alloc(524288);
  bf16* WvvT  = (bf16*)alloc(8192);
  bf16* WvoT  = (bf16*)alloc(8192);
  bf16* Wfv1T = (bf16*)alloc(32768);
  bf16* Wfv2T = (bf16*)alloc(32768);
  float* bqkv = (float*)alloc(3072);
  float* kmax = (float*)alloc(64);
  bf16* sn    = (bf16*)alloc(4194304);      // reused for sn2
  bf16* qkv   = (bf16*)alloc(12582912);     // 8192 x 768; later alias: hv
  bf16* vsT   = (bf16*)alloc(4194304);
  bf16* sA    = (bf16*)alloc(4194304);
  float* s2   = (float*)alloc(8388608);
  bf16* vnX   = (bf16*)alloc(3145728);      // later alias: vn2X
  bf16* vmixX = (bf16*)alloc(3145728);      // later alias: tvXb
  bf16* vmixXT= (bf16*)alloc(3145728);      // (b, 192, 2048)
  float* v2X  = (float*)alloc(6291456);
  bf16* slab  = (bf16*)alloc(12582912);     // 4 x 8192 x 192
  bf16* h1    = (bf16*)alloc(16777216);     // 8192 x 1024
  bf16* vn2X  = vnX;
  bf16* tvXb  = vmixX;
  bf16* hv    = qkv;                        // qkv dead after attention
  if (o > ws_size) return;

  // --- prep ---
  pos_kernel<<<32, 256, 0, stream>>>(pos, posf, 8192);
  WTPack pk;
  pk.d[0] = {Wq,   WqkvT,          256, 256};
  pk.d[1] = {Wk,   WqkvT + 65536,  256, 256};
  pk.d[2] = {Wv,   WqkvT + 131072, 256, 256};
  pk.d[3] = {Wo,   WoT,            256, 256};
  pk.d[4] = {Wf1,  Wf1T,           256, 1024};
  pk.d[5] = {Wf2,  Wf2T,           1024, 256};
  pk.d[6] = {Wvv,  WvvT,           64, 64};
  pk.d[7] = {Wvo,  WvoT,           64, 64};
  pk.d[8] = {Wfv1, Wfv1T,          64, 256};
  pk.d[9] = {Wfv2, Wfv2T,          256, 64};
  wtrans_kernel<<<dim3(32,32,10), 256, 0, stream>>>(pk);
  bcat_kernel<<<3, 256, 0, stream>>>(bq, bk, bv, bqkv, kmax);

  // --- norm1 (scalar + vector) ---
  ln_kernel<<<8192, 256, 0, stream>>>(s, g1, be1, sn);
  vnorm1_kernel<<<8192, 192, 0, stream>>>(v, vs1, vnX);

  // --- vmixX = vnX @ WvvT, then per-b transpose -> vmixXT ---
  gemm_kernel<4,4,0,0,0,0,0><<<dim3(1,384,1), 64, 0, stream>>>(vnX,64,0,0, WvvT,64,0,0,
      nullptr, nullptr,0,0,0, vmixX,64,0,0, 64, 1, 1);
  transpose_kernel<bf16><<<dim3(6,64,4), 256, 0, stream>>>(vmixX, 192, 393216,0,
      vmixXT, 2048, 393216,0, 1);

  // --- fused QKV projection ---
  gemm_kernel<4,4,0,0,0,0,1><<<dim3(12,128,1), 64, 0, stream>>>(sn,256,0,0, WqkvT,256,0,0,
      bqkv, nullptr,0,0,0, qkv,768,0,0, 256, 1, 1);
  transpose_kernel<bf16><<<dim3(2,64,16), 256, 0, stream>>>(qkv+512, 768, 1572864,64,
      vsT, 2048, 524288,131072, 4);

  // --- stabilizer prepass + fully fused attention ---
  knorm_kernel<<<dim3(16,8), 256, 0, stream>>>(qkv, kmax);
  attn_kernel<<<dim3(32,16), 256, 0, stream>>>(qkv, vsT, vmixXT, posf, kmax,
      w_d, b_d, sA, slab);
  hred_kernel<<<768, 256, 0, stream>>>(slab, tvXb);

  // --- output projection + residual: s2 = s + sA@Wo + bo (fp32) ---
  gemm_kernel<4,4,0,1,0,0,1><<<dim3(4,128,1), 64, 0, stream>>>(sA,256,0,0, WoT,256,0,0,
      bo, s,256,0,0, s2,256,0,0, 256, 1, 1);

  // --- v2X = v (interleaved resid) + tvXb @ WvoT ---
  gemm_kernel<4,4,0,1,1,0,0><<<dim3(1,384,1), 64, 0, stream>>>(tvXb,64,0,0, WvoT,64,0,0,
      nullptr, v,0,0,0, v2X,64,0,0, 64, 1, 1);

  // --- norm2 + FFN ---
  ln_kernel<<<8192, 256, 0, stream>>>(s2, g2, be2, sn);
  gemm_kernel<4,4,1,0,0,0,1><<<dim3(16,128,1), 64, 0, stream>>>(sn,256,0,0, Wf1T,256,0,0,
      bf1, nullptr,0,0,0, h1,1024,0,0, 256, 1, 1);
  gemm_kernel<4,4,0,1,0,0,1><<<dim3(4,128,1), 64, 0, stream>>>(h1,1024,0,0, Wf2T,1024,0,0,
      bf2, s2,256,0,0, outS,256,0,0, 1024, 1, 1);

  // --- vector FFN ---
  vnorm2_kernel<<<8192, 192, 0, stream>>>(v2X, vs2, vn2X);
  gemm_kernel<4,4,0,0,0,0,1><<<dim3(4,384,1), 64, 0, stream>>>(vn2X,64,0,0, Wfv1T,64,0,0,
      nullptr, nullptr,0,0,0, hv,256,0,0, 64, 1, 1);
  gemm_kernel<4,4,0,1,0,1,0><<<dim3(1,384,1), 64, 0, stream>>>(hv,256,0,0, Wfv2T,256,0,0,
      nullptr, v2X,64,0,0, outV,0,0,0, 256, 1, 1);
}

// Round 7
// 403.241 us; speedup vs baseline: 2.7256x; 2.7256x over previous
//
#include <hip/hip_runtime.h>
#include <hip/hip_bf16.h>

using bf16 = __hip_bfloat16;
typedef __attribute__((ext_vector_type(8))) short short8;
typedef __attribute__((ext_vector_type(4))) float float4v;
typedef __attribute__((ext_vector_type(16))) float f32x16;
typedef __attribute__((ext_vector_type(4))) unsigned uint4v;

__device__ __forceinline__ float b2f(bf16 x){ return __bfloat162float(x); }
__device__ __forceinline__ bf16  f2b(float x){ return __float2bfloat16(x); }
__device__ __forceinline__ bf16  tob(float x){ return f2b(x); }
__device__ __forceinline__ bf16  tob(bf16 x){ return x; }
__device__ __forceinline__ float frcp(float x){ return __builtin_amdgcn_rcpf(x); }
__device__ __forceinline__ float bs2f(short s){
  unsigned u = ((unsigned)(unsigned short)s) << 16;
  return __builtin_bit_cast(float, u);
}
__device__ __forceinline__ unsigned cvt_pk_bf16(float lo, float hi){
  unsigned r; asm("v_cvt_pk_bf16_f32 %0, %1, %2" : "=v"(r) : "v"(lo), "v"(hi)); return r;
}
__device__ __forceinline__ void plswap(unsigned &a, unsigned &b){
  asm("v_permlane32_swap_b32 %0, %1" : "+v"(a), "+v"(b));
}

#define EPSV 1e-5f
#define Z16 {0.f,0.f,0.f,0.f,0.f,0.f,0.f,0.f,0.f,0.f,0.f,0.f,0.f,0.f,0.f,0.f}

// ------------------------------------------------------------------
// pos prep: posf[r] = {x,y,z,|p|^2} fp32
// ------------------------------------------------------------------
__global__ __launch_bounds__(256) void pos_kernel(const float* __restrict__ pos,
                                                  float* __restrict__ posf, int rows){
  int r = blockIdx.x*256 + threadIdx.x;
  if (r >= rows) return;
  float x = pos[3*r], y = pos[3*r+1], z = pos[3*r+2];
  posf[4*r] = x; posf[4*r+1] = y; posf[4*r+2] = z; posf[4*r+3] = x*x + y*y + z*z;
}

// ------------------------------------------------------------------
// all 10 weight transposes (fp32 -> bf16) in ONE launch.
// ------------------------------------------------------------------
struct WTDesc { const float* src; bf16* dst; int rows, cols; };
struct WTPack { WTDesc d[10]; };

__global__ __launch_bounds__(256) void wtrans_kernel(WTPack p){
  WTDesc w = p.d[blockIdx.z];
  long r0 = (long)blockIdx.y*32, c0 = (long)blockIdx.x*32;
  if (r0 >= w.rows || c0 >= w.cols) return;
  __shared__ bf16 tile[32][33];
  int tx = threadIdx.x & 31, ty = threadIdx.x >> 5;
#pragma unroll
  for (int i = ty; i < 32; i += 8) tile[i][tx] = f2b(w.src[(r0+i)*w.cols + c0 + tx]);
  __syncthreads();
#pragma unroll
  for (int i = ty; i < 32; i += 8) w.dst[(c0+i)*w.rows + r0 + tx] = tile[tx][i];
}

// ------------------------------------------------------------------
// batched 32x32-tiled transpose (+ cast to bf16)
// ------------------------------------------------------------------
template<typename TI>
__global__ __launch_bounds__(256) void transpose_kernel(
    const TI* __restrict__ in, long ldin, long is1, long is2,
    bf16* __restrict__ out, long ldout, long os1, long os2, int Z2)
{
  int z = blockIdx.z, z1 = z / Z2, z2 = z - z1*Z2;
  in  += (long)z1*is1 + (long)z2*is2;
  out += (long)z1*os1 + (long)z2*os2;
  __shared__ bf16 tile[32][33];
  int tx = threadIdx.x & 31, ty = threadIdx.x >> 5;
  long r0 = (long)blockIdx.y*32, c0 = (long)blockIdx.x*32;
#pragma unroll
  for (int i = ty; i < 32; i += 8) tile[i][tx] = tob(in[(r0+i)*ldin + c0 + tx]);
  __syncthreads();
#pragma unroll
  for (int i = ty; i < 32; i += 8) out[(c0+i)*ldout + r0 + tx] = tile[tx][i];
}

// ------------------------------------------------------------------
// bias concat for fused QKV (+ zero the kmax accumulator)
// ------------------------------------------------------------------
__global__ __launch_bounds__(256) void bcat_kernel(const float* __restrict__ bq,
                                                   const float* __restrict__ bk,
                                                   const float* __restrict__ bv,
                                                   float* __restrict__ bqkv,
                                                   float* __restrict__ kmax){
  int j = blockIdx.x*256 + threadIdx.x;
  if (blockIdx.x == 0 && threadIdx.x < 16) kmax[threadIdx.x] = 0.f;
  if (j >= 768) return;
  bqkv[j] = (j < 256) ? bq[j] : (j < 512) ? bk[j-256] : bv[j-512];
}

// ------------------------------------------------------------------
// LayerNorm over S=256 per row (fp32 in -> bf16 out)
// ------------------------------------------------------------------
__global__ __launch_bounds__(256) void ln_kernel(const float* __restrict__ x,
                                                 const float* __restrict__ g,
                                                 const float* __restrict__ be,
                                                 bf16* __restrict__ out){
  const long row = blockIdx.x;
  const int t = threadIdx.x;
  __shared__ float r1[256], r2[256];
  float v = x[(row<<8) + t];
  r1[t] = v; r2[t] = v*v; __syncthreads();
  for (int s=128;s>0;s>>=1){
    if (t<s){ r1[t] += r1[t+s]; r2[t] += r2[t+s]; }
    __syncthreads();
  }
  const float mu = r1[0] * (1.f/256.f);
  const float var = r2[0] * (1.f/256.f) - mu*mu;
  const float rstd = rsqrtf(fmaxf(var, 0.f) + EPSV);
  out[(row<<8)+t] = f2b((v-mu)*rstd*g[t] + be[t]);
}

// ------------------------------------------------------------------
// eq-norm 1: v (b,n,c,x) fp32 -> vnX[(b,n,x), c] bf16
// ------------------------------------------------------------------
__global__ __launch_bounds__(192) void vnorm1_kernel(const float* __restrict__ vin,
                                                     const float* __restrict__ vs1,
                                                     bf16* __restrict__ vnX){
  const long row = blockIdx.x;
  const int t = threadIdx.x;
  __shared__ float vv[192], nrm[64];
  __shared__ float smean;
  vv[t] = vin[row*192 + t];
  __syncthreads();
  if (t < 64){
    float a = vv[3*t], b = vv[3*t+1], c = vv[3*t+2];
    nrm[t] = sqrtf(a*a + b*b + c*c);
  }
  __syncthreads();
  if (t == 0){ float s = 0.f; for (int i=0;i<64;i++) s += nrm[i]; smean = s*(1.f/64.f); }
  __syncthreads();
  const int c = t/3, x = t - 3*c;
  const float val = vv[t] / (nrm[c] + EPSV) * smean * vs1[c];
  vnX[row*192 + x*64 + c] = f2b(val);
}

// ------------------------------------------------------------------
// eq-norm 2: v2X[(b,n), x*64+c] fp32 -> vn2X same layout bf16
// ------------------------------------------------------------------
__global__ __launch_bounds__(192) void vnorm2_kernel(const float* __restrict__ v2X,
                                                     const float* __restrict__ vs2,
                                                     bf16* __restrict__ vn2X){
  const long row = blockIdx.x;
  const int t = threadIdx.x;
  __shared__ float vv[192], nrm[64];
  __shared__ float smean;
  vv[t] = v2X[row*192 + t];
  __syncthreads();
  if (t < 64){
    float a = vv[t], b = vv[t+64], c = vv[t+128];
    nrm[t] = sqrtf(a*a + b*b + c*c);
  }
  __syncthreads();
  if (t == 0){ float s = 0.f; for (int i=0;i<64;i++) s += nrm[i]; smean = s*(1.f/64.f); }
  __syncthreads();
  const int c = t & 63;
  vn2X[row*192 + t] = f2b(vv[t] / (nrm[c] + EPSV) * smean * vs2[c]);
}

// ------------------------------------------------------------------
// per-(b,h) max ||k||^2 via atomicMax (uint order == float order, >=0).
// grid (16 bh, 8 chunks of 256 rows); bcat_kernel zeroes kmax first.
// ------------------------------------------------------------------
__global__ __launch_bounds__(256) void knorm_kernel(const bf16* __restrict__ qkv,
                                                    float* __restrict__ kmax){
  const int bh = blockIdx.x, b = bh>>2, h = bh&3;
  const int t = threadIdx.x;
  __shared__ float red[256];
  long row = (long)b*2048 + (long)blockIdx.y*256 + t;
  const short8* kp = (const short8*)(qkv + row*768 + 256 + h*64);
  float ss = 0.f;
#pragma unroll
  for (int c=0;c<8;c++){
    short8 v = kp[c];
#pragma unroll
    for (int j=0;j<8;j++){ float f = bs2f(v[j]); ss = fmaf(f,f,ss); }
  }
  red[t] = ss; __syncthreads();
  for (int s=128;s>0;s>>=1){ if (t<s) red[t] = fmaxf(red[t], red[t+s]); __syncthreads(); }
  if (t==0) atomicMax((unsigned*)&kmax[bh], __float_as_uint(red[0]));
}

// ------------------------------------------------------------------
// FUSED ATTENTION, 8-wave m-split (2 groups x 4 q-waves, 2 waves/SIMD):
//   round-5 benched structure: 116.7 us, VGPR 124. DO NOT raise
//   occupancy: 3 waves/SIMD caps regs at ~170 < ~200 live state ->
//   scratch spill (rounds 4 & 6, both ~8x slower).
// ------------------------------------------------------------------
#define ATT_K_OFF   0
#define ATT_V_OFF   4096
#define ATT_X_OFF   9216
#define ATT_P_OFF   24576
#define ATT_TILE    25088
#define ATT_GRP     50176          // 2 dbuf per group
#define ATT_LACC    98304          // 8*64 floats = 2048 B
#define ATT_SMEM    100352

__global__ __launch_bounds__(512, 2) void attn_kernel(
    const bf16* __restrict__ qkv,    // [8192][768] (Q|K|V, 4 heads x 64)
    const bf16* __restrict__ vsT,    // [b][h][64][2048]
    const bf16* __restrict__ vmixT,  // [b][192][2048]
    const float* __restrict__ posf,  // [b][2048][4]
    const float* __restrict__ kmaxA, // [16] max ||k||^2
    const float* __restrict__ w_dist, const float* __restrict__ b_dist,
    bf16* __restrict__ sA,           // [8192][256]
    bf16* __restrict__ slab)         // [4][8192][192]
{
  __shared__ __align__(16) char smem[ATT_SMEM];
  const int qb = blockIdx.x;         // 0..15
  const int bh = blockIdx.y;         // 0..15
  const int b  = bh >> 2, h = bh & 3;
  const int tid = threadIdx.x;
  const int w = tid >> 6, lane = tid & 63;
  const int g = w >> 2, qw = w & 3;
  const int lq = lane & 31, hi = lane >> 5;
  const int gtid = tid & 255;

  const int qloc = qb*128 + qw*32 + lq;
  const long rowQ = (long)b*2048 + qloc;

  // Q fragments (B operand): col=q (lane&31), k=d = kc*16 + hi*8 + j
  short8 qf[4];
  {
    const bf16* qp = qkv + rowQ*768 + h*64 + hi*8;
#pragma unroll
    for (int kc=0;kc<4;kc++) qf[kc] = *(const short8*)(qp + kc*16);
  }
  // stabilizer: sqrt(|q|^2 * max|k|^2) / 8  (>= max_m qk/8; bias only subtracts)
  float q2 = 0.f;
#pragma unroll
  for (int kc=0;kc<4;kc++)
#pragma unroll
    for (int j=0;j<8;j++){ float qv = bs2f(qf[kc][j]); q2 = fmaf(qv,qv,q2); }
  q2 += __shfl_xor(q2, 32);
  const float mxs = sqrtf(q2 * kmaxA[bh]) * 0.125f;
  const float wh = w_dist[h], bhd = b_dist[h];
  const float4v pn = *(const float4v*)(posf + (long)b*8192 + (long)qloc*4);
  const float m2x = -2.f*pn[0], m2y = -2.f*pn[1], m2z = -2.f*pn[2], pnw = pn[3];

  f32x16 O[2]  = {Z16, Z16};
  f32x16 VM[6] = {Z16, Z16, Z16, Z16, Z16, Z16};
  float lacc = 0.f;

  // per-group staging (256 threads, 20.5 KB/tile)
  short8 stK, stV, stX0, stX1, stX2; float4v stP;
  const int sm = gtid >> 3, sc = gtid & 7;   // K: row(32) x chunk(8)
  const int vd = gtid >> 2, vc = gtid & 3;   // V/X: row x chunk(4)
  const bf16* Kg = qkv + (long)b*2048*768 + 256 + h*64;
  const bf16* Vg = vsT + (long)b*524288 + (long)h*131072;
  const bf16* Xg = vmixT + (long)b*393216;
  const float* Pg = posf + (long)b*8192;
  char* gbase = smem + g*ATT_GRP;

  auto LOADT = [&](int m0){
    stK  = *(const short8*)(Kg + (long)(m0+sm)*768 + sc*8);
    stV  = *(const short8*)(Vg + (long)vd*2048 + m0 + vc*8);
    stX0 = *(const short8*)(Xg + (long)vd*2048 + m0 + vc*8);
    stX1 = *(const short8*)(Xg + (long)(64+vd)*2048 + m0 + vc*8);
    stX2 = *(const short8*)(Xg + (long)(128+vd)*2048 + m0 + vc*8);
    if (gtid < 32) stP = *(const float4v*)(Pg + (long)(m0+gtid)*4);
  };
  auto WRITET = [&](char* buf){
    *(short8*)(buf + ATT_K_OFF + sm*128 + ((sc ^ (sm&7))<<4)) = stK;   // XOR-swizzle
    *(short8*)(buf + ATT_V_OFF + vd*80 + vc*16) = stV;
    *(short8*)(buf + ATT_X_OFF + vd*80 + vc*16) = stX0;
    *(short8*)(buf + ATT_X_OFF + (64+vd)*80 + vc*16) = stX1;
    *(short8*)(buf + ATT_X_OFF + (128+vd)*80 + vc*16) = stX2;
    if (gtid < 32) *(float4v*)(buf + ATT_P_OFF + gtid*16) = stP;
  };

  auto COMPUTE = [&](const char* buf){
    const char* Kb = buf + ATT_K_OFF;
    const char* Vb = buf + ATT_V_OFF;
    const char* Xb = buf + ATT_X_OFF;
    const float4v* pmb = (const float4v*)(buf + ATT_P_OFF);
    // swapped QK^T: S[m][q], col = lane&31 = q
    f32x16 S = Z16;
#pragma unroll
    for (int kc=0;kc<4;kc++){
      short8 kf = *(const short8*)(Kb + lq*128 + (((kc*2+hi) ^ (lq&7))<<4));
      S = __builtin_amdgcn_mfma_f32_32x32x16_bf16(kf, qf[kc], S, 0, 0, 0);
    }
    // dist bias + exp (unnormalized, fixed stabilizer); m = i + 8gg + 4hi
    float P[16];
#pragma unroll
    for (int gg=0; gg<4; gg++){
#pragma unroll
      for (int i=0;i<4;i++){
        float4v pm = pmb[gg*8 + hi*4 + i];
        float d2 = fmaf(m2x, pm[0], fmaf(m2y, pm[1], fmaf(m2z, pm[2], pnw + pm[3])));
        float dist = sqrtf(fmaxf(d2, 1e-12f));
        float sig = frcp(1.f + __expf(fmaf(dist, wh, bhd)));
        float p = __expf(fmaf(S[gg*4+i], 0.125f, -mxs)) * sig;
        lacc += p;
        P[gg*4+i] = p;
      }
    }
    // P -> bf16 B-operand (col=q, k=m) via cvt_pk + permlane32_swap
    unsigned pk[8];
#pragma unroll
    for (int t=0;t<8;t++) pk[t] = cvt_pk_bf16(P[2*t], P[2*t+1]);
    plswap(pk[0], pk[2]); plswap(pk[1], pk[3]);   // chunk0: m 0..15
    plswap(pk[4], pk[6]); plswap(pk[5], pk[7]);   // chunk1: m 16..31
    uint4v y0v = {pk[0], pk[1], pk[2], pk[3]};
    uint4v y1v = {pk[4], pk[5], pk[6], pk[7]};
    short8 Y0 = __builtin_bit_cast(short8, y0v);
    short8 Y1 = __builtin_bit_cast(short8, y1v);
    // PV: O^T[d][q] += V^T[d][m] * P[q][m]
#pragma unroll
    for (int dblk=0; dblk<2; dblk++){
      short8 v0 = *(const short8*)(Vb + (dblk*32+lq)*80 + hi*16);
      short8 v1 = *(const short8*)(Vb + (dblk*32+lq)*80 + 32 + hi*16);
      O[dblk] = __builtin_amdgcn_mfma_f32_32x32x16_bf16(v0, Y0, O[dblk], 0,0,0);
      O[dblk] = __builtin_amdgcn_mfma_f32_32x32x16_bf16(v1, Y1, O[dblk], 0,0,0);
    }
    // vmix: VM^T[e][q] += vmix^T[e][m] * P[q][m]
#pragma unroll
    for (int eblk=0; eblk<6; eblk++){
      short8 x0 = *(const short8*)(Xb + (eblk*32+lq)*80 + hi*16);
      short8 x1 = *(const short8*)(Xb + (eblk*32+lq)*80 + 32 + hi*16);
      VM[eblk] = __builtin_amdgcn_mfma_f32_32x32x16_bf16(x0, Y0, VM[eblk], 0,0,0);
      VM[eblk] = __builtin_amdgcn_mfma_f32_32x32x16_bf16(x1, Y1, VM[eblk], 0,0,0);
    }
  };

  // group g computes tiles g, g+2, ..., g+62 (32 tiles each)
  LOADT(g*32);
  WRITET(gbase);
  __syncthreads();
#pragma unroll 1
  for (int i=0; i<32; ++i){
    if (i < 31) LOADT((2*(i+1)+g)*32);
    COMPUTE(gbase + (i&1)*ATT_TILE);
    if (i < 31) WRITET(gbase + ((i+1)&1)*ATT_TILE);
    __syncthreads();
  }

  // ---------------- cross-group combine (odd strides: conflict-free) ----------------
  float* laccT = (float*)(smem + ATT_LACC);
  laccT[w*64 + lane] = lacc;
  if (g == 1){                       // group 1 exports O (stride 33 floats)
    float* Od = (float*)(smem + ATT_GRP) + (qw*64+lane)*33;
#pragma unroll
    for (int r=0;r<16;r++){ Od[r] = O[0][r]; Od[16+r] = O[1][r]; }
  }
  __syncthreads();
  const float lsum = laccT[qw*64+lq] + laccT[qw*64+32+lq]
                   + laccT[(4+qw)*64+lq] + laccT[(4+qw)*64+32+lq];
  if (g == 0){                       // group 0 accumulates full O
    const float* Od = (const float*)(smem + ATT_GRP) + (qw*64+lane)*33;
#pragma unroll
    for (int r=0;r<16;r++){ O[0][r] += Od[r]; O[1][r] += Od[16+r]; }
  }
  __syncthreads();
  // VM in two halves (stride 49 floats; each half fits the 50176 B group-0 area)
#pragma unroll
  for (int hf=0; hf<2; hf++){
    if (g == 0){                     // group 0 exports VM half
      float* Vd = (float*)smem + (qw*64+lane)*49;
#pragma unroll
      for (int e=0;e<3;e++)
#pragma unroll
        for (int r=0;r<16;r++) Vd[e*16+r] = VM[hf*3+e][r];
    }
    __syncthreads();
    if (g == 1){                     // group 1 accumulates full VM
      const float* Vd = (const float*)smem + (qw*64+lane)*49;
#pragma unroll
      for (int e=0;e<3;e++)
#pragma unroll
        for (int r=0;r<16;r++) VM[hf*3+e][r] += Vd[e*16+r];
    }
    __syncthreads();
  }

  // ---------------- parallel epilogue ----------------
  const float sinv = frcp(lsum);
  if (g == 0){
    // s_attn: transpose O^T[d][q] -> [q][64d] via LDS (pitch 136B)
    char* scr = smem + qw*12544;
#pragma unroll
    for (int dblk=0; dblk<2; dblk++)
#pragma unroll
      for (int pp=0; pp<8; pp++){
        const int r = 2*pp;
        const int d = dblk*32 + (r&3) + 8*(r>>2) + 4*hi;
        unsigned u = cvt_pk_bf16(O[dblk][r]*sinv, O[dblk][r+1]*sinv);
        *(unsigned*)(scr + lq*136 + d*2) = u;
      }
  } else {
    // vmix: transpose VM^T[e][q] -> [q][192e] via LDS (pitch 392B)
    const float vinv = 0.25f * sinv;
    char* scr = smem + ATT_GRP + qw*12544;
#pragma unroll
    for (int eblk=0; eblk<6; eblk++)
#pragma unroll
      for (int pp=0; pp<8; pp++){
        const int r = 2*pp;
        const int e = eblk*32 + (r&3) + 8*(r>>2) + 4*hi;
        unsigned u = cvt_pk_bf16(VM[eblk][r]*vinv, VM[eblk][r+1]*vinv);
        *(unsigned*)(scr + lq*392 + e*2) = u;
      }
  }
  __syncthreads();
  if (g == 0){
    const char* scr = smem + qw*12544;
    const int q = lane >> 1, half = lane & 1;
    const char* src = scr + q*136 + half*64;
    char* dst = (char*)(sA + (long)(b*2048 + qb*128 + qw*32 + q)*256 + h*64 + half*32);
#pragma unroll
    for (int i=0;i<8;i++)
      *(unsigned long long*)(dst + i*8) = *(const unsigned long long*)(src + i*8);
  } else {
    const char* scr = smem + ATT_GRP + qw*12544;
    const int q = lane >> 1, half = lane & 1;
    const char* src = scr + q*392 + half*192;
    char* dst = (char*)(slab + (long)h*1572864
                        + (long)(b*2048 + qb*128 + qw*32 + q)*192 + half*96);
#pragma unroll
    for (int i=0;i<24;i++)
      *(unsigned long long*)(dst + i*8) = *(const unsigned long long*)(src + i*8);
  }
}

// ------------------------------------------------------------------
// reduce 4 per-head slabs (already scaled by 1/(4 l_h)) -> tvXb bf16
// ------------------------------------------------------------------
__global__ __launch_bounds__(256) void hred_kernel(const bf16* __restrict__ slab,
                                                   bf16* __restrict__ out){
  long i = (long)blockIdx.x*256 + threadIdx.x;   // over 196608 short8s
  if (i >= 196608) return;
  const short8* s0 = (const short8*)slab + i;
  short8 a = s0[0], b = s0[196608], c = s0[2*196608], d = s0[3*196608];
  short8 o;
#pragma unroll
  for (int j=0;j<8;j++){
    float f = bs2f(a[j]) + bs2f(b[j]) + bs2f(c[j]) + bs2f(d[j]);
    bf16 hv = f2b(f); o[j] = *(short*)&hv;
  }
  ((short8*)out)[i] = o;
}

// ------------------------------------------------------------------
// TILED GEMM: 128x128 tile, 256 thr = 4 waves (2x2 of 64x64), BK=32,
// double-buffered LDS (32 KB), one barrier per K-step. Linear LDS
// layout [128][32] bf16: both ds_write (staging) and ds_read (frags)
// tile contiguous 1KB regions per wave => conflict-free. Requires
// M%128==0, N%128==0, K%32==0. C[i][j] = sum_k A[i][k]*BT[j][k].
// ------------------------------------------------------------------
template<int ACT, int OUTM>
__global__ __launch_bounds__(256) void tgemm_kernel(
    const bf16* __restrict__ A, long lda,
    const bf16* __restrict__ BT, long ldb,
    const float* __restrict__ bias,
    const float* __restrict__ resid,   // fp32, same ld as C
    void* __restrict__ Cv, long ldc,
    int K)
{
  __shared__ __align__(16) bf16 As[2][128*32];
  __shared__ __align__(16) bf16 Bs[2][128*32];
  const int tid = threadIdx.x;
  const int w = tid >> 6, lane = tid & 63;
  const int wr = w >> 1, wc = w & 1;
  const int col = lane & 15, quad = lane >> 4;
  const long rowA0 = (long)blockIdx.y*128;
  const long colB0 = (long)blockIdx.x*128;

  // staging: thread t covers rows (t>>2) and (t>>2)+64, chunk t&3 (16B)
  const int tr = tid >> 2, tc = tid & 3;
  const bf16* Ag = A + (rowA0 + tr)*lda + tc*8;
  const bf16* Bg = BT + (colB0 + tr)*ldb + tc*8;

  short8 sa[2], sb[2];
  auto LOAD = [&](int k0){
#pragma unroll
    for (int c=0;c<2;c++){
      sa[c] = *(const short8*)(Ag + (long)c*64*lda + k0);
      sb[c] = *(const short8*)(Bg + (long)c*64*ldb + k0);
    }
  };
  auto STORE = [&](int buf){
#pragma unroll
    for (int c=0;c<2;c++){
      *(short8*)(&As[buf][(tr + 64*c)*32 + tc*8]) = sa[c];
      *(short8*)(&Bs[buf][(tr + 64*c)*32 + tc*8]) = sb[c];
    }
  };

  float4v acc[4][4];
#pragma unroll
  for (int m=0;m<4;m++)
#pragma unroll
    for (int n=0;n<4;n++) acc[m][n] = (float4v){0.f,0.f,0.f,0.f};

  LOAD(0); STORE(0);
  __syncthreads();
  const int nk = K >> 5;
#pragma unroll 1
  for (int ks=0; ks<nk; ++ks){
    if (ks+1 < nk) LOAD((ks+1)*32);
    const bf16* Ab = &As[ks&1][(wr*64 + col)*32 + quad*8];
    const bf16* Bb = &Bs[ks&1][(wc*64 + col)*32 + quad*8];
    short8 af[4], bfv[4];
#pragma unroll
    for (int m=0;m<4;m++) af[m] = *(const short8*)(Ab + m*16*32);
#pragma unroll
    for (int n=0;n<4;n++) bfv[n] = *(const short8*)(Bb + n*16*32);
#pragma unroll
    for (int m=0;m<4;m++)
#pragma unroll
      for (int n=0;n<4;n++)
        acc[m][n] = __builtin_amdgcn_mfma_f32_16x16x32_bf16(af[m], bfv[n], acc[m][n], 0, 0, 0);
    if (ks+1 < nk) STORE((ks+1)&1);   // other buffer: no alias with this step's reads
    __syncthreads();                  // writes visible before next step's reads
  }

  // epilogue
#pragma unroll
  for (int m=0;m<4;m++){
    const long ci0 = rowA0 + wr*64 + m*16 + quad*4;
#pragma unroll
    for (int n=0;n<4;n++){
      const long cj = colB0 + wc*64 + n*16 + col;
      const float bbias = bias ? bias[cj] : 0.f;
#pragma unroll
      for (int r=0;r<4;r++){
        const long ci = ci0 + r;
        float val = acc[m][n][r] + bbias;
        if (ACT == 1) val = 0.5f*val*(1.f + erff(val*0.70710678118654752f));
        if (resid) val += resid[ci*ldc + cj];
        if (OUTM == 0) ((bf16*)Cv)[ci*ldc + cj] = f2b(val);
        else           ((float*)Cv)[ci*ldc + cj] = val;
      }
    }
  }
}

// ------------------------------------------------------------------
// simple MFMA GEMM (small shapes: K=64 / N=64 paths)
// ------------------------------------------------------------------
template<int MT, int NT, int ACT, int OUTM, int RXIL, int CXIL>
__global__ __launch_bounds__(64) void gemm_kernel(
    const bf16* __restrict__ A, long lda, long As1, long As2,
    const bf16* __restrict__ BT, long ldb, long Bs1, long Bs2,
    const float* __restrict__ bias,
    const float* __restrict__ resid, long ldr, long Rs1, long Rs2,
    void* __restrict__ Cv, long ldc, long Cs1, long Cs2,
    int K, int Z2, int KS)
{
  int z = blockIdx.z;
  int zz = z / KS, ks = z - zz*KS;
  int z1 = zz / Z2, z2 = zz - z1*Z2;
  A  += (long)z1*As1 + (long)z2*As2 + (long)ks*K;
  BT += (long)z1*Bs1 + (long)z2*Bs2 + (long)ks*K;
  if (resid) resid += (long)z1*Rs1 + (long)z2*Rs2;
  const long cbase = (long)z1*Cs1 + (long)z2*Cs2;

  const int lane = threadIdx.x;
  const int col = lane & 15, quad = lane >> 4;
  const long rowA0 = (long)blockIdx.y*(16*MT);
  const long colB0 = (long)blockIdx.x*(16*NT);

  float4v acc[MT][NT];
#pragma unroll
  for (int m=0;m<MT;m++)
#pragma unroll
    for (int n=0;n<NT;n++) acc[m][n] = (float4v){0.f,0.f,0.f,0.f};

  const bf16* ap[MT];
  const bf16* bp[NT];
#pragma unroll
  for (int m=0;m<MT;m++) ap[m] = A + (rowA0 + m*16 + col)*lda + quad*8;
#pragma unroll
  for (int n=0;n<NT;n++) bp[n] = BT + (colB0 + n*16 + col)*ldb + quad*8;

  for (int k0 = 0; k0 < K; k0 += 32){
    short8 a[MT], bb[NT];
#pragma unroll
    for (int m=0;m<MT;m++){ a[m] = *(const short8*)ap[m]; ap[m] += 32; }
#pragma unroll
    for (int n=0;n<NT;n++){ bb[n] = *(const short8*)bp[n]; bp[n] += 32; }
#pragma unroll
    for (int m=0;m<MT;m++)
#pragma unroll
      for (int n=0;n<NT;n++)
        acc[m][n] = __builtin_amdgcn_mfma_f32_16x16x32_bf16(a[m], bb[n], acc[m][n], 0, 0, 0);
  }

#pragma unroll
  for (int m=0;m<MT;m++){
    const long ri = rowA0 + m*16 + quad*4;
#pragma unroll
    for (int n=0;n<NT;n++){
      const long cj = colB0 + n*16 + col;
      const float bbias = bias ? bias[cj] : 0.f;
#pragma unroll
      for (int r=0;r<4;r++){
        const long ci = ri + r;
        float val = acc[m][n][r] + bbias;
        if (ACT == 1) val = 0.5f*val*(1.f + erff(val*0.70710678118654752f));
        if (resid){
          const long raddr = RXIL ? ((ci/3)*192 + cj*3 + (ci%3)) : (ci*ldr + cj);
          val += resid[raddr];
        }
        const long caddr = CXIL ? (cbase + (ci/3)*192 + cj*3 + (ci%3))
                                : (cbase + ci*ldc + cj);
        if (OUTM == 0)      ((bf16*)Cv)[caddr] = f2b(val);
        else if (OUTM == 1) ((float*)Cv)[caddr] = val;
        else                unsafeAtomicAdd(&((float*)Cv)[caddr], val);
      }
    }
  }
}

// ------------------------------------------------------------------
extern "C" void kernel_launch(void* const* d_in, const int* in_sizes, int n_in,
                              void* d_out, int out_size, void* d_ws, size_t ws_size,
                              hipStream_t stream)
{
  const float* s    = (const float*)d_in[0];
  const float* v    = (const float*)d_in[1];
  const float* pos  = (const float*)d_in[2];
  const float* Wq   = (const float*)d_in[3];
  const float* bq   = (const float*)d_in[4];
  const float* Wk   = (const float*)d_in[5];
  const float* bk   = (const float*)d_in[6];
  const float* Wv   = (const float*)d_in[7];
  const float* bv   = (const float*)d_in[8];
  const float* Wo   = (const float*)d_in[9];
  const float* bo   = (const float*)d_in[10];
  const float* w_d  = (const float*)d_in[11];
  const float* b_d  = (const float*)d_in[12];
  const float* Wvv  = (const float*)d_in[13];
  const float* Wvo  = (const float*)d_in[14];
  const float* g1   = (const float*)d_in[15];
  const float* be1  = (const float*)d_in[16];
  const float* vs1  = (const float*)d_in[17];
  const float* g2   = (const float*)d_in[18];
  const float* be2  = (const float*)d_in[19];
  const float* vs2  = (const float*)d_in[20];
  const float* Wf1  = (const float*)d_in[21];
  const float* bf1  = (const float*)d_in[22];
  const float* Wf2  = (const float*)d_in[23];
  const float* bf2  = (const float*)d_in[24];
  const float* Wfv1 = (const float*)d_in[25];
  const float* Wfv2 = (const float*)d_in[26];

  float* outS = (float*)d_out;
  float* outV = outS + (size_t)4*2048*256;

  char* w = (char*)d_ws;
  size_t o = 0;
  auto alloc = [&](size_t bytes)->char* {
    char* p = w + o;
    o = (o + bytes + 255) & ~(size_t)255;
    return p;
  };
  float* posf  = (float*)alloc(131072);
  bf16* WqkvT = (bf16*)alloc(393216);       // 768 x 256
  bf16* WoT   = (bf16*)alloc(131072);
  bf16* Wf1T  = (bf16*)alloc(524288);
  bf16* Wf2T  = (bf16*)alloc(524288);
  bf16* WvvT  = (bf16*)alloc(8192);
  bf16* WvoT  = (bf16*)alloc(8192);
  bf16* Wfv1T = (bf16*)alloc(32768);
  bf16* Wfv2T = (bf16*)alloc(32768);
  float* bqkv = (float*)alloc(3072);
  float* kmax = (float*)alloc(64);
  bf16* sn    = (bf16*)alloc(4194304);      // reused for sn2
  bf16* qkv   = (bf16*)alloc(12582912);     // 8192 x 768; later alias: hv
  bf16* vsT   = (bf16*)alloc(4194304);
  bf16* sA    = (bf16*)alloc(4194304);
  float* s2   = (float*)alloc(8388608);
  bf16* vnX   = (bf16*)alloc(3145728);      // later alias: vn2X
  bf16* vmixX = (bf16*)alloc(3145728);      // later alias: tvXb
  bf16* vmixXT= (bf16*)alloc(3145728);      // (b, 192, 2048)
  float* v2X  = (float*)alloc(6291456);
  bf16* slab  = (bf16*)alloc(12582912);     // 4 x 8192 x 192
  bf16* h1    = (bf16*)alloc(16777216);     // 8192 x 1024
  bf16* vn2X  = vnX;
  bf16* tvXb  = vmixX;
  bf16* hv    = qkv;                        // qkv dead after attention
  if (o > ws_size) return;

  // --- prep ---
  pos_kernel<<<32, 256, 0, stream>>>(pos, posf, 8192);
  WTPack pk;
  pk.d[0] = {Wq,   WqkvT,          256, 256};
  pk.d[1] = {Wk,   WqkvT + 65536,  256, 256};
  pk.d[2] = {Wv,   WqkvT + 131072, 256, 256};
  pk.d[3] = {Wo,   WoT,            256, 256};
  pk.d[4] = {Wf1,  Wf1T,           256, 1024};
  pk.d[5] = {Wf2,  Wf2T,           1024, 256};
  pk.d[6] = {Wvv,  WvvT,           64, 64};
  pk.d[7] = {Wvo,  WvoT,           64, 64};
  pk.d[8] = {Wfv1, Wfv1T,          64, 256};
  pk.d[9] = {Wfv2, Wfv2T,          256, 64};
  wtrans_kernel<<<dim3(32,32,10), 256, 0, stream>>>(pk);
  bcat_kernel<<<3, 256, 0, stream>>>(bq, bk, bv, bqkv, kmax);

  // --- norm1 (scalar + vector) ---
  ln_kernel<<<8192, 256, 0, stream>>>(s, g1, be1, sn);
  vnorm1_kernel<<<8192, 192, 0, stream>>>(v, vs1, vnX);

  // --- vmixX = vnX @ WvvT, then per-b transpose -> vmixXT ---
  gemm_kernel<2,4,0,0,0,0><<<dim3(1,768,1), 64, 0, stream>>>(vnX,64,0,0, WvvT,64,0,0,
      nullptr, nullptr,0,0,0, vmixX,64,0,0, 64, 1, 1);
  transpose_kernel<bf16><<<dim3(6,64,4), 256, 0, stream>>>(vmixX, 192, 393216,0,
      vmixXT, 2048, 393216,0, 1);

  // --- fused QKV projection (tiled): M=8192, N=768, K=256 ---
  tgemm_kernel<0,0><<<dim3(6,64), 256, 0, stream>>>(sn,256, WqkvT,256,
      bqkv, nullptr, qkv,768, 256);
  transpose_kernel<bf16><<<dim3(2,64,16), 256, 0, stream>>>(qkv+512, 768, 1572864,64,
      vsT, 2048, 524288,131072, 4);

  // --- stabilizer prepass + fully fused attention ---
  knorm_kernel<<<dim3(16,8), 256, 0, stream>>>(qkv, kmax);
  attn_kernel<<<dim3(16,16), 512, 0, stream>>>(qkv, vsT, vmixXT, posf, kmax,
      w_d, b_d, sA, slab);
  hred_kernel<<<768, 256, 0, stream>>>(slab, tvXb);

  // --- output projection + residual: s2 = s + sA@Wo + bo (fp32, tiled) ---
  tgemm_kernel<0,1><<<dim3(2,64), 256, 0, stream>>>(sA,256, WoT,256,
      bo, s, s2,256, 256);

  // --- v2X = v (interleaved resid) + tvXb @ WvoT ---
  gemm_kernel<2,4,0,1,1,0><<<dim3(1,768,1), 64, 0, stream>>>(tvXb,64,0,0, WvoT,64,0,0,
      nullptr, v,0,0,0, v2X,64,0,0, 64, 1, 1);

  // --- norm2 + FFN (tiled GEMMs) ---
  ln_kernel<<<8192, 256, 0, stream>>>(s2, g2, be2, sn);
  tgemm_kernel<1,0><<<dim3(8,64), 256, 0, stream>>>(sn,256, Wf1T,256,
      bf1, nullptr, h1,1024, 256);
  tgemm_kernel<0,1><<<dim3(2,64), 256, 0, stream>>>(h1,1024, Wf2T,1024,
      bf2, s2, outS,256, 1024);

  // --- vector FFN ---
  vnorm2_kernel<<<8192, 192, 0, stream>>>(v2X, vs2, vn2X);
  gemm_kernel<2,4,0,0,0,0><<<dim3(4,768,1), 64, 0, stream>>>(vn2X,64,0,0, Wfv1T,64,0,0,
      nullptr, nullptr,0,0,0, hv,256,0,0, 64, 1, 1);
  gemm_kernel<2,4,0,1,0,1><<<dim3(1,768,1), 64, 0, stream>>>(hv,256,0,0, Wfv2T,256,0,0,
      nullptr, v2X,64,0,0, outV,0,0,0, 256, 1, 1);
}

// Round 8
// 377.690 us; speedup vs baseline: 2.9100x; 1.0677x over previous
//
#include <hip/hip_runtime.h>
#include <hip/hip_bf16.h>

using bf16 = __hip_bfloat16;
typedef __attribute__((ext_vector_type(8))) short short8;
typedef __attribute__((ext_vector_type(4))) float float4v;
typedef __attribute__((ext_vector_type(16))) float f32x16;
typedef __attribute__((ext_vector_type(4))) unsigned uint4v;

__device__ __forceinline__ float b2f(bf16 x){ return __bfloat162float(x); }
__device__ __forceinline__ bf16  f2b(float x){ return __float2bfloat16(x); }
__device__ __forceinline__ bf16  tob(float x){ return f2b(x); }
__device__ __forceinline__ bf16  tob(bf16 x){ return x; }
__device__ __forceinline__ float frcp(float x){ return __builtin_amdgcn_rcpf(x); }
__device__ __forceinline__ float bs2f(short s){
  unsigned u = ((unsigned)(unsigned short)s) << 16;
  return __builtin_bit_cast(float, u);
}
__device__ __forceinline__ unsigned cvt_pk_bf16(float lo, float hi){
  unsigned r; asm("v_cvt_pk_bf16_f32 %0, %1, %2" : "=v"(r) : "v"(lo), "v"(hi)); return r;
}
__device__ __forceinline__ void plswap(unsigned &a, unsigned &b){
  asm("v_permlane32_swap_b32 %0, %1" : "+v"(a), "+v"(b));
}

#define EPSV 1e-5f
#define Z16 {0.f,0.f,0.f,0.f,0.f,0.f,0.f,0.f,0.f,0.f,0.f,0.f,0.f,0.f,0.f,0.f}

// ------------------------------------------------------------------
// pos prep: posf[r] = {x,y,z,|p|^2} fp32
// ------------------------------------------------------------------
__global__ __launch_bounds__(256) void pos_kernel(const float* __restrict__ pos,
                                                  float* __restrict__ posf, int rows){
  int r = blockIdx.x*256 + threadIdx.x;
  if (r >= rows) return;
  float x = pos[3*r], y = pos[3*r+1], z = pos[3*r+2];
  posf[4*r] = x; posf[4*r+1] = y; posf[4*r+2] = z; posf[4*r+3] = x*x + y*y + z*z;
}

// ------------------------------------------------------------------
// all 10 weight transposes (fp32 -> bf16) in ONE launch.
// ------------------------------------------------------------------
struct WTDesc { const float* src; bf16* dst; int rows, cols; };
struct WTPack { WTDesc d[10]; };

__global__ __launch_bounds__(256) void wtrans_kernel(WTPack p){
  WTDesc w = p.d[blockIdx.z];
  long r0 = (long)blockIdx.y*32, c0 = (long)blockIdx.x*32;
  if (r0 >= w.rows || c0 >= w.cols) return;
  __shared__ bf16 tile[32][33];
  int tx = threadIdx.x & 31, ty = threadIdx.x >> 5;
#pragma unroll
  for (int i = ty; i < 32; i += 8) tile[i][tx] = f2b(w.src[(r0+i)*w.cols + c0 + tx]);
  __syncthreads();
#pragma unroll
  for (int i = ty; i < 32; i += 8) w.dst[(c0+i)*w.rows + r0 + tx] = tile[tx][i];
}

// ------------------------------------------------------------------
// batched 32x32-tiled transpose (+ cast to bf16)
// ------------------------------------------------------------------
template<typename TI>
__global__ __launch_bounds__(256) void transpose_kernel(
    const TI* __restrict__ in, long ldin, long is1, long is2,
    bf16* __restrict__ out, long ldout, long os1, long os2, int Z2)
{
  int z = blockIdx.z, z1 = z / Z2, z2 = z - z1*Z2;
  in  += (long)z1*is1 + (long)z2*is2;
  out += (long)z1*os1 + (long)z2*os2;
  __shared__ bf16 tile[32][33];
  int tx = threadIdx.x & 31, ty = threadIdx.x >> 5;
  long r0 = (long)blockIdx.y*32, c0 = (long)blockIdx.x*32;
#pragma unroll
  for (int i = ty; i < 32; i += 8) tile[i][tx] = tob(in[(r0+i)*ldin + c0 + tx]);
  __syncthreads();
#pragma unroll
  for (int i = ty; i < 32; i += 8) out[(c0+i)*ldout + r0 + tx] = tile[tx][i];
}

// ------------------------------------------------------------------
// bias concat for fused QKV (+ zero the kmax accumulator)
// ------------------------------------------------------------------
__global__ __launch_bounds__(256) void bcat_kernel(const float* __restrict__ bq,
                                                   const float* __restrict__ bk,
                                                   const float* __restrict__ bv,
                                                   float* __restrict__ bqkv,
                                                   float* __restrict__ kmax){
  int j = blockIdx.x*256 + threadIdx.x;
  if (blockIdx.x == 0 && threadIdx.x < 16) kmax[threadIdx.x] = 0.f;
  if (j >= 768) return;
  bqkv[j] = (j < 256) ? bq[j] : (j < 512) ? bk[j-256] : bv[j-512];
}

// ------------------------------------------------------------------
// LayerNorm over S=256 per row (fp32 in -> bf16 out), wave-shuffle reduce
// ------------------------------------------------------------------
__global__ __launch_bounds__(256) void ln_kernel(const float* __restrict__ x,
                                                 const float* __restrict__ g,
                                                 const float* __restrict__ be,
                                                 bf16* __restrict__ out){
  const long row = blockIdx.x;
  const int t = threadIdx.x, lane = t & 63, wv = t >> 6;
  __shared__ float ws1[4], ws2[4];
  float v = x[(row<<8) + t];
  float s1 = v, s2 = v*v;
#pragma unroll
  for (int off=32; off; off>>=1){
    s1 += __shfl_xor(s1, off);
    s2 += __shfl_xor(s2, off);
  }
  if (lane == 0){ ws1[wv] = s1; ws2[wv] = s2; }
  __syncthreads();
  const float r1 = ws1[0]+ws1[1]+ws1[2]+ws1[3];
  const float r2 = ws2[0]+ws2[1]+ws2[2]+ws2[3];
  const float mu = r1 * (1.f/256.f);
  const float var = r2 * (1.f/256.f) - mu*mu;
  const float rstd = rsqrtf(fmaxf(var, 0.f) + EPSV);
  out[(row<<8)+t] = f2b((v-mu)*rstd*g[t] + be[t]);
}

// ------------------------------------------------------------------
// eq-norm 1: v (b,n,c,x) fp32 -> vnX[(b,n,x), c] bf16  (wave-reduce mean)
// ------------------------------------------------------------------
__global__ __launch_bounds__(192) void vnorm1_kernel(const float* __restrict__ vin,
                                                     const float* __restrict__ vs1,
                                                     bf16* __restrict__ vnX){
  const long row = blockIdx.x;
  const int t = threadIdx.x;
  __shared__ float vv[192], nrm[64];
  __shared__ float smean;
  vv[t] = vin[row*192 + t];
  __syncthreads();
  if (t < 64){                      // threads 0..63 = wave 0
    float a = vv[3*t], b = vv[3*t+1], c = vv[3*t+2];
    float nv = sqrtf(a*a + b*b + c*c);
    nrm[t] = nv;
    float s = nv;
#pragma unroll
    for (int off=32; off; off>>=1) s += __shfl_xor(s, off);
    if (t == 0) smean = s*(1.f/64.f);
  }
  __syncthreads();
  const int c = t/3, x = t - 3*c;
  const float val = vv[t] / (nrm[c] + EPSV) * smean * vs1[c];
  vnX[row*192 + x*64 + c] = f2b(val);
}

// ------------------------------------------------------------------
// eq-norm 2: v2X[(b,n), x*64+c] fp32 -> vn2X same layout bf16
// ------------------------------------------------------------------
__global__ __launch_bounds__(192) void vnorm2_kernel(const float* __restrict__ v2X,
                                                     const float* __restrict__ vs2,
                                                     bf16* __restrict__ vn2X){
  const long row = blockIdx.x;
  const int t = threadIdx.x;
  __shared__ float vv[192], nrm[64];
  __shared__ float smean;
  vv[t] = v2X[row*192 + t];
  __syncthreads();
  if (t < 64){
    float a = vv[t], b = vv[t+64], c = vv[t+128];
    float nv = sqrtf(a*a + b*b + c*c);
    nrm[t] = nv;
    float s = nv;
#pragma unroll
    for (int off=32; off; off>>=1) s += __shfl_xor(s, off);
    if (t == 0) smean = s*(1.f/64.f);
  }
  __syncthreads();
  const int c = t & 63;
  vn2X[row*192 + t] = f2b(vv[t] / (nrm[c] + EPSV) * smean * vs2[c]);
}

// ------------------------------------------------------------------
// per-(b,h) max ||k||^2 via atomicMax (uint order == float order, >=0).
// ------------------------------------------------------------------
__global__ __launch_bounds__(256) void knorm_kernel(const bf16* __restrict__ qkv,
                                                    float* __restrict__ kmax){
  const int bh = blockIdx.x, b = bh>>2, h = bh&3;
  const int t = threadIdx.x, lane = t & 63, wv = t >> 6;
  __shared__ float red[4];
  long row = (long)b*2048 + (long)blockIdx.y*256 + t;
  const short8* kp = (const short8*)(qkv + row*768 + 256 + h*64);
  float ss = 0.f;
#pragma unroll
  for (int c=0;c<8;c++){
    short8 v = kp[c];
#pragma unroll
    for (int j=0;j<8;j++){ float f = bs2f(v[j]); ss = fmaf(f,f,ss); }
  }
#pragma unroll
  for (int off=32; off; off>>=1) ss = fmaxf(ss, __shfl_xor(ss, off));
  if (lane == 0) red[wv] = ss;
  __syncthreads();
  if (t == 0){
    float m = fmaxf(fmaxf(red[0],red[1]), fmaxf(red[2],red[3]));
    atomicMax((unsigned*)&kmax[bh], __float_as_uint(m));
  }
}

// ------------------------------------------------------------------
// FUSED ATTENTION, 8-wave m-split (2 groups x 4 q-waves, 2 waves/SIMD):
//   round-5 benched structure: 116.7 us, VGPR 124. DO NOT raise
//   occupancy: 3 waves/SIMD caps regs at ~170 < ~200 live state ->
//   scratch spill (rounds 4 & 6, both ~8x slower).
// ------------------------------------------------------------------
#define ATT_K_OFF   0
#define ATT_V_OFF   4096
#define ATT_X_OFF   9216
#define ATT_P_OFF   24576
#define ATT_TILE    25088
#define ATT_GRP     50176          // 2 dbuf per group
#define ATT_LACC    98304          // 8*64 floats = 2048 B
#define ATT_SMEM    100352

__global__ __launch_bounds__(512, 2) void attn_kernel(
    const bf16* __restrict__ qkv,    // [8192][768] (Q|K|V, 4 heads x 64)
    const bf16* __restrict__ vsT,    // [b][h][64][2048]
    const bf16* __restrict__ vmixT,  // [b][192][2048]
    const float* __restrict__ posf,  // [b][2048][4]
    const float* __restrict__ kmaxA, // [16] max ||k||^2
    const float* __restrict__ w_dist, const float* __restrict__ b_dist,
    bf16* __restrict__ sA,           // [8192][256]
    bf16* __restrict__ slab)         // [4][8192][192]
{
  __shared__ __align__(16) char smem[ATT_SMEM];
  const int qb = blockIdx.x;         // 0..15
  const int bh = blockIdx.y;         // 0..15
  const int b  = bh >> 2, h = bh & 3;
  const int tid = threadIdx.x;
  const int w = tid >> 6, lane = tid & 63;
  const int g = w >> 2, qw = w & 3;
  const int lq = lane & 31, hi = lane >> 5;
  const int gtid = tid & 255;

  const int qloc = qb*128 + qw*32 + lq;
  const long rowQ = (long)b*2048 + qloc;

  // Q fragments (B operand): col=q (lane&31), k=d = kc*16 + hi*8 + j
  short8 qf[4];
  {
    const bf16* qp = qkv + rowQ*768 + h*64 + hi*8;
#pragma unroll
    for (int kc=0;kc<4;kc++) qf[kc] = *(const short8*)(qp + kc*16);
  }
  // stabilizer: sqrt(|q|^2 * max|k|^2) / 8  (>= max_m qk/8; bias only subtracts)
  float q2 = 0.f;
#pragma unroll
  for (int kc=0;kc<4;kc++)
#pragma unroll
    for (int j=0;j<8;j++){ float qv = bs2f(qf[kc][j]); q2 = fmaf(qv,qv,q2); }
  q2 += __shfl_xor(q2, 32);
  const float mxs = sqrtf(q2 * kmaxA[bh]) * 0.125f;
  const float wh = w_dist[h], bhd = b_dist[h];
  const float4v pn = *(const float4v*)(posf + (long)b*8192 + (long)qloc*4);
  const float m2x = -2.f*pn[0], m2y = -2.f*pn[1], m2z = -2.f*pn[2], pnw = pn[3];

  f32x16 O[2]  = {Z16, Z16};
  f32x16 VM[6] = {Z16, Z16, Z16, Z16, Z16, Z16};
  float lacc = 0.f;

  // per-group staging (256 threads, 20.5 KB/tile)
  short8 stK, stV, stX0, stX1, stX2; float4v stP;
  const int sm = gtid >> 3, sc = gtid & 7;   // K: row(32) x chunk(8)
  const int vd = gtid >> 2, vc = gtid & 3;   // V/X: row x chunk(4)
  const bf16* Kg = qkv + (long)b*2048*768 + 256 + h*64;
  const bf16* Vg = vsT + (long)b*524288 + (long)h*131072;
  const bf16* Xg = vmixT + (long)b*393216;
  const float* Pg = posf + (long)b*8192;
  char* gbase = smem + g*ATT_GRP;

  auto LOADT = [&](int m0){
    stK  = *(const short8*)(Kg + (long)(m0+sm)*768 + sc*8);
    stV  = *(const short8*)(Vg + (long)vd*2048 + m0 + vc*8);
    stX0 = *(const short8*)(Xg + (long)vd*2048 + m0 + vc*8);
    stX1 = *(const short8*)(Xg + (long)(64+vd)*2048 + m0 + vc*8);
    stX2 = *(const short8*)(Xg + (long)(128+vd)*2048 + m0 + vc*8);
    if (gtid < 32) stP = *(const float4v*)(Pg + (long)(m0+gtid)*4);
  };
  auto WRITET = [&](char* buf){
    *(short8*)(buf + ATT_K_OFF + sm*128 + ((sc ^ (sm&7))<<4)) = stK;   // XOR-swizzle
    *(short8*)(buf + ATT_V_OFF + vd*80 + vc*16) = stV;
    *(short8*)(buf + ATT_X_OFF + vd*80 + vc*16) = stX0;
    *(short8*)(buf + ATT_X_OFF + (64+vd)*80 + vc*16) = stX1;
    *(short8*)(buf + ATT_X_OFF + (128+vd)*80 + vc*16) = stX2;
    if (gtid < 32) *(float4v*)(buf + ATT_P_OFF + gtid*16) = stP;
  };

  auto COMPUTE = [&](const char* buf){
    const char* Kb = buf + ATT_K_OFF;
    const char* Vb = buf + ATT_V_OFF;
    const char* Xb = buf + ATT_X_OFF;
    const float4v* pmb = (const float4v*)(buf + ATT_P_OFF);
    // swapped QK^T: S[m][q], col = lane&31 = q
    f32x16 S = Z16;
#pragma unroll
    for (int kc=0;kc<4;kc++){
      short8 kf = *(const short8*)(Kb + lq*128 + (((kc*2+hi) ^ (lq&7))<<4));
      S = __builtin_amdgcn_mfma_f32_32x32x16_bf16(kf, qf[kc], S, 0, 0, 0);
    }
    // dist bias + exp (unnormalized, fixed stabilizer); m = i + 8gg + 4hi
    float P[16];
#pragma unroll
    for (int gg=0; gg<4; gg++){
#pragma unroll
      for (int i=0;i<4;i++){
        float4v pm = pmb[gg*8 + hi*4 + i];
        float d2 = fmaf(m2x, pm[0], fmaf(m2y, pm[1], fmaf(m2z, pm[2], pnw + pm[3])));
        float dist = sqrtf(fmaxf(d2, 1e-12f));
        float sig = frcp(1.f + __expf(fmaf(dist, wh, bhd)));
        float p = __expf(fmaf(S[gg*4+i], 0.125f, -mxs)) * sig;
        lacc += p;
        P[gg*4+i] = p;
      }
    }
    // P -> bf16 B-operand (col=q, k=m) via cvt_pk + permlane32_swap
    unsigned pk[8];
#pragma unroll
    for (int t=0;t<8;t++) pk[t] = cvt_pk_bf16(P[2*t], P[2*t+1]);
    plswap(pk[0], pk[2]); plswap(pk[1], pk[3]);   // chunk0: m 0..15
    plswap(pk[4], pk[6]); plswap(pk[5], pk[7]);   // chunk1: m 16..31
    uint4v y0v = {pk[0], pk[1], pk[2], pk[3]};
    uint4v y1v = {pk[4], pk[5], pk[6], pk[7]};
    short8 Y0 = __builtin_bit_cast(short8, y0v);
    short8 Y1 = __builtin_bit_cast(short8, y1v);
    // PV: O^T[d][q] += V^T[d][m] * P[q][m]
#pragma unroll
    for (int dblk=0; dblk<2; dblk++){
      short8 v0 = *(const short8*)(Vb + (dblk*32+lq)*80 + hi*16);
      short8 v1 = *(const short8*)(Vb + (dblk*32+lq)*80 + 32 + hi*16);
      O[dblk] = __builtin_amdgcn_mfma_f32_32x32x16_bf16(v0, Y0, O[dblk], 0,0,0);
      O[dblk] = __builtin_amdgcn_mfma_f32_32x32x16_bf16(v1, Y1, O[dblk], 0,0,0);
    }
    // vmix: VM^T[e][q] += vmix^T[e][m] * P[q][m]
#pragma unroll
    for (int eblk=0; eblk<6; eblk++){
      short8 x0 = *(const short8*)(Xb + (eblk*32+lq)*80 + hi*16);
      short8 x1 = *(const short8*)(Xb + (eblk*32+lq)*80 + 32 + hi*16);
      VM[eblk] = __builtin_amdgcn_mfma_f32_32x32x16_bf16(x0, Y0, VM[eblk], 0,0,0);
      VM[eblk] = __builtin_amdgcn_mfma_f32_32x32x16_bf16(x1, Y1, VM[eblk], 0,0,0);
    }
  };

  // group g computes tiles g, g+2, ..., g+62 (32 tiles each)
  LOADT(g*32);
  WRITET(gbase);
  __syncthreads();
#pragma unroll 1
  for (int i=0; i<32; ++i){
    if (i < 31) LOADT((2*(i+1)+g)*32);
    COMPUTE(gbase + (i&1)*ATT_TILE);
    if (i < 31) WRITET(gbase + ((i+1)&1)*ATT_TILE);
    __syncthreads();
  }

  // ---------------- cross-group combine (odd strides: conflict-free) ----------------
  float* laccT = (float*)(smem + ATT_LACC);
  laccT[w*64 + lane] = lacc;
  if (g == 1){                       // group 1 exports O (stride 33 floats)
    float* Od = (float*)(smem + ATT_GRP) + (qw*64+lane)*33;
#pragma unroll
    for (int r=0;r<16;r++){ Od[r] = O[0][r]; Od[16+r] = O[1][r]; }
  }
  __syncthreads();
  const float lsum = laccT[qw*64+lq] + laccT[qw*64+32+lq]
                   + laccT[(4+qw)*64+lq] + laccT[(4+qw)*64+32+lq];
  if (g == 0){                       // group 0 accumulates full O
    const float* Od = (const float*)(smem + ATT_GRP) + (qw*64+lane)*33;
#pragma unroll
    for (int r=0;r<16;r++){ O[0][r] += Od[r]; O[1][r] += Od[16+r]; }
  }
  __syncthreads();
  // VM in two halves (stride 49 floats; each half fits the 50176 B group-0 area)
#pragma unroll
  for (int hf=0; hf<2; hf++){
    if (g == 0){                     // group 0 exports VM half
      float* Vd = (float*)smem + (qw*64+lane)*49;
#pragma unroll
      for (int e=0;e<3;e++)
#pragma unroll
        for (int r=0;r<16;r++) Vd[e*16+r] = VM[hf*3+e][r];
    }
    __syncthreads();
    if (g == 1){                     // group 1 accumulates full VM
      const float* Vd = (const float*)smem + (qw*64+lane)*49;
#pragma unroll
      for (int e=0;e<3;e++)
#pragma unroll
        for (int r=0;r<16;r++) VM[hf*3+e][r] += Vd[e*16+r];
    }
    __syncthreads();
  }

  // ---------------- parallel epilogue ----------------
  const float sinv = frcp(lsum);
  if (g == 0){
    // s_attn: transpose O^T[d][q] -> [q][64d] via LDS (pitch 136B)
    char* scr = smem + qw*12544;
#pragma unroll
    for (int dblk=0; dblk<2; dblk++)
#pragma unroll
      for (int pp=0; pp<8; pp++){
        const int r = 2*pp;
        const int d = dblk*32 + (r&3) + 8*(r>>2) + 4*hi;
        unsigned u = cvt_pk_bf16(O[dblk][r]*sinv, O[dblk][r+1]*sinv);
        *(unsigned*)(scr + lq*136 + d*2) = u;
      }
  } else {
    // vmix: transpose VM^T[e][q] -> [q][192e] via LDS (pitch 392B)
    const float vinv = 0.25f * sinv;
    char* scr = smem + ATT_GRP + qw*12544;
#pragma unroll
    for (int eblk=0; eblk<6; eblk++)
#pragma unroll
      for (int pp=0; pp<8; pp++){
        const int r = 2*pp;
        const int e = eblk*32 + (r&3) + 8*(r>>2) + 4*hi;
        unsigned u = cvt_pk_bf16(VM[eblk][r]*vinv, VM[eblk][r+1]*vinv);
        *(unsigned*)(scr + lq*392 + e*2) = u;
      }
  }
  __syncthreads();
  if (g == 0){
    const char* scr = smem + qw*12544;
    const int q = lane >> 1, half = lane & 1;
    const char* src = scr + q*136 + half*64;
    char* dst = (char*)(sA + (long)(b*2048 + qb*128 + qw*32 + q)*256 + h*64 + half*32);
#pragma unroll
    for (int i=0;i<8;i++)
      *(unsigned long long*)(dst + i*8) = *(const unsigned long long*)(src + i*8);
  } else {
    const char* scr = smem + ATT_GRP + qw*12544;
    const int q = lane >> 1, half = lane & 1;
    const char* src = scr + q*392 + half*192;
    char* dst = (char*)(slab + (long)h*1572864
                        + (long)(b*2048 + qb*128 + qw*32 + q)*192 + half*96);
#pragma unroll
    for (int i=0;i<24;i++)
      *(unsigned long long*)(dst + i*8) = *(const unsigned long long*)(src + i*8);
  }
}

// ------------------------------------------------------------------
// reduce 4 per-head slabs (already scaled by 1/(4 l_h)) -> tvXb bf16
// ------------------------------------------------------------------
__global__ __launch_bounds__(256) void hred_kernel(const bf16* __restrict__ slab,
                                                   bf16* __restrict__ out){
  long i = (long)blockIdx.x*256 + threadIdx.x;   // over 196608 short8s
  if (i >= 196608) return;
  const short8* s0 = (const short8*)slab + i;
  short8 a = s0[0], b = s0[196608], c = s0[2*196608], d = s0[3*196608];
  short8 o;
#pragma unroll
  for (int j=0;j<8;j++){
    float f = bs2f(a[j]) + bs2f(b[j]) + bs2f(c[j]) + bs2f(d[j]);
    bf16 hv = f2b(f); o[j] = *(short*)&hv;
  }
  ((short8*)out)[i] = o;
}

// ------------------------------------------------------------------
// TILED GEMM 64x128: 256 thr = 4 waves side-by-side, each 64 rows x 32
// cols (4 m-frags x 2 n-frags, acc = 32 VGPR). BK=32 double-buffered
// LDS (24.6 KB) -> ~6 blocks/CU. Linear LDS: A[64][32], B[128][32];
// staging and frag reads both tile contiguous 1 KB/wave regions ->
// conflict-free. Requires M%64==0, N%128==0, K%32==0.
// ------------------------------------------------------------------
template<int ACT, int OUTM>
__global__ __launch_bounds__(256) void tgemm64_kernel(
    const bf16* __restrict__ A, long lda,
    const bf16* __restrict__ BT, long ldb,
    const float* __restrict__ bias,
    const float* __restrict__ resid,   // fp32, same ld as C
    void* __restrict__ Cv, long ldc,
    int K)
{
  __shared__ __align__(16) bf16 As[2][64*32];
  __shared__ __align__(16) bf16 Bs[2][128*32];
  const int tid = threadIdx.x;
  const int wc = tid >> 6, lane = tid & 63;
  const int col = lane & 15, quad = lane >> 4;
  const long rowA0 = (long)blockIdx.y*64;
  const long colB0 = (long)blockIdx.x*128;

  const int tr = tid >> 2, tc = tid & 3;
  const bf16* Ag = A + (rowA0 + tr)*lda + tc*8;
  const bf16* Bg = BT + (colB0 + tr)*ldb + tc*8;

  short8 sa, sb[2];
  auto LOAD = [&](int k0){
    sa = *(const short8*)(Ag + k0);
    sb[0] = *(const short8*)(Bg + k0);
    sb[1] = *(const short8*)(Bg + (long)64*ldb + k0);
  };
  auto STORE = [&](int buf){
    *(short8*)(&As[buf][tr*32 + tc*8]) = sa;
    *(short8*)(&Bs[buf][tr*32 + tc*8]) = sb[0];
    *(short8*)(&Bs[buf][(tr+64)*32 + tc*8]) = sb[1];
  };

  float4v acc[4][2];
#pragma unroll
  for (int m=0;m<4;m++)
#pragma unroll
    for (int n=0;n<2;n++) acc[m][n] = (float4v){0.f,0.f,0.f,0.f};

  LOAD(0); STORE(0);
  __syncthreads();
  const int nk = K >> 5;
#pragma unroll 1
  for (int ks=0; ks<nk; ++ks){
    if (ks+1 < nk) LOAD((ks+1)*32);
    const bf16* Ab = &As[ks&1][col*32 + quad*8];
    const bf16* Bb = &Bs[ks&1][(wc*32 + col)*32 + quad*8];
    short8 af[4], bfv[2];
#pragma unroll
    for (int m=0;m<4;m++) af[m] = *(const short8*)(Ab + m*16*32);
#pragma unroll
    for (int n=0;n<2;n++) bfv[n] = *(const short8*)(Bb + n*16*32);
#pragma unroll
    for (int m=0;m<4;m++)
#pragma unroll
      for (int n=0;n<2;n++)
        acc[m][n] = __builtin_amdgcn_mfma_f32_16x16x32_bf16(af[m], bfv[n], acc[m][n], 0, 0, 0);
    if (ks+1 < nk) STORE((ks+1)&1);
    __syncthreads();
  }

  // epilogue
#pragma unroll
  for (int m=0;m<4;m++){
    const long ci0 = rowA0 + m*16 + quad*4;
#pragma unroll
    for (int n=0;n<2;n++){
      const long cj = colB0 + wc*32 + n*16 + col;
      const float bbias = bias ? bias[cj] : 0.f;
#pragma unroll
      for (int r=0;r<4;r++){
        const long ci = ci0 + r;
        float val = acc[m][n][r] + bbias;
        if (ACT == 1) val = 0.5f*val*(1.f + erff(val*0.70710678118654752f));
        if (resid) val += resid[ci*ldc + cj];
        if (OUTM == 0) ((bf16*)Cv)[ci*ldc + cj] = f2b(val);
        else           ((float*)Cv)[ci*ldc + cj] = val;
      }
    }
  }
}

// ------------------------------------------------------------------
// simple MFMA GEMM (small shapes: K=64 / N=64 paths)
// ------------------------------------------------------------------
template<int MT, int NT, int ACT, int OUTM, int RXIL, int CXIL>
__global__ __launch_bounds__(64) void gemm_kernel(
    const bf16* __restrict__ A, long lda, long As1, long As2,
    const bf16* __restrict__ BT, long ldb, long Bs1, long Bs2,
    const float* __restrict__ bias,
    const float* __restrict__ resid, long ldr, long Rs1, long Rs2,
    void* __restrict__ Cv, long ldc, long Cs1, long Cs2,
    int K, int Z2, int KS)
{
  int z = blockIdx.z;
  int zz = z / KS, ks = z - zz*KS;
  int z1 = zz / Z2, z2 = zz - z1*Z2;
  A  += (long)z1*As1 + (long)z2*As2 + (long)ks*K;
  BT += (long)z1*Bs1 + (long)z2*Bs2 + (long)ks*K;
  if (resid) resid += (long)z1*Rs1 + (long)z2*Rs2;
  const long cbase = (long)z1*Cs1 + (long)z2*Cs2;

  const int lane = threadIdx.x;
  const int col = lane & 15, quad = lane >> 4;
  const long rowA0 = (long)blockIdx.y*(16*MT);
  const long colB0 = (long)blockIdx.x*(16*NT);

  float4v acc[MT][NT];
#pragma unroll
  for (int m=0;m<MT;m++)
#pragma unroll
    for (int n=0;n<NT;n++) acc[m][n] = (float4v){0.f,0.f,0.f,0.f};

  const bf16* ap[MT];
  const bf16* bp[NT];
#pragma unroll
  for (int m=0;m<MT;m++) ap[m] = A + (rowA0 + m*16 + col)*lda + quad*8;
#pragma unroll
  for (int n=0;n<NT;n++) bp[n] = BT + (colB0 + n*16 + col)*ldb + quad*8;

  for (int k0 = 0; k0 < K; k0 += 32){
    short8 a[MT], bb[NT];
#pragma unroll
    for (int m=0;m<MT;m++){ a[m] = *(const short8*)ap[m]; ap[m] += 32; }
#pragma unroll
    for (int n=0;n<NT;n++){ bb[n] = *(const short8*)bp[n]; bp[n] += 32; }
#pragma unroll
    for (int m=0;m<MT;m++)
#pragma unroll
      for (int n=0;n<NT;n++)
        acc[m][n] = __builtin_amdgcn_mfma_f32_16x16x32_bf16(a[m], bb[n], acc[m][n], 0, 0, 0);
  }

#pragma unroll
  for (int m=0;m<MT;m++){
    const long ri = rowA0 + m*16 + quad*4;
#pragma unroll
    for (int n=0;n<NT;n++){
      const long cj = colB0 + n*16 + col;
      const float bbias = bias ? bias[cj] : 0.f;
#pragma unroll
      for (int r=0;r<4;r++){
        const long ci = ri + r;
        float val = acc[m][n][r] + bbias;
        if (ACT == 1) val = 0.5f*val*(1.f + erff(val*0.70710678118654752f));
        if (resid){
          const long raddr = RXIL ? ((ci/3)*192 + cj*3 + (ci%3)) : (ci*ldr + cj);
          val += resid[raddr];
        }
        const long caddr = CXIL ? (cbase + (ci/3)*192 + cj*3 + (ci%3))
                                : (cbase + ci*ldc + cj);
        if (OUTM == 0)      ((bf16*)Cv)[caddr] = f2b(val);
        else if (OUTM == 1) ((float*)Cv)[caddr] = val;
        else                unsafeAtomicAdd(&((float*)Cv)[caddr], val);
      }
    }
  }
}

// ------------------------------------------------------------------
extern "C" void kernel_launch(void* const* d_in, const int* in_sizes, int n_in,
                              void* d_out, int out_size, void* d_ws, size_t ws_size,
                              hipStream_t stream)
{
  const float* s    = (const float*)d_in[0];
  const float* v    = (const float*)d_in[1];
  const float* pos  = (const float*)d_in[2];
  const float* Wq   = (const float*)d_in[3];
  const float* bq   = (const float*)d_in[4];
  const float* Wk   = (const float*)d_in[5];
  const float* bk   = (const float*)d_in[6];
  const float* Wv   = (const float*)d_in[7];
  const float* bv   = (const float*)d_in[8];
  const float* Wo   = (const float*)d_in[9];
  const float* bo   = (const float*)d_in[10];
  const float* w_d  = (const float*)d_in[11];
  const float* b_d  = (const float*)d_in[12];
  const float* Wvv  = (const float*)d_in[13];
  const float* Wvo  = (const float*)d_in[14];
  const float* g1   = (const float*)d_in[15];
  const float* be1  = (const float*)d_in[16];
  const float* vs1  = (const float*)d_in[17];
  const float* g2   = (const float*)d_in[18];
  const float* be2  = (const float*)d_in[19];
  const float* vs2  = (const float*)d_in[20];
  const float* Wf1  = (const float*)d_in[21];
  const float* bf1  = (const float*)d_in[22];
  const float* Wf2  = (const float*)d_in[23];
  const float* bf2  = (const float*)d_in[24];
  const float* Wfv1 = (const float*)d_in[25];
  const float* Wfv2 = (const float*)d_in[26];

  float* outS = (float*)d_out;
  float* outV = outS + (size_t)4*2048*256;

  char* w = (char*)d_ws;
  size_t o = 0;
  auto alloc = [&](size_t bytes)->char* {
    char* p = w + o;
    o = (o + bytes + 255) & ~(size_t)255;
    return p;
  };
  float* posf  = (float*)alloc(131072);
  bf16* WqkvT = (bf16*)alloc(393216);       // 768 x 256
  bf16* WoT   = (bf16*)alloc(131072);
  bf16* Wf1T  = (bf16*)alloc(524288);
  bf16* Wf2T  = (bf16*)alloc(524288);
  bf16* WvvT  = (bf16*)alloc(8192);
  bf16* WvoT  = (bf16*)alloc(8192);
  bf16* Wfv1T = (bf16*)alloc(32768);
  bf16* Wfv2T = (bf16*)alloc(32768);
  float* bqkv = (float*)alloc(3072);
  float* kmax = (float*)alloc(64);
  bf16* sn    = (bf16*)alloc(4194304);      // reused for sn2
  bf16* qkv   = (bf16*)alloc(12582912);     // 8192 x 768; later alias: hv
  bf16* vsT   = (bf16*)alloc(4194304);
  bf16* sA    = (bf16*)alloc(4194304);
  float* s2   = (float*)alloc(8388608);
  bf16* vnX   = (bf16*)alloc(3145728);      // later alias: vn2X
  bf16* vmixX = (bf16*)alloc(3145728);      // later alias: tvXb
  bf16* vmixXT= (bf16*)alloc(3145728);      // (b, 192, 2048)
  float* v2X  = (float*)alloc(6291456);
  bf16* slab  = (bf16*)alloc(12582912);     // 4 x 8192 x 192
  bf16* h1    = (bf16*)alloc(16777216);     // 8192 x 1024
  bf16* vn2X  = vnX;
  bf16* tvXb  = vmixX;
  bf16* hv    = qkv;                        // qkv dead after attention
  if (o > ws_size) return;

  // --- prep ---
  pos_kernel<<<32, 256, 0, stream>>>(pos, posf, 8192);
  WTPack pk;
  pk.d[0] = {Wq,   WqkvT,          256, 256};
  pk.d[1] = {Wk,   WqkvT + 65536,  256, 256};
  pk.d[2] = {Wv,   WqkvT + 131072, 256, 256};
  pk.d[3] = {Wo,   WoT,            256, 256};
  pk.d[4] = {Wf1,  Wf1T,           256, 1024};
  pk.d[5] = {Wf2,  Wf2T,           1024, 256};
  pk.d[6] = {Wvv,  WvvT,           64, 64};
  pk.d[7] = {Wvo,  WvoT,           64, 64};
  pk.d[8] = {Wfv1, Wfv1T,          64, 256};
  pk.d[9] = {Wfv2, Wfv2T,          256, 64};
  wtrans_kernel<<<dim3(32,32,10), 256, 0, stream>>>(pk);
  bcat_kernel<<<3, 256, 0, stream>>>(bq, bk, bv, bqkv, kmax);

  // --- norm1 (scalar + vector) ---
  ln_kernel<<<8192, 256, 0, stream>>>(s, g1, be1, sn);
  vnorm1_kernel<<<8192, 192, 0, stream>>>(v, vs1, vnX);

  // --- vmixX = vnX @ WvvT, then per-b transpose -> vmixXT ---
  gemm_kernel<2,4,0,0,0,0><<<dim3(1,768,1), 64, 0, stream>>>(vnX,64,0,0, WvvT,64,0,0,
      nullptr, nullptr,0,0,0, vmixX,64,0,0, 64, 1, 1);
  transpose_kernel<bf16><<<dim3(6,64,4), 256, 0, stream>>>(vmixX, 192, 393216,0,
      vmixXT, 2048, 393216,0, 1);

  // --- fused QKV projection (64x128 tiles) ---
  tgemm64_kernel<0,0><<<dim3(6,128), 256, 0, stream>>>(sn,256, WqkvT,256,
      bqkv, nullptr, qkv,768, 256);
  transpose_kernel<bf16><<<dim3(2,64,16), 256, 0, stream>>>(qkv+512, 768, 1572864,64,
      vsT, 2048, 524288,131072, 4);

  // --- stabilizer prepass + fully fused attention ---
  knorm_kernel<<<dim3(16,8), 256, 0, stream>>>(qkv, kmax);
  attn_kernel<<<dim3(16,16), 512, 0, stream>>>(qkv, vsT, vmixXT, posf, kmax,
      w_d, b_d, sA, slab);
  hred_kernel<<<768, 256, 0, stream>>>(slab, tvXb);

  // --- output projection + residual: s2 = s + sA@Wo + bo (fp32) ---
  tgemm64_kernel<0,1><<<dim3(2,128), 256, 0, stream>>>(sA,256, WoT,256,
      bo, s, s2,256, 256);

  // --- v2X = v (interleaved resid) + tvXb @ WvoT ---
  gemm_kernel<2,4,0,1,1,0><<<dim3(1,768,1), 64, 0, stream>>>(tvXb,64,0,0, WvoT,64,0,0,
      nullptr, v,0,0,0, v2X,64,0,0, 64, 1, 1);

  // --- norm2 + FFN ---
  ln_kernel<<<8192, 256, 0, stream>>>(s2, g2, be2, sn);
  tgemm64_kernel<1,0><<<dim3(8,128), 256, 0, stream>>>(sn,256, Wf1T,256,
      bf1, nullptr, h1,1024, 256);
  tgemm64_kernel<0,1><<<dim3(2,128), 256, 0, stream>>>(h1,1024, Wf2T,1024,
      bf2, s2, outS,256, 1024);

  // --- vector FFN ---
  vnorm2_kernel<<<8192, 192, 0, stream>>>(v2X, vs2, vn2X);
  tgemm64_kernel<0,0><<<dim3(2,384), 256, 0, stream>>>(vn2X,64, Wfv1T,64,
      nullptr, nullptr, hv,256, 64);
  gemm_kernel<2,4,0,1,0,1><<<dim3(1,768,1), 64, 0, stream>>>(hv,256,0,0, Wfv2T,256,0,0,
      nullptr, v2X,64,0,0, outV,0,0,0, 256, 1, 1);
}

// Round 9
// 373.525 us; speedup vs baseline: 2.9425x; 1.0112x over previous
//
#include <hip/hip_runtime.h>
#include <hip/hip_bf16.h>

using bf16 = __hip_bfloat16;
typedef __attribute__((ext_vector_type(8))) short short8;
typedef __attribute__((ext_vector_type(4))) float float4v;
typedef __attribute__((ext_vector_type(16))) float f32x16;
typedef __attribute__((ext_vector_type(4))) unsigned uint4v;

__device__ __forceinline__ float b2f(bf16 x){ return __bfloat162float(x); }
__device__ __forceinline__ bf16  f2b(float x){ return __float2bfloat16(x); }
__device__ __forceinline__ bf16  tob(float x){ return f2b(x); }
__device__ __forceinline__ bf16  tob(bf16 x){ return x; }
__device__ __forceinline__ float frcp(float x){ return __builtin_amdgcn_rcpf(x); }
__device__ __forceinline__ float bs2f(short s){
  unsigned u = ((unsigned)(unsigned short)s) << 16;
  return __builtin_bit_cast(float, u);
}
__device__ __forceinline__ unsigned cvt_pk_bf16(float lo, float hi){
  unsigned r; asm("v_cvt_pk_bf16_f32 %0, %1, %2" : "=v"(r) : "v"(lo), "v"(hi)); return r;
}
__device__ __forceinline__ void plswap(unsigned &a, unsigned &b){
  asm("v_permlane32_swap_b32 %0, %1" : "+v"(a), "+v"(b));
}

#define EPSV 1e-5f
#define Z16 {0.f,0.f,0.f,0.f,0.f,0.f,0.f,0.f,0.f,0.f,0.f,0.f,0.f,0.f,0.f,0.f}

// ------------------------------------------------------------------
// all 10 weight transposes (fp32 -> bf16) + pos prep + bias concat
// in ONE launch (z==10 handles pos/bcat/kmax-zero).
// ------------------------------------------------------------------
struct WTDesc { const float* src; bf16* dst; int rows, cols; };
struct WTPack { WTDesc d[10]; };

__global__ __launch_bounds__(256) void wtrans_kernel(WTPack p,
    const float* __restrict__ pos, float* __restrict__ posf,
    const float* __restrict__ bq, const float* __restrict__ bk,
    const float* __restrict__ bv, float* __restrict__ bqkv,
    float* __restrict__ kmax){
  const int t = threadIdx.x;
  if (blockIdx.z == 10){
    if (blockIdx.y == 0 && blockIdx.x < 32){
      int r = blockIdx.x*256 + t;
      float x = pos[3*r], y = pos[3*r+1], z = pos[3*r+2];
      posf[4*r] = x; posf[4*r+1] = y; posf[4*r+2] = z; posf[4*r+3] = x*x + y*y + z*z;
    } else if (blockIdx.y == 1 && blockIdx.x < 3){
      int j = blockIdx.x*256 + t;
      if (blockIdx.x == 0 && t < 16) kmax[t] = 0.f;
      bqkv[j] = (j < 256) ? bq[j] : (j < 512) ? bk[j-256] : bv[j-512];
    }
    return;
  }
  WTDesc w = p.d[blockIdx.z];
  long r0 = (long)blockIdx.y*32, c0 = (long)blockIdx.x*32;
  if (r0 >= w.rows || c0 >= w.cols) return;
  __shared__ bf16 tile[32][33];
  int tx = t & 31, ty = t >> 5;
#pragma unroll
  for (int i = ty; i < 32; i += 8) tile[i][tx] = f2b(w.src[(r0+i)*w.cols + c0 + tx]);
  __syncthreads();
#pragma unroll
  for (int i = ty; i < 32; i += 8) w.dst[(c0+i)*w.rows + r0 + tx] = tile[tx][i];
}

// ------------------------------------------------------------------
// batched 32x32-tiled transpose (+ cast to bf16)
// ------------------------------------------------------------------
template<typename TI>
__global__ __launch_bounds__(256) void transpose_kernel(
    const TI* __restrict__ in, long ldin, long is1, long is2,
    bf16* __restrict__ out, long ldout, long os1, long os2, int Z2)
{
  int z = blockIdx.z, z1 = z / Z2, z2 = z - z1*Z2;
  in  += (long)z1*is1 + (long)z2*is2;
  out += (long)z1*os1 + (long)z2*os2;
  __shared__ bf16 tile[32][33];
  int tx = threadIdx.x & 31, ty = threadIdx.x >> 5;
  long r0 = (long)blockIdx.y*32, c0 = (long)blockIdx.x*32;
#pragma unroll
  for (int i = ty; i < 32; i += 8) tile[i][tx] = tob(in[(r0+i)*ldin + c0 + tx]);
  __syncthreads();
#pragma unroll
  for (int i = ty; i < 32; i += 8) out[(c0+i)*ldout + r0 + tx] = tile[tx][i];
}

// ------------------------------------------------------------------
// fused vsT transpose (z<16) + knorm (z==16): both consume qkv.
// knorm: per-(b,h) max ||k||^2 via atomicMax (uint order==float, >=0).
// ------------------------------------------------------------------
__global__ __launch_bounds__(256) void trk_kernel(const bf16* __restrict__ qkv,
                                                  bf16* __restrict__ vsT,
                                                  float* __restrict__ kmax){
  const int t = threadIdx.x;
  if (blockIdx.z < 16){
    int z = blockIdx.z, z1 = z >> 2, z2 = z & 3;   // b, h
    const bf16* in = qkv + 512 + (long)z1*1572864 + (long)z2*64;
    bf16* out = vsT + (long)z1*524288 + (long)z2*131072;
    __shared__ bf16 tile[32][33];
    int tx = t & 31, ty = t >> 5;
    long r0 = (long)blockIdx.y*32, c0 = (long)blockIdx.x*32;
#pragma unroll
    for (int i = ty; i < 32; i += 8) tile[i][tx] = in[(r0+i)*768 + c0 + tx];
    __syncthreads();
#pragma unroll
    for (int i = ty; i < 32; i += 8) out[(c0+i)*2048 + r0 + tx] = tile[tx][i];
  } else {
    const int idx = blockIdx.y*2 + blockIdx.x;     // 0..127
    const int bh = idx >> 3, chunk = idx & 7;
    const int b = bh >> 2, h = bh & 3;
    const int lane = t & 63, wv = t >> 6;
    __shared__ float red[4];
    long row = (long)b*2048 + (long)chunk*256 + t;
    const short8* kp = (const short8*)(qkv + row*768 + 256 + h*64);
    float ss = 0.f;
#pragma unroll
    for (int c=0;c<8;c++){
      short8 v = kp[c];
#pragma unroll
      for (int j=0;j<8;j++){ float f = bs2f(v[j]); ss = fmaf(f,f,ss); }
    }
#pragma unroll
    for (int off=32; off; off>>=1) ss = fmaxf(ss, __shfl_xor(ss, off));
    if (lane == 0) red[wv] = ss;
    __syncthreads();
    if (t == 0){
      float m = fmaxf(fmaxf(red[0],red[1]), fmaxf(red[2],red[3]));
      atomicMax((unsigned*)&kmax[bh], __float_as_uint(m));
    }
  }
}

// ------------------------------------------------------------------
// fused LayerNorm (blocks < 8192) + eq-norm (blocks >= 8192).
// VN=1: vnorm1 addressing (v (b,n,c,x) -> vnX[(b,n,x),c]);
// VN=2: vnorm2 addressing (v2X[(b,n),x*64+c] -> same layout).
// ------------------------------------------------------------------
template<int VN>
__global__ __launch_bounds__(256) void lnvn_kernel(
    const float* __restrict__ x, const float* __restrict__ g,
    const float* __restrict__ be, bf16* __restrict__ outln,
    const float* __restrict__ vin, const float* __restrict__ vs,
    bf16* __restrict__ outvn)
{
  const int t = threadIdx.x;
  if (blockIdx.x < 8192){
    const long row = blockIdx.x;
    const int lane = t & 63, wv = t >> 6;
    __shared__ float ws1[4], ws2[4];
    float v = x[(row<<8) + t];
    float s1 = v, s2 = v*v;
#pragma unroll
    for (int off=32; off; off>>=1){
      s1 += __shfl_xor(s1, off);
      s2 += __shfl_xor(s2, off);
    }
    if (lane == 0){ ws1[wv] = s1; ws2[wv] = s2; }
    __syncthreads();
    const float r1 = ws1[0]+ws1[1]+ws1[2]+ws1[3];
    const float r2 = ws2[0]+ws2[1]+ws2[2]+ws2[3];
    const float mu = r1 * (1.f/256.f);
    const float var = r2 * (1.f/256.f) - mu*mu;
    const float rstd = rsqrtf(fmaxf(var, 0.f) + EPSV);
    outln[(row<<8)+t] = f2b((v-mu)*rstd*g[t] + be[t]);
  } else {
    const long row = blockIdx.x - 8192;
    __shared__ float vv[192], nrm[64];
    __shared__ float smean;
    if (t < 192) vv[t] = vin[row*192 + t];
    __syncthreads();
    if (t < 64){
      float a, b, c;
      if (VN == 1){ a = vv[3*t]; b = vv[3*t+1]; c = vv[3*t+2]; }
      else        { a = vv[t]; b = vv[t+64]; c = vv[t+128]; }
      float nv = sqrtf(a*a + b*b + c*c);
      nrm[t] = nv;
      float s = nv;
#pragma unroll
      for (int off=32; off; off>>=1) s += __shfl_xor(s, off);
      if (t == 0) smean = s*(1.f/64.f);
    }
    __syncthreads();
    if (t < 192){
      if (VN == 1){
        const int c = t/3, xx = t - 3*c;
        outvn[row*192 + xx*64 + c] = f2b(vv[t] / (nrm[c] + EPSV) * smean * vs[c]);
      } else {
        const int c = t & 63;
        outvn[row*192 + t] = f2b(vv[t] / (nrm[c] + EPSV) * smean * vs[c]);
      }
    }
  }
}

// ------------------------------------------------------------------
// addb: out[row][j] = in[row][j] + bias[j]  (fp32, 256 cols)
// ------------------------------------------------------------------
__global__ __launch_bounds__(256) void addb_kernel(const float* __restrict__ in,
                                                   const float* __restrict__ bias,
                                                   float* __restrict__ out){
  long i = (long)blockIdx.x*256 + threadIdx.x;
  out[i] = in[i] + bias[threadIdx.x];
}

// ------------------------------------------------------------------
// FUSED ATTENTION, 8-wave m-split (2 groups x 4 q-waves, 2 waves/SIMD):
//   round-5 benched structure: 116.7 us, VGPR 124. DO NOT raise
//   occupancy: 3 waves/SIMD caps regs at ~170 < ~200 live state ->
//   scratch spill (rounds 4 & 6, both ~8x slower).
// ------------------------------------------------------------------
#define ATT_K_OFF   0
#define ATT_V_OFF   4096
#define ATT_X_OFF   9216
#define ATT_P_OFF   24576
#define ATT_TILE    25088
#define ATT_GRP     50176          // 2 dbuf per group
#define ATT_LACC    98304          // 8*64 floats = 2048 B
#define ATT_SMEM    100352

__global__ __launch_bounds__(512, 2) void attn_kernel(
    const bf16* __restrict__ qkv,    // [8192][768] (Q|K|V, 4 heads x 64)
    const bf16* __restrict__ vsT,    // [b][h][64][2048]
    const bf16* __restrict__ vmixT,  // [b][192][2048]
    const float* __restrict__ posf,  // [b][2048][4]
    const float* __restrict__ kmaxA, // [16] max ||k||^2
    const float* __restrict__ w_dist, const float* __restrict__ b_dist,
    bf16* __restrict__ sA,           // [8192][256]
    bf16* __restrict__ slab)         // [4][8192][192]
{
  __shared__ __align__(16) char smem[ATT_SMEM];
  const int qb = blockIdx.x;         // 0..15
  const int bh = blockIdx.y;         // 0..15
  const int b  = bh >> 2, h = bh & 3;
  const int tid = threadIdx.x;
  const int w = tid >> 6, lane = tid & 63;
  const int g = w >> 2, qw = w & 3;
  const int lq = lane & 31, hi = lane >> 5;
  const int gtid = tid & 255;

  const int qloc = qb*128 + qw*32 + lq;
  const long rowQ = (long)b*2048 + qloc;

  // Q fragments (B operand): col=q (lane&31), k=d = kc*16 + hi*8 + j
  short8 qf[4];
  {
    const bf16* qp = qkv + rowQ*768 + h*64 + hi*8;
#pragma unroll
    for (int kc=0;kc<4;kc++) qf[kc] = *(const short8*)(qp + kc*16);
  }
  // stabilizer: sqrt(|q|^2 * max|k|^2) / 8  (>= max_m qk/8; bias only subtracts)
  float q2 = 0.f;
#pragma unroll
  for (int kc=0;kc<4;kc++)
#pragma unroll
    for (int j=0;j<8;j++){ float qv = bs2f(qf[kc][j]); q2 = fmaf(qv,qv,q2); }
  q2 += __shfl_xor(q2, 32);
  const float mxs = sqrtf(q2 * kmaxA[bh]) * 0.125f;
  const float wh = w_dist[h], bhd = b_dist[h];
  const float4v pn = *(const float4v*)(posf + (long)b*8192 + (long)qloc*4);
  const float m2x = -2.f*pn[0], m2y = -2.f*pn[1], m2z = -2.f*pn[2], pnw = pn[3];

  f32x16 O[2]  = {Z16, Z16};
  f32x16 VM[6] = {Z16, Z16, Z16, Z16, Z16, Z16};
  float lacc = 0.f;

  // per-group staging (256 threads, 20.5 KB/tile)
  short8 stK, stV, stX0, stX1, stX2; float4v stP;
  const int sm = gtid >> 3, sc = gtid & 7;   // K: row(32) x chunk(8)
  const int vd = gtid >> 2, vc = gtid & 3;   // V/X: row x chunk(4)
  const bf16* Kg = qkv + (long)b*2048*768 + 256 + h*64;
  const bf16* Vg = vsT + (long)b*524288 + (long)h*131072;
  const bf16* Xg = vmixT + (long)b*393216;
  const float* Pg = posf + (long)b*8192;
  char* gbase = smem + g*ATT_GRP;

  auto LOADT = [&](int m0){
    stK  = *(const short8*)(Kg + (long)(m0+sm)*768 + sc*8);
    stV  = *(const short8*)(Vg + (long)vd*2048 + m0 + vc*8);
    stX0 = *(const short8*)(Xg + (long)vd*2048 + m0 + vc*8);
    stX1 = *(const short8*)(Xg + (long)(64+vd)*2048 + m0 + vc*8);
    stX2 = *(const short8*)(Xg + (long)(128+vd)*2048 + m0 + vc*8);
    if (gtid < 32) stP = *(const float4v*)(Pg + (long)(m0+gtid)*4);
  };
  auto WRITET = [&](char* buf){
    *(short8*)(buf + ATT_K_OFF + sm*128 + ((sc ^ (sm&7))<<4)) = stK;   // XOR-swizzle
    *(short8*)(buf + ATT_V_OFF + vd*80 + vc*16) = stV;
    *(short8*)(buf + ATT_X_OFF + vd*80 + vc*16) = stX0;
    *(short8*)(buf + ATT_X_OFF + (64+vd)*80 + vc*16) = stX1;
    *(short8*)(buf + ATT_X_OFF + (128+vd)*80 + vc*16) = stX2;
    if (gtid < 32) *(float4v*)(buf + ATT_P_OFF + gtid*16) = stP;
  };

  auto COMPUTE = [&](const char* buf){
    const char* Kb = buf + ATT_K_OFF;
    const char* Vb = buf + ATT_V_OFF;
    const char* Xb = buf + ATT_X_OFF;
    const float4v* pmb = (const float4v*)(buf + ATT_P_OFF);
    // swapped QK^T: S[m][q], col = lane&31 = q
    f32x16 S = Z16;
#pragma unroll
    for (int kc=0;kc<4;kc++){
      short8 kf = *(const short8*)(Kb + lq*128 + (((kc*2+hi) ^ (lq&7))<<4));
      S = __builtin_amdgcn_mfma_f32_32x32x16_bf16(kf, qf[kc], S, 0, 0, 0);
    }
    // dist bias + exp (unnormalized, fixed stabilizer); m = i + 8gg + 4hi
    float P[16];
#pragma unroll
    for (int gg=0; gg<4; gg++){
#pragma unroll
      for (int i=0;i<4;i++){
        float4v pm = pmb[gg*8 + hi*4 + i];
        float d2 = fmaf(m2x, pm[0], fmaf(m2y, pm[1], fmaf(m2z, pm[2], pnw + pm[3])));
        float dist = sqrtf(fmaxf(d2, 1e-12f));
        float sig = frcp(1.f + __expf(fmaf(dist, wh, bhd)));
        float p = __expf(fmaf(S[gg*4+i], 0.125f, -mxs)) * sig;
        lacc += p;
        P[gg*4+i] = p;
      }
    }
    // P -> bf16 B-operand (col=q, k=m) via cvt_pk + permlane32_swap
    unsigned pk[8];
#pragma unroll
    for (int t=0;t<8;t++) pk[t] = cvt_pk_bf16(P[2*t], P[2*t+1]);
    plswap(pk[0], pk[2]); plswap(pk[1], pk[3]);   // chunk0: m 0..15
    plswap(pk[4], pk[6]); plswap(pk[5], pk[7]);   // chunk1: m 16..31
    uint4v y0v = {pk[0], pk[1], pk[2], pk[3]};
    uint4v y1v = {pk[4], pk[5], pk[6], pk[7]};
    short8 Y0 = __builtin_bit_cast(short8, y0v);
    short8 Y1 = __builtin_bit_cast(short8, y1v);
    // PV: O^T[d][q] += V^T[d][m] * P[q][m]
#pragma unroll
    for (int dblk=0; dblk<2; dblk++){
      short8 v0 = *(const short8*)(Vb + (dblk*32+lq)*80 + hi*16);
      short8 v1 = *(const short8*)(Vb + (dblk*32+lq)*80 + 32 + hi*16);
      O[dblk] = __builtin_amdgcn_mfma_f32_32x32x16_bf16(v0, Y0, O[dblk], 0,0,0);
      O[dblk] = __builtin_amdgcn_mfma_f32_32x32x16_bf16(v1, Y1, O[dblk], 0,0,0);
    }
    // vmix: VM^T[e][q] += vmix^T[e][m] * P[q][m]
#pragma unroll
    for (int eblk=0; eblk<6; eblk++){
      short8 x0 = *(const short8*)(Xb + (eblk*32+lq)*80 + hi*16);
      short8 x1 = *(const short8*)(Xb + (eblk*32+lq)*80 + 32 + hi*16);
      VM[eblk] = __builtin_amdgcn_mfma_f32_32x32x16_bf16(x0, Y0, VM[eblk], 0,0,0);
      VM[eblk] = __builtin_amdgcn_mfma_f32_32x32x16_bf16(x1, Y1, VM[eblk], 0,0,0);
    }
  };

  // group g computes tiles g, g+2, ..., g+62 (32 tiles each)
  LOADT(g*32);
  WRITET(gbase);
  __syncthreads();
#pragma unroll 1
  for (int i=0; i<32; ++i){
    if (i < 31) LOADT((2*(i+1)+g)*32);
    COMPUTE(gbase + (i&1)*ATT_TILE);
    if (i < 31) WRITET(gbase + ((i+1)&1)*ATT_TILE);
    __syncthreads();
  }

  // ---------------- cross-group combine (odd strides: conflict-free) ----------------
  float* laccT = (float*)(smem + ATT_LACC);
  laccT[w*64 + lane] = lacc;
  if (g == 1){                       // group 1 exports O (stride 33 floats)
    float* Od = (float*)(smem + ATT_GRP) + (qw*64+lane)*33;
#pragma unroll
    for (int r=0;r<16;r++){ Od[r] = O[0][r]; Od[16+r] = O[1][r]; }
  }
  __syncthreads();
  const float lsum = laccT[qw*64+lq] + laccT[qw*64+32+lq]
                   + laccT[(4+qw)*64+lq] + laccT[(4+qw)*64+32+lq];
  if (g == 0){                       // group 0 accumulates full O
    const float* Od = (const float*)(smem + ATT_GRP) + (qw*64+lane)*33;
#pragma unroll
    for (int r=0;r<16;r++){ O[0][r] += Od[r]; O[1][r] += Od[16+r]; }
  }
  __syncthreads();
  // VM in two halves (stride 49 floats; each half fits the 50176 B group-0 area)
#pragma unroll
  for (int hf=0; hf<2; hf++){
    if (g == 0){                     // group 0 exports VM half
      float* Vd = (float*)smem + (qw*64+lane)*49;
#pragma unroll
      for (int e=0;e<3;e++)
#pragma unroll
        for (int r=0;r<16;r++) Vd[e*16+r] = VM[hf*3+e][r];
    }
    __syncthreads();
    if (g == 1){                     // group 1 accumulates full VM
      const float* Vd = (const float*)smem + (qw*64+lane)*49;
#pragma unroll
      for (int e=0;e<3;e++)
#pragma unroll
        for (int r=0;r<16;r++) VM[hf*3+e][r] += Vd[e*16+r];
    }
    __syncthreads();
  }

  // ---------------- parallel epilogue ----------------
  const float sinv = frcp(lsum);
  if (g == 0){
    // s_attn: transpose O^T[d][q] -> [q][64d] via LDS (pitch 136B)
    char* scr = smem + qw*12544;
#pragma unroll
    for (int dblk=0; dblk<2; dblk++)
#pragma unroll
      for (int pp=0; pp<8; pp++){
        const int r = 2*pp;
        const int d = dblk*32 + (r&3) + 8*(r>>2) + 4*hi;
        unsigned u = cvt_pk_bf16(O[dblk][r]*sinv, O[dblk][r+1]*sinv);
        *(unsigned*)(scr + lq*136 + d*2) = u;
      }
  } else {
    // vmix: transpose VM^T[e][q] -> [q][192e] via LDS (pitch 392B)
    const float vinv = 0.25f * sinv;
    char* scr = smem + ATT_GRP + qw*12544;
#pragma unroll
    for (int eblk=0; eblk<6; eblk++)
#pragma unroll
      for (int pp=0; pp<8; pp++){
        const int r = 2*pp;
        const int e = eblk*32 + (r&3) + 8*(r>>2) + 4*hi;
        unsigned u = cvt_pk_bf16(VM[eblk][r]*vinv, VM[eblk][r+1]*vinv);
        *(unsigned*)(scr + lq*392 + e*2) = u;
      }
  }
  __syncthreads();
  if (g == 0){
    const char* scr = smem + qw*12544;
    const int q = lane >> 1, half = lane & 1;
    const char* src = scr + q*136 + half*64;
    char* dst = (char*)(sA + (long)(b*2048 + qb*128 + qw*32 + q)*256 + h*64 + half*32);
#pragma unroll
    for (int i=0;i<8;i++)
      *(unsigned long long*)(dst + i*8) = *(const unsigned long long*)(src + i*8);
  } else {
    const char* scr = smem + ATT_GRP + qw*12544;
    const int q = lane >> 1, half = lane & 1;
    const char* src = scr + q*392 + half*192;
    char* dst = (char*)(slab + (long)h*1572864
                        + (long)(b*2048 + qb*128 + qw*32 + q)*192 + half*96);
#pragma unroll
    for (int i=0;i<24;i++)
      *(unsigned long long*)(dst + i*8) = *(const unsigned long long*)(src + i*8);
  }
}

// ------------------------------------------------------------------
// TILED GEMM 64x128: 256 thr = 4 waves side-by-side, each 64 rows x 32
// cols. BK=32 double-buffered LDS (24.6 KB). Linear LDS layouts are
// conflict-free (contiguous 1 KB/wave regions). K-split via blockIdx.z
// (A/BT advanced by z*K; K = chunk length). OUTM: 0 bf16 store,
// 1 fp32 store, 2 fp32 unsafeAtomicAdd (bias/resid must be nullptr).
// ------------------------------------------------------------------
template<int ACT, int OUTM>
__global__ __launch_bounds__(256) void tgemm64_kernel(
    const bf16* __restrict__ A, long lda,
    const bf16* __restrict__ BT, long ldb,
    const float* __restrict__ bias,
    const float* __restrict__ resid,   // fp32, same ld as C
    void* __restrict__ Cv, long ldc,
    int K)
{
  __shared__ __align__(16) bf16 As[2][64*32];
  __shared__ __align__(16) bf16 Bs[2][128*32];
  const int tid = threadIdx.x;
  const int wc = tid >> 6, lane = tid & 63;
  const int col = lane & 15, quad = lane >> 4;
  const long rowA0 = (long)blockIdx.y*64;
  const long colB0 = (long)blockIdx.x*128;
  const long koff = (long)blockIdx.z*K;

  const int tr = tid >> 2, tc = tid & 3;
  const bf16* Ag = A + (rowA0 + tr)*lda + koff + tc*8;
  const bf16* Bg = BT + (colB0 + tr)*ldb + koff + tc*8;

  short8 sa, sb[2];
  auto LOAD = [&](int k0){
    sa = *(const short8*)(Ag + k0);
    sb[0] = *(const short8*)(Bg + k0);
    sb[1] = *(const short8*)(Bg + (long)64*ldb + k0);
  };
  auto STORE = [&](int buf){
    *(short8*)(&As[buf][tr*32 + tc*8]) = sa;
    *(short8*)(&Bs[buf][tr*32 + tc*8]) = sb[0];
    *(short8*)(&Bs[buf][(tr+64)*32 + tc*8]) = sb[1];
  };

  float4v acc[4][2];
#pragma unroll
  for (int m=0;m<4;m++)
#pragma unroll
    for (int n=0;n<2;n++) acc[m][n] = (float4v){0.f,0.f,0.f,0.f};

  LOAD(0); STORE(0);
  __syncthreads();
  const int nk = K >> 5;
#pragma unroll 1
  for (int ks=0; ks<nk; ++ks){
    if (ks+1 < nk) LOAD((ks+1)*32);
    const bf16* Ab = &As[ks&1][col*32 + quad*8];
    const bf16* Bb = &Bs[ks&1][(wc*32 + col)*32 + quad*8];
    short8 af[4], bfv[2];
#pragma unroll
    for (int m=0;m<4;m++) af[m] = *(const short8*)(Ab + m*16*32);
#pragma unroll
    for (int n=0;n<2;n++) bfv[n] = *(const short8*)(Bb + n*16*32);
#pragma unroll
    for (int m=0;m<4;m++)
#pragma unroll
      for (int n=0;n<2;n++)
        acc[m][n] = __builtin_amdgcn_mfma_f32_16x16x32_bf16(af[m], bfv[n], acc[m][n], 0, 0, 0);
    if (ks+1 < nk) STORE((ks+1)&1);
    __syncthreads();
  }

  // epilogue
#pragma unroll
  for (int m=0;m<4;m++){
    const long ci0 = rowA0 + m*16 + quad*4;
#pragma unroll
    for (int n=0;n<2;n++){
      const long cj = colB0 + wc*32 + n*16 + col;
      const float bbias = bias ? bias[cj] : 0.f;
#pragma unroll
      for (int r=0;r<4;r++){
        const long ci = ci0 + r;
        float val = acc[m][n][r] + bbias;
        if (ACT == 1) val = 0.5f*val*(1.f + erff(val*0.70710678118654752f));
        if (resid) val += resid[ci*ldc + cj];
        if (OUTM == 0)      ((bf16*)Cv)[ci*ldc + cj] = f2b(val);
        else if (OUTM == 1) ((float*)Cv)[ci*ldc + cj] = val;
        else                unsafeAtomicAdd(&((float*)Cv)[ci*ldc + cj], val);
      }
    }
  }
}

// ------------------------------------------------------------------
// simple MFMA GEMM (small shapes: K=64 / N=64 paths).
// HS=1: A operand is the 4-way head-slab sum (A + h*1572864), fp32
// summed then cvt to bf16 — replaces the hred pass bit-identically.
// ------------------------------------------------------------------
template<int MT, int NT, int ACT, int OUTM, int RXIL, int CXIL, int HS>
__global__ __launch_bounds__(64) void gemm_kernel(
    const bf16* __restrict__ A, long lda, long As1, long As2,
    const bf16* __restrict__ BT, long ldb, long Bs1, long Bs2,
    const float* __restrict__ bias,
    const float* __restrict__ resid, long ldr, long Rs1, long Rs2,
    void* __restrict__ Cv, long ldc, long Cs1, long Cs2,
    int K, int Z2, int KS)
{
  int z = blockIdx.z;
  int zz = z / KS, ks = z - zz*KS;
  int z1 = zz / Z2, z2 = zz - z1*Z2;
  A  += (long)z1*As1 + (long)z2*As2 + (long)ks*K;
  BT += (long)z1*Bs1 + (long)z2*Bs2 + (long)ks*K;
  if (resid) resid += (long)z1*Rs1 + (long)z2*Rs2;
  const long cbase = (long)z1*Cs1 + (long)z2*Cs2;

  const int lane = threadIdx.x;
  const int col = lane & 15, quad = lane >> 4;
  const long rowA0 = (long)blockIdx.y*(16*MT);
  const long colB0 = (long)blockIdx.x*(16*NT);

  float4v acc[MT][NT];
#pragma unroll
  for (int m=0;m<MT;m++)
#pragma unroll
    for (int n=0;n<NT;n++) acc[m][n] = (float4v){0.f,0.f,0.f,0.f};

  const bf16* ap[MT];
  const bf16* bp[NT];
#pragma unroll
  for (int m=0;m<MT;m++) ap[m] = A + (rowA0 + m*16 + col)*lda + quad*8;
#pragma unroll
  for (int n=0;n<NT;n++) bp[n] = BT + (colB0 + n*16 + col)*ldb + quad*8;

  for (int k0 = 0; k0 < K; k0 += 32){
    short8 a[MT], bb[NT];
#pragma unroll
    for (int m=0;m<MT;m++){
      if (HS){
        short8 x0 = *(const short8*)ap[m];
        short8 x1 = *(const short8*)(ap[m] + 1572864);
        short8 x2 = *(const short8*)(ap[m] + 3145728);
        short8 x3 = *(const short8*)(ap[m] + 4718592);
        short8 r;
#pragma unroll
        for (int j=0;j<8;j++){
          float f = bs2f(x0[j]) + bs2f(x1[j]) + bs2f(x2[j]) + bs2f(x3[j]);
          bf16 hb = f2b(f); r[j] = *(short*)&hb;
        }
        a[m] = r;
      } else {
        a[m] = *(const short8*)ap[m];
      }
      ap[m] += 32;
    }
#pragma unroll
    for (int n=0;n<NT;n++){ bb[n] = *(const short8*)bp[n]; bp[n] += 32; }
#pragma unroll
    for (int m=0;m<MT;m++)
#pragma unroll
      for (int n=0;n<NT;n++)
        acc[m][n] = __builtin_amdgcn_mfma_f32_16x16x32_bf16(a[m], bb[n], acc[m][n], 0, 0, 0);
  }

#pragma unroll
  for (int m=0;m<MT;m++){
    const long ri = rowA0 + m*16 + quad*4;
#pragma unroll
    for (int n=0;n<NT;n++){
      const long cj = colB0 + n*16 + col;
      const float bbias = bias ? bias[cj] : 0.f;
#pragma unroll
      for (int r=0;r<4;r++){
        const long ci = ri + r;
        float val = acc[m][n][r] + bbias;
        if (ACT == 1) val = 0.5f*val*(1.f + erff(val*0.70710678118654752f));
        if (resid){
          const long raddr = RXIL ? ((ci/3)*192 + cj*3 + (ci%3)) : (ci*ldr + cj);
          val += resid[raddr];
        }
        const long caddr = CXIL ? (cbase + (ci/3)*192 + cj*3 + (ci%3))
                                : (cbase + ci*ldc + cj);
        if (OUTM == 0)      ((bf16*)Cv)[caddr] = f2b(val);
        else if (OUTM == 1) ((float*)Cv)[caddr] = val;
        else                unsafeAtomicAdd(&((float*)Cv)[caddr], val);
      }
    }
  }
}

// ------------------------------------------------------------------
extern "C" void kernel_launch(void* const* d_in, const int* in_sizes, int n_in,
                              void* d_out, int out_size, void* d_ws, size_t ws_size,
                              hipStream_t stream)
{
  const float* s    = (const float*)d_in[0];
  const float* v    = (const float*)d_in[1];
  const float* pos  = (const float*)d_in[2];
  const float* Wq   = (const float*)d_in[3];
  const float* bq   = (const float*)d_in[4];
  const float* Wk   = (const float*)d_in[5];
  const float* bk   = (const float*)d_in[6];
  const float* Wv   = (const float*)d_in[7];
  const float* bv   = (const float*)d_in[8];
  const float* Wo   = (const float*)d_in[9];
  const float* bo   = (const float*)d_in[10];
  const float* w_d  = (const float*)d_in[11];
  const float* b_d  = (const float*)d_in[12];
  const float* Wvv  = (const float*)d_in[13];
  const float* Wvo  = (const float*)d_in[14];
  const float* g1   = (const float*)d_in[15];
  const float* be1  = (const float*)d_in[16];
  const float* vs1  = (const float*)d_in[17];
  const float* g2   = (const float*)d_in[18];
  const float* be2  = (const float*)d_in[19];
  const float* vs2  = (const float*)d_in[20];
  const float* Wf1  = (const float*)d_in[21];
  const float* bf1  = (const float*)d_in[22];
  const float* Wf2  = (const float*)d_in[23];
  const float* bf2  = (const float*)d_in[24];
  const float* Wfv1 = (const float*)d_in[25];
  const float* Wfv2 = (const float*)d_in[26];

  float* outS = (float*)d_out;
  float* outV = outS + (size_t)4*2048*256;

  char* w = (char*)d_ws;
  size_t o = 0;
  auto alloc = [&](size_t bytes)->char* {
    char* p = w + o;
    o = (o + bytes + 255) & ~(size_t)255;
    return p;
  };
  float* posf  = (float*)alloc(131072);
  bf16* WqkvT = (bf16*)alloc(393216);       // 768 x 256
  bf16* WoT   = (bf16*)alloc(131072);
  bf16* Wf1T  = (bf16*)alloc(524288);
  bf16* Wf2T  = (bf16*)alloc(524288);
  bf16* WvvT  = (bf16*)alloc(8192);
  bf16* WvoT  = (bf16*)alloc(8192);
  bf16* Wfv1T = (bf16*)alloc(32768);
  bf16* Wfv2T = (bf16*)alloc(32768);
  float* bqkv = (float*)alloc(3072);
  float* kmax = (float*)alloc(64);
  bf16* sn    = (bf16*)alloc(4194304);      // reused for sn2
  bf16* qkv   = (bf16*)alloc(12582912);     // 8192 x 768; later alias: hv
  bf16* vsT   = (bf16*)alloc(4194304);
  bf16* sA    = (bf16*)alloc(4194304);
  float* s2   = (float*)alloc(8388608);
  bf16* vnX   = (bf16*)alloc(3145728);      // later alias: vn2X
  bf16* vmixX = (bf16*)alloc(3145728);
  bf16* vmixXT= (bf16*)alloc(3145728);      // (b, 192, 2048)
  float* v2X  = (float*)alloc(6291456);
  bf16* slab  = (bf16*)alloc(12582912);     // 4 x 8192 x 192
  bf16* h1    = (bf16*)alloc(16777216);     // 8192 x 1024
  bf16* vn2X  = vnX;
  bf16* hv    = qkv;                        // qkv dead after attention
  if (o > ws_size) return;

  // --- prep (weights + pos + bias concat in one launch) ---
  WTPack pk;
  pk.d[0] = {Wq,   WqkvT,          256, 256};
  pk.d[1] = {Wk,   WqkvT + 65536,  256, 256};
  pk.d[2] = {Wv,   WqkvT + 131072, 256, 256};
  pk.d[3] = {Wo,   WoT,            256, 256};
  pk.d[4] = {Wf1,  Wf1T,           256, 1024};
  pk.d[5] = {Wf2,  Wf2T,           1024, 256};
  pk.d[6] = {Wvv,  WvvT,           64, 64};
  pk.d[7] = {Wvo,  WvoT,           64, 64};
  pk.d[8] = {Wfv1, Wfv1T,          64, 256};
  pk.d[9] = {Wfv2, Wfv2T,          256, 64};
  wtrans_kernel<<<dim3(32,32,11), 256, 0, stream>>>(pk, pos, posf, bq, bk, bv, bqkv, kmax);

  // --- norm1 (scalar + vector, fused) ---
  lnvn_kernel<1><<<16384, 256, 0, stream>>>(s, g1, be1, sn, v, vs1, vnX);

  // --- vmixX = vnX @ WvvT, then per-b transpose -> vmixXT ---
  gemm_kernel<2,4,0,0,0,0,0><<<dim3(1,768,1), 64, 0, stream>>>(vnX,64,0,0, WvvT,64,0,0,
      nullptr, nullptr,0,0,0, vmixX,64,0,0, 64, 1, 1);
  transpose_kernel<bf16><<<dim3(6,64,4), 256, 0, stream>>>(vmixX, 192, 393216,0,
      vmixXT, 2048, 393216,0, 1);

  // --- fused QKV projection (64x128 tiles) ---
  tgemm64_kernel<0,0><<<dim3(6,128), 256, 0, stream>>>(sn,256, WqkvT,256,
      bqkv, nullptr, qkv,768, 256);

  // --- vsT transpose + knorm (fused, both read qkv) ---
  trk_kernel<<<dim3(2,64,17), 256, 0, stream>>>(qkv, vsT, kmax);

  // --- fully fused attention ---
  attn_kernel<<<dim3(16,16), 512, 0, stream>>>(qkv, vsT, vmixXT, posf, kmax,
      w_d, b_d, sA, slab);

  // --- s2 = (s + bo) + sA@Wo  (prefill + K-split atomic GEMM, 2 blk/CU) ---
  addb_kernel<<<8192, 256, 0, stream>>>(s, bo, s2);
  tgemm64_kernel<0,2><<<dim3(2,128,2), 256, 0, stream>>>(sA,256, WoT,256,
      nullptr, nullptr, s2,256, 128);

  // --- v2X = v (interleaved resid) + (sum_h slab) @ WvoT  (hred folded) ---
  gemm_kernel<2,4,0,1,1,0,1><<<dim3(1,768,1), 64, 0, stream>>>(slab,64,0,0, WvoT,64,0,0,
      nullptr, v,0,0,0, v2X,64,0,0, 64, 1, 1);

  // --- norm2 (scalar + vector, fused) ---
  lnvn_kernel<2><<<16384, 256, 0, stream>>>(s2, g2, be2, sn, v2X, vs2, vn2X);

  // --- FFN ---
  tgemm64_kernel<1,0><<<dim3(8,128), 256, 0, stream>>>(sn,256, Wf1T,256,
      bf1, nullptr, h1,1024, 256);
  addb_kernel<<<8192, 256, 0, stream>>>(s2, bf2, outS);
  tgemm64_kernel<0,2><<<dim3(2,128,2), 256, 0, stream>>>(h1,1024, Wf2T,1024,
      nullptr, nullptr, outS,256, 512);

  // --- vector FFN ---
  tgemm64_kernel<0,0><<<dim3(2,384), 256, 0, stream>>>(vn2X,64, Wfv1T,64,
      nullptr, nullptr, hv,256, 64);
  gemm_kernel<2,4,0,1,0,1,0><<<dim3(1,768,1), 64, 0, stream>>>(hv,256,0,0, Wfv2T,256,0,0,
      nullptr, v2X,64,0,0, outV,0,0,0, 256, 1, 1);
}

// Round 10
// 361.986 us; speedup vs baseline: 3.0363x; 1.0319x over previous
//
#include <hip/hip_runtime.h>
#include <hip/hip_bf16.h>

using bf16 = __hip_bfloat16;
typedef __attribute__((ext_vector_type(8))) short short8;
typedef __attribute__((ext_vector_type(4))) float float4v;
typedef __attribute__((ext_vector_type(16))) float f32x16;
typedef __attribute__((ext_vector_type(4))) unsigned uint4v;

__device__ __forceinline__ float b2f(bf16 x){ return __bfloat162float(x); }
__device__ __forceinline__ bf16  f2b(float x){ return __float2bfloat16(x); }
__device__ __forceinline__ bf16  tob(float x){ return f2b(x); }
__device__ __forceinline__ bf16  tob(bf16 x){ return x; }
__device__ __forceinline__ float frcp(float x){ return __builtin_amdgcn_rcpf(x); }
__device__ __forceinline__ float fexp2(float x){
  float r; asm("v_exp_f32 %0, %1" : "=v"(r) : "v"(x)); return r;
}
__device__ __forceinline__ float bs2f(short s){
  unsigned u = ((unsigned)(unsigned short)s) << 16;
  return __builtin_bit_cast(float, u);
}
__device__ __forceinline__ unsigned cvt_pk_bf16(float lo, float hi){
  unsigned r; asm("v_cvt_pk_bf16_f32 %0, %1, %2" : "=v"(r) : "v"(lo), "v"(hi)); return r;
}
__device__ __forceinline__ void plswap(unsigned &a, unsigned &b){
  asm("v_permlane32_swap_b32 %0, %1" : "+v"(a), "+v"(b));
}

#define EPSV 1e-5f
#define L2E  1.44269504f
#define Z16 {0.f,0.f,0.f,0.f,0.f,0.f,0.f,0.f,0.f,0.f,0.f,0.f,0.f,0.f,0.f,0.f}

// ------------------------------------------------------------------
// all 10 weight transposes (fp32 -> bf16) + pos prep + bias concat
// in ONE launch (z==10 handles pos/bcat/kmax-zero).
// ------------------------------------------------------------------
struct WTDesc { const float* src; bf16* dst; int rows, cols; };
struct WTPack { WTDesc d[10]; };

__global__ __launch_bounds__(256) void wtrans_kernel(WTPack p,
    const float* __restrict__ pos, float* __restrict__ posf,
    const float* __restrict__ bq, const float* __restrict__ bk,
    const float* __restrict__ bv, float* __restrict__ bqkv,
    float* __restrict__ kmax){
  const int t = threadIdx.x;
  if (blockIdx.z == 10){
    if (blockIdx.y == 0 && blockIdx.x < 32){
      int r = blockIdx.x*256 + t;
      float x = pos[3*r], y = pos[3*r+1], z = pos[3*r+2];
      posf[4*r] = x; posf[4*r+1] = y; posf[4*r+2] = z; posf[4*r+3] = x*x + y*y + z*z;
    } else if (blockIdx.y == 1 && blockIdx.x < 3){
      int j = blockIdx.x*256 + t;
      if (blockIdx.x == 0 && t < 16) kmax[t] = 0.f;
      bqkv[j] = (j < 256) ? bq[j] : (j < 512) ? bk[j-256] : bv[j-512];
    }
    return;
  }
  WTDesc w = p.d[blockIdx.z];
  long r0 = (long)blockIdx.y*32, c0 = (long)blockIdx.x*32;
  if (r0 >= w.rows || c0 >= w.cols) return;
  __shared__ bf16 tile[32][33];
  int tx = t & 31, ty = t >> 5;
#pragma unroll
  for (int i = ty; i < 32; i += 8) tile[i][tx] = f2b(w.src[(r0+i)*w.cols + c0 + tx]);
  __syncthreads();
#pragma unroll
  for (int i = ty; i < 32; i += 8) w.dst[(c0+i)*w.rows + r0 + tx] = tile[tx][i];
}

// ------------------------------------------------------------------
// batched 32x32-tiled transpose (+ cast to bf16)
// ------------------------------------------------------------------
template<typename TI>
__global__ __launch_bounds__(256) void transpose_kernel(
    const TI* __restrict__ in, long ldin, long is1, long is2,
    bf16* __restrict__ out, long ldout, long os1, long os2, int Z2)
{
  int z = blockIdx.z, z1 = z / Z2, z2 = z - z1*Z2;
  in  += (long)z1*is1 + (long)z2*is2;
  out += (long)z1*os1 + (long)z2*os2;
  __shared__ bf16 tile[32][33];
  int tx = threadIdx.x & 31, ty = threadIdx.x >> 5;
  long r0 = (long)blockIdx.y*32, c0 = (long)blockIdx.x*32;
#pragma unroll
  for (int i = ty; i < 32; i += 8) tile[i][tx] = tob(in[(r0+i)*ldin + c0 + tx]);
  __syncthreads();
#pragma unroll
  for (int i = ty; i < 32; i += 8) out[(c0+i)*ldout + r0 + tx] = tile[tx][i];
}

// ------------------------------------------------------------------
// fused vsT transpose (z<16) + knorm (z==16): both consume qkv.
// ------------------------------------------------------------------
__global__ __launch_bounds__(256) void trk_kernel(const bf16* __restrict__ qkv,
                                                  bf16* __restrict__ vsT,
                                                  float* __restrict__ kmax){
  const int t = threadIdx.x;
  if (blockIdx.z < 16){
    int z = blockIdx.z, z1 = z >> 2, z2 = z & 3;   // b, h
    const bf16* in = qkv + 512 + (long)z1*1572864 + (long)z2*64;
    bf16* out = vsT + (long)z1*524288 + (long)z2*131072;
    __shared__ bf16 tile[32][33];
    int tx = t & 31, ty = t >> 5;
    long r0 = (long)blockIdx.y*32, c0 = (long)blockIdx.x*32;
#pragma unroll
    for (int i = ty; i < 32; i += 8) tile[i][tx] = in[(r0+i)*768 + c0 + tx];
    __syncthreads();
#pragma unroll
    for (int i = ty; i < 32; i += 8) out[(c0+i)*2048 + r0 + tx] = tile[tx][i];
  } else {
    const int idx = blockIdx.y*2 + blockIdx.x;     // 0..127
    const int bh = idx >> 3, chunk = idx & 7;
    const int b = bh >> 2, h = bh & 3;
    const int lane = t & 63, wv = t >> 6;
    __shared__ float red[4];
    long row = (long)b*2048 + (long)chunk*256 + t;
    const short8* kp = (const short8*)(qkv + row*768 + 256 + h*64);
    float ss = 0.f;
#pragma unroll
    for (int c=0;c<8;c++){
      short8 v = kp[c];
#pragma unroll
      for (int j=0;j<8;j++){ float f = bs2f(v[j]); ss = fmaf(f,f,ss); }
    }
#pragma unroll
    for (int off=32; off; off>>=1) ss = fmaxf(ss, __shfl_xor(ss, off));
    if (lane == 0) red[wv] = ss;
    __syncthreads();
    if (t == 0){
      float m = fmaxf(fmaxf(red[0],red[1]), fmaxf(red[2],red[3]));
      atomicMax((unsigned*)&kmax[bh], __float_as_uint(m));
    }
  }
}

// ------------------------------------------------------------------
// fused LayerNorm (blocks < 8192) + eq-norm (blocks >= 8192).
// ------------------------------------------------------------------
template<int VN>
__global__ __launch_bounds__(256) void lnvn_kernel(
    const float* __restrict__ x, const float* __restrict__ g,
    const float* __restrict__ be, bf16* __restrict__ outln,
    const float* __restrict__ vin, const float* __restrict__ vs,
    bf16* __restrict__ outvn)
{
  const int t = threadIdx.x;
  if (blockIdx.x < 8192){
    const long row = blockIdx.x;
    const int lane = t & 63, wv = t >> 6;
    __shared__ float ws1[4], ws2[4];
    float v = x[(row<<8) + t];
    float s1 = v, s2 = v*v;
#pragma unroll
    for (int off=32; off; off>>=1){
      s1 += __shfl_xor(s1, off);
      s2 += __shfl_xor(s2, off);
    }
    if (lane == 0){ ws1[wv] = s1; ws2[wv] = s2; }
    __syncthreads();
    const float r1 = ws1[0]+ws1[1]+ws1[2]+ws1[3];
    const float r2 = ws2[0]+ws2[1]+ws2[2]+ws2[3];
    const float mu = r1 * (1.f/256.f);
    const float var = r2 * (1.f/256.f) - mu*mu;
    const float rstd = rsqrtf(fmaxf(var, 0.f) + EPSV);
    outln[(row<<8)+t] = f2b((v-mu)*rstd*g[t] + be[t]);
  } else {
    const long row = blockIdx.x - 8192;
    __shared__ float vv[192], nrm[64];
    __shared__ float smean;
    if (t < 192) vv[t] = vin[row*192 + t];
    __syncthreads();
    if (t < 64){
      float a, b, c;
      if (VN == 1){ a = vv[3*t]; b = vv[3*t+1]; c = vv[3*t+2]; }
      else        { a = vv[t]; b = vv[t+64]; c = vv[t+128]; }
      float nv = sqrtf(a*a + b*b + c*c);
      nrm[t] = nv;
      float s = nv;
#pragma unroll
      for (int off=32; off; off>>=1) s += __shfl_xor(s, off);
      if (t == 0) smean = s*(1.f/64.f);
    }
    __syncthreads();
    if (t < 192){
      if (VN == 1){
        const int c = t/3, xx = t - 3*c;
        outvn[row*192 + xx*64 + c] = f2b(vv[t] / (nrm[c] + EPSV) * smean * vs[c]);
      } else {
        const int c = t & 63;
        outvn[row*192 + t] = f2b(vv[t] / (nrm[c] + EPSV) * smean * vs[c]);
      }
    }
  }
}

// ------------------------------------------------------------------
// FUSED ATTENTION, 8-wave m-split (2 groups x 4 q-waves, 2 waves/SIMD):
//   round-5 benched structure (116.7 us, VGPR 124) + exp2 prescale.
//   DO NOT raise occupancy: 3 waves/SIMD caps regs at ~170 < ~200 live
//   state -> scratch spill (rounds 4 & 6, both ~8x slower).
// ------------------------------------------------------------------
#define ATT_K_OFF   0
#define ATT_V_OFF   4096
#define ATT_X_OFF   9216
#define ATT_P_OFF   24576
#define ATT_TILE    25088
#define ATT_GRP     50176          // 2 dbuf per group
#define ATT_LACC    98304          // 8*64 floats = 2048 B
#define ATT_SMEM    100352

__global__ __launch_bounds__(512, 2) void attn_kernel(
    const bf16* __restrict__ qkv,    // [8192][768] (Q|K|V, 4 heads x 64)
    const bf16* __restrict__ vsT,    // [b][h][64][2048]
    const bf16* __restrict__ vmixT,  // [b][192][2048]
    const float* __restrict__ posf,  // [b][2048][4]
    const float* __restrict__ kmaxA, // [16] max ||k||^2
    const float* __restrict__ w_dist, const float* __restrict__ b_dist,
    bf16* __restrict__ sA,           // [8192][256]
    bf16* __restrict__ slab)         // [4][8192][192]
{
  __shared__ __align__(16) char smem[ATT_SMEM];
  const int qb = blockIdx.x;         // 0..15
  const int bh = blockIdx.y;         // 0..15
  const int b  = bh >> 2, h = bh & 3;
  const int tid = threadIdx.x;
  const int w = tid >> 6, lane = tid & 63;
  const int g = w >> 2, qw = w & 3;
  const int lq = lane & 31, hi = lane >> 5;
  const int gtid = tid & 255;

  const int qloc = qb*128 + qw*32 + lq;
  const long rowQ = (long)b*2048 + qloc;

  // Q fragments (B operand): col=q (lane&31), k=d = kc*16 + hi*8 + j
  short8 qf[4];
  {
    const bf16* qp = qkv + rowQ*768 + h*64 + hi*8;
#pragma unroll
    for (int kc=0;kc<4;kc++) qf[kc] = *(const short8*)(qp + kc*16);
  }
  // stabilizer (exp2 domain): log2-scaled throughout
  float q2 = 0.f;
#pragma unroll
  for (int kc=0;kc<4;kc++)
#pragma unroll
    for (int j=0;j<8;j++){ float qv = bs2f(qf[kc][j]); q2 = fmaf(qv,qv,q2); }
  q2 += __shfl_xor(q2, 32);
  const float mxs2 = sqrtf(q2 * kmaxA[bh]) * (0.125f * L2E);
  const float wh2 = w_dist[h] * L2E, bhd2 = b_dist[h] * L2E;
  const float4v pn = *(const float4v*)(posf + (long)b*8192 + (long)qloc*4);
  const float m2x = -2.f*pn[0], m2y = -2.f*pn[1], m2z = -2.f*pn[2], pnw = pn[3];

  f32x16 O[2]  = {Z16, Z16};
  f32x16 VM[6] = {Z16, Z16, Z16, Z16, Z16, Z16};
  float lacc = 0.f;

  // per-group staging (256 threads, 20.5 KB/tile)
  short8 stK, stV, stX0, stX1, stX2; float4v stP;
  const int sm = gtid >> 3, sc = gtid & 7;   // K: row(32) x chunk(8)
  const int vd = gtid >> 2, vc = gtid & 3;   // V/X: row x chunk(4)
  const bf16* Kg = qkv + (long)b*2048*768 + 256 + h*64;
  const bf16* Vg = vsT + (long)b*524288 + (long)h*131072;
  const bf16* Xg = vmixT + (long)b*393216;
  const float* Pg = posf + (long)b*8192;
  char* gbase = smem + g*ATT_GRP;

  auto LOADT = [&](int m0){
    stK  = *(const short8*)(Kg + (long)(m0+sm)*768 + sc*8);
    stV  = *(const short8*)(Vg + (long)vd*2048 + m0 + vc*8);
    stX0 = *(const short8*)(Xg + (long)vd*2048 + m0 + vc*8);
    stX1 = *(const short8*)(Xg + (long)(64+vd)*2048 + m0 + vc*8);
    stX2 = *(const short8*)(Xg + (long)(128+vd)*2048 + m0 + vc*8);
    if (gtid < 32) stP = *(const float4v*)(Pg + (long)(m0+gtid)*4);
  };
  auto WRITET = [&](char* buf){
    *(short8*)(buf + ATT_K_OFF + sm*128 + ((sc ^ (sm&7))<<4)) = stK;   // XOR-swizzle
    *(short8*)(buf + ATT_V_OFF + vd*80 + vc*16) = stV;
    *(short8*)(buf + ATT_X_OFF + vd*80 + vc*16) = stX0;
    *(short8*)(buf + ATT_X_OFF + (64+vd)*80 + vc*16) = stX1;
    *(short8*)(buf + ATT_X_OFF + (128+vd)*80 + vc*16) = stX2;
    if (gtid < 32) *(float4v*)(buf + ATT_P_OFF + gtid*16) = stP;
  };

  auto COMPUTE = [&](const char* buf){
    const char* Kb = buf + ATT_K_OFF;
    const char* Vb = buf + ATT_V_OFF;
    const char* Xb = buf + ATT_X_OFF;
    const float4v* pmb = (const float4v*)(buf + ATT_P_OFF);
    // swapped QK^T: S[m][q], col = lane&31 = q
    f32x16 S = Z16;
#pragma unroll
    for (int kc=0;kc<4;kc++){
      short8 kf = *(const short8*)(Kb + lq*128 + (((kc*2+hi) ^ (lq&7))<<4));
      S = __builtin_amdgcn_mfma_f32_32x32x16_bf16(kf, qf[kc], S, 0, 0, 0);
    }
    // dist bias + exp2 (unnormalized, fixed stabilizer); m = i + 8gg + 4hi
    float P[16];
#pragma unroll
    for (int gg=0; gg<4; gg++){
#pragma unroll
      for (int i=0;i<4;i++){
        float4v pm = pmb[gg*8 + hi*4 + i];
        float d2 = fmaf(m2x, pm[0], fmaf(m2y, pm[1], fmaf(m2z, pm[2], pnw + pm[3])));
        float dist = sqrtf(fmaxf(d2, 1e-12f));
        float sig = frcp(1.f + fexp2(fmaf(dist, wh2, bhd2)));
        float p = fexp2(fmaf(S[gg*4+i], 0.125f*L2E, -mxs2)) * sig;
        lacc += p;
        P[gg*4+i] = p;
      }
    }
    // P -> bf16 B-operand (col=q, k=m) via cvt_pk + permlane32_swap
    unsigned pk[8];
#pragma unroll
    for (int t=0;t<8;t++) pk[t] = cvt_pk_bf16(P[2*t], P[2*t+1]);
    plswap(pk[0], pk[2]); plswap(pk[1], pk[3]);   // chunk0: m 0..15
    plswap(pk[4], pk[6]); plswap(pk[5], pk[7]);   // chunk1: m 16..31
    uint4v y0v = {pk[0], pk[1], pk[2], pk[3]};
    uint4v y1v = {pk[4], pk[5], pk[6], pk[7]};
    short8 Y0 = __builtin_bit_cast(short8, y0v);
    short8 Y1 = __builtin_bit_cast(short8, y1v);
    // PV: O^T[d][q] += V^T[d][m] * P[q][m]
#pragma unroll
    for (int dblk=0; dblk<2; dblk++){
      short8 v0 = *(const short8*)(Vb + (dblk*32+lq)*80 + hi*16);
      short8 v1 = *(const short8*)(Vb + (dblk*32+lq)*80 + 32 + hi*16);
      O[dblk] = __builtin_amdgcn_mfma_f32_32x32x16_bf16(v0, Y0, O[dblk], 0,0,0);
      O[dblk] = __builtin_amdgcn_mfma_f32_32x32x16_bf16(v1, Y1, O[dblk], 0,0,0);
    }
    // vmix: VM^T[e][q] += vmix^T[e][m] * P[q][m]
#pragma unroll
    for (int eblk=0; eblk<6; eblk++){
      short8 x0 = *(const short8*)(Xb + (eblk*32+lq)*80 + hi*16);
      short8 x1 = *(const short8*)(Xb + (eblk*32+lq)*80 + 32 + hi*16);
      VM[eblk] = __builtin_amdgcn_mfma_f32_32x32x16_bf16(x0, Y0, VM[eblk], 0,0,0);
      VM[eblk] = __builtin_amdgcn_mfma_f32_32x32x16_bf16(x1, Y1, VM[eblk], 0,0,0);
    }
  };

  // group g computes tiles g, g+2, ..., g+62 (32 tiles each)
  LOADT(g*32);
  WRITET(gbase);
  __syncthreads();
#pragma unroll 1
  for (int i=0; i<32; ++i){
    if (i < 31) LOADT((2*(i+1)+g)*32);
    COMPUTE(gbase + (i&1)*ATT_TILE);
    if (i < 31) WRITET(gbase + ((i+1)&1)*ATT_TILE);
    __syncthreads();
  }

  // ---------------- cross-group combine (odd strides: conflict-free) ----------------
  float* laccT = (float*)(smem + ATT_LACC);
  laccT[w*64 + lane] = lacc;
  if (g == 1){                       // group 1 exports O (stride 33 floats)
    float* Od = (float*)(smem + ATT_GRP) + (qw*64+lane)*33;
#pragma unroll
    for (int r=0;r<16;r++){ Od[r] = O[0][r]; Od[16+r] = O[1][r]; }
  }
  __syncthreads();
  const float lsum = laccT[qw*64+lq] + laccT[qw*64+32+lq]
                   + laccT[(4+qw)*64+lq] + laccT[(4+qw)*64+32+lq];
  if (g == 0){                       // group 0 accumulates full O
    const float* Od = (const float*)(smem + ATT_GRP) + (qw*64+lane)*33;
#pragma unroll
    for (int r=0;r<16;r++){ O[0][r] += Od[r]; O[1][r] += Od[16+r]; }
  }
  __syncthreads();
  // VM in two halves (stride 49 floats; each half fits the 50176 B group-0 area)
#pragma unroll
  for (int hf=0; hf<2; hf++){
    if (g == 0){                     // group 0 exports VM half
      float* Vd = (float*)smem + (qw*64+lane)*49;
#pragma unroll
      for (int e=0;e<3;e++)
#pragma unroll
        for (int r=0;r<16;r++) Vd[e*16+r] = VM[hf*3+e][r];
    }
    __syncthreads();
    if (g == 1){                     // group 1 accumulates full VM
      const float* Vd = (const float*)smem + (qw*64+lane)*49;
#pragma unroll
      for (int e=0;e<3;e++)
#pragma unroll
        for (int r=0;r<16;r++) VM[hf*3+e][r] += Vd[e*16+r];
    }
    __syncthreads();
  }

  // ---------------- parallel epilogue ----------------
  const float sinv = frcp(lsum);
  if (g == 0){
    // s_attn: transpose O^T[d][q] -> [q][64d] via LDS (pitch 136B)
    char* scr = smem + qw*12544;
#pragma unroll
    for (int dblk=0; dblk<2; dblk++)
#pragma unroll
      for (int pp=0; pp<8; pp++){
        const int r = 2*pp;
        const int d = dblk*32 + (r&3) + 8*(r>>2) + 4*hi;
        unsigned u = cvt_pk_bf16(O[dblk][r]*sinv, O[dblk][r+1]*sinv);
        *(unsigned*)(scr + lq*136 + d*2) = u;
      }
  } else {
    // vmix: transpose VM^T[e][q] -> [q][192e] via LDS (pitch 392B)
    const float vinv = 0.25f * sinv;
    char* scr = smem + ATT_GRP + qw*12544;
#pragma unroll
    for (int eblk=0; eblk<6; eblk++)
#pragma unroll
      for (int pp=0; pp<8; pp++){
        const int r = 2*pp;
        const int e = eblk*32 + (r&3) + 8*(r>>2) + 4*hi;
        unsigned u = cvt_pk_bf16(VM[eblk][r]*vinv, VM[eblk][r+1]*vinv);
        *(unsigned*)(scr + lq*392 + e*2) = u;
      }
  }
  __syncthreads();
  if (g == 0){
    const char* scr = smem + qw*12544;
    const int q = lane >> 1, half = lane & 1;
    const char* src = scr + q*136 + half*64;
    char* dst = (char*)(sA + (long)(b*2048 + qb*128 + qw*32 + q)*256 + h*64 + half*32);
#pragma unroll
    for (int i=0;i<8;i++)
      *(unsigned long long*)(dst + i*8) = *(const unsigned long long*)(src + i*8);
  } else {
    const char* scr = smem + ATT_GRP + qw*12544;
    const int q = lane >> 1, half = lane & 1;
    const char* src = scr + q*392 + half*192;
    char* dst = (char*)(slab + (long)h*1572864
                        + (long)(b*2048 + qb*128 + qw*32 + q)*192 + half*96);
#pragma unroll
    for (int i=0;i<24;i++)
      *(unsigned long long*)(dst + i*8) = *(const unsigned long long*)(src + i*8);
  }
}

// ------------------------------------------------------------------
// TILED GEMM 64xBN (BN = 128 or 64): 256 thr = 4 waves side-by-side,
// each 64 rows x BN/4 cols. BK=32 double-buffered LDS. Linear LDS
// layouts are conflict-free (contiguous 1 KB/wave regions).
// OUTM: 0 bf16 store, 1 fp32 store (+ bias/resid in epilogue).
// ------------------------------------------------------------------
template<int ACT, int OUTM, int BN>
__global__ __launch_bounds__(256) void tgemm64_kernel(
    const bf16* __restrict__ A, long lda,
    const bf16* __restrict__ BT, long ldb,
    const float* __restrict__ bias,
    const float* __restrict__ resid,   // fp32, same ld as C
    void* __restrict__ Cv, long ldc,
    int K)
{
  constexpr int NF = BN/64;            // n-frags per wave (2 or 1)
  __shared__ __align__(16) bf16 As[2][64*32];
  __shared__ __align__(16) bf16 Bs[2][BN*32];
  const int tid = threadIdx.x;
  const int wc = tid >> 6, lane = tid & 63;
  const int col = lane & 15, quad = lane >> 4;
  const long rowA0 = (long)blockIdx.y*64;
  const long colB0 = (long)blockIdx.x*BN;

  const int tr = tid >> 2, tc = tid & 3;
  const bf16* Ag = A + (rowA0 + tr)*lda + tc*8;
  const bf16* Bg = BT + (colB0 + tr)*ldb + tc*8;

  short8 sa, sb[NF];
  auto LOAD = [&](int k0){
    sa = *(const short8*)(Ag + k0);
    sb[0] = *(const short8*)(Bg + k0);
    if (NF == 2) sb[NF-1] = *(const short8*)(Bg + (long)64*ldb + k0);
  };
  auto STORE = [&](int buf){
    *(short8*)(&As[buf][tr*32 + tc*8]) = sa;
    *(short8*)(&Bs[buf][tr*32 + tc*8]) = sb[0];
    if (NF == 2) *(short8*)(&Bs[buf][(tr+64)*32 + tc*8]) = sb[NF-1];
  };

  float4v acc[4][NF];
#pragma unroll
  for (int m=0;m<4;m++)
#pragma unroll
    for (int n=0;n<NF;n++) acc[m][n] = (float4v){0.f,0.f,0.f,0.f};

  LOAD(0); STORE(0);
  __syncthreads();
  const int nk = K >> 5;
#pragma unroll 1
  for (int ks=0; ks<nk; ++ks){
    if (ks+1 < nk) LOAD((ks+1)*32);
    const bf16* Ab = &As[ks&1][col*32 + quad*8];
    const bf16* Bb = &Bs[ks&1][(wc*(16*NF) + col)*32 + quad*8];
    short8 af[4], bfv[NF];
#pragma unroll
    for (int m=0;m<4;m++) af[m] = *(const short8*)(Ab + m*16*32);
#pragma unroll
    for (int n=0;n<NF;n++) bfv[n] = *(const short8*)(Bb + n*16*32);
#pragma unroll
    for (int m=0;m<4;m++)
#pragma unroll
      for (int n=0;n<NF;n++)
        acc[m][n] = __builtin_amdgcn_mfma_f32_16x16x32_bf16(af[m], bfv[n], acc[m][n], 0, 0, 0);
    if (ks+1 < nk) STORE((ks+1)&1);
    __syncthreads();
  }

  // epilogue
#pragma unroll
  for (int m=0;m<4;m++){
    const long ci0 = rowA0 + m*16 + quad*4;
#pragma unroll
    for (int n=0;n<NF;n++){
      const long cj = colB0 + wc*(16*NF) + n*16 + col;
      const float bbias = bias ? bias[cj] : 0.f;
#pragma unroll
      for (int r=0;r<4;r++){
        const long ci = ci0 + r;
        float val = acc[m][n][r] + bbias;
        if (ACT == 1) val = 0.5f*val*(1.f + erff(val*0.70710678118654752f));
        if (resid) val += resid[ci*ldc + cj];
        if (OUTM == 0) ((bf16*)Cv)[ci*ldc + cj] = f2b(val);
        else           ((float*)Cv)[ci*ldc + cj] = val;
      }
    }
  }
}

// ------------------------------------------------------------------
// simple MFMA GEMM (small shapes: K=64 / N=64 paths).
// HS=1: A operand is the 4-way head-slab sum (hred folded in).
// ------------------------------------------------------------------
template<int MT, int NT, int ACT, int OUTM, int RXIL, int CXIL, int HS>
__global__ __launch_bounds__(64) void gemm_kernel(
    const bf16* __restrict__ A, long lda, long As1, long As2,
    const bf16* __restrict__ BT, long ldb, long Bs1, long Bs2,
    const float* __restrict__ bias,
    const float* __restrict__ resid, long ldr, long Rs1, long Rs2,
    void* __restrict__ Cv, long ldc, long Cs1, long Cs2,
    int K, int Z2, int KS)
{
  int z = blockIdx.z;
  int zz = z / KS, ks = z - zz*KS;
  int z1 = zz / Z2, z2 = zz - z1*Z2;
  A  += (long)z1*As1 + (long)z2*As2 + (long)ks*K;
  BT += (long)z1*Bs1 + (long)z2*Bs2 + (long)ks*K;
  if (resid) resid += (long)z1*Rs1 + (long)z2*Rs2;
  const long cbase = (long)z1*Cs1 + (long)z2*Cs2;

  const int lane = threadIdx.x;
  const int col = lane & 15, quad = lane >> 4;
  const long rowA0 = (long)blockIdx.y*(16*MT);
  const long colB0 = (long)blockIdx.x*(16*NT);

  float4v acc[MT][NT];
#pragma unroll
  for (int m=0;m<MT;m++)
#pragma unroll
    for (int n=0;n<NT;n++) acc[m][n] = (float4v){0.f,0.f,0.f,0.f};

  const bf16* ap[MT];
  const bf16* bp[NT];
#pragma unroll
  for (int m=0;m<MT;m++) ap[m] = A + (rowA0 + m*16 + col)*lda + quad*8;
#pragma unroll
  for (int n=0;n<NT;n++) bp[n] = BT + (colB0 + n*16 + col)*ldb + quad*8;

  for (int k0 = 0; k0 < K; k0 += 32){
    short8 a[MT], bb[NT];
#pragma unroll
    for (int m=0;m<MT;m++){
      if (HS){
        short8 x0 = *(const short8*)ap[m];
        short8 x1 = *(const short8*)(ap[m] + 1572864);
        short8 x2 = *(const short8*)(ap[m] + 3145728);
        short8 x3 = *(const short8*)(ap[m] + 4718592);
        short8 r;
#pragma unroll
        for (int j=0;j<8;j++){
          float f = bs2f(x0[j]) + bs2f(x1[j]) + bs2f(x2[j]) + bs2f(x3[j]);
          bf16 hb = f2b(f); r[j] = *(short*)&hb;
        }
        a[m] = r;
      } else {
        a[m] = *(const short8*)ap[m];
      }
      ap[m] += 32;
    }
#pragma unroll
    for (int n=0;n<NT;n++){ bb[n] = *(const short8*)bp[n]; bp[n] += 32; }
#pragma unroll
    for (int m=0;m<MT;m++)
#pragma unroll
      for (int n=0;n<NT;n++)
        acc[m][n] = __builtin_amdgcn_mfma_f32_16x16x32_bf16(a[m], bb[n], acc[m][n], 0, 0, 0);
  }

#pragma unroll
  for (int m=0;m<MT;m++){
    const long ri = rowA0 + m*16 + quad*4;
#pragma unroll
    for (int n=0;n<NT;n++){
      const long cj = colB0 + n*16 + col;
      const float bbias = bias ? bias[cj] : 0.f;
#pragma unroll
      for (int r=0;r<4;r++){
        const long ci = ri + r;
        float val = acc[m][n][r] + bbias;
        if (ACT == 1) val = 0.5f*val*(1.f + erff(val*0.70710678118654752f));
        if (resid){
          const long raddr = RXIL ? ((ci/3)*192 + cj*3 + (ci%3)) : (ci*ldr + cj);
          val += resid[raddr];
        }
        const long caddr = CXIL ? (cbase + (ci/3)*192 + cj*3 + (ci%3))
                                : (cbase + ci*ldc + cj);
        if (OUTM == 0)      ((bf16*)Cv)[caddr] = f2b(val);
        else if (OUTM == 1) ((float*)Cv)[caddr] = val;
        else                unsafeAtomicAdd(&((float*)Cv)[caddr], val);
      }
    }
  }
}

// ------------------------------------------------------------------
extern "C" void kernel_launch(void* const* d_in, const int* in_sizes, int n_in,
                              void* d_out, int out_size, void* d_ws, size_t ws_size,
                              hipStream_t stream)
{
  const float* s    = (const float*)d_in[0];
  const float* v    = (const float*)d_in[1];
  const float* pos  = (const float*)d_in[2];
  const float* Wq   = (const float*)d_in[3];
  const float* bq   = (const float*)d_in[4];
  const float* Wk   = (const float*)d_in[5];
  const float* bk   = (const float*)d_in[6];
  const float* Wv   = (const float*)d_in[7];
  const float* bv   = (const float*)d_in[8];
  const float* Wo   = (const float*)d_in[9];
  const float* bo   = (const float*)d_in[10];
  const float* w_d  = (const float*)d_in[11];
  const float* b_d  = (const float*)d_in[12];
  const float* Wvv  = (const float*)d_in[13];
  const float* Wvo  = (const float*)d_in[14];
  const float* g1   = (const float*)d_in[15];
  const float* be1  = (const float*)d_in[16];
  const float* vs1  = (const float*)d_in[17];
  const float* g2   = (const float*)d_in[18];
  const float* be2  = (const float*)d_in[19];
  const float* vs2  = (const float*)d_in[20];
  const float* Wf1  = (const float*)d_in[21];
  const float* bf1  = (const float*)d_in[22];
  const float* Wf2  = (const float*)d_in[23];
  const float* bf2  = (const float*)d_in[24];
  const float* Wfv1 = (const float*)d_in[25];
  const float* Wfv2 = (const float*)d_in[26];

  float* outS = (float*)d_out;
  float* outV = outS + (size_t)4*2048*256;

  char* w = (char*)d_ws;
  size_t o = 0;
  auto alloc = [&](size_t bytes)->char* {
    char* p = w + o;
    o = (o + bytes + 255) & ~(size_t)255;
    return p;
  };
  float* posf  = (float*)alloc(131072);
  bf16* WqkvT = (bf16*)alloc(393216);       // 768 x 256
  bf16* WoT   = (bf16*)alloc(131072);
  bf16* Wf1T  = (bf16*)alloc(524288);
  bf16* Wf2T  = (bf16*)alloc(524288);
  bf16* WvvT  = (bf16*)alloc(8192);
  bf16* WvoT  = (bf16*)alloc(8192);
  bf16* Wfv1T = (bf16*)alloc(32768);
  bf16* Wfv2T = (bf16*)alloc(32768);
  float* bqkv = (float*)alloc(3072);
  float* kmax = (float*)alloc(64);
  bf16* sn    = (bf16*)alloc(4194304);      // reused for sn2
  bf16* qkv   = (bf16*)alloc(12582912);     // 8192 x 768; later alias: hv
  bf16* vsT   = (bf16*)alloc(4194304);
  bf16* sA    = (bf16*)alloc(4194304);
  float* s2   = (float*)alloc(8388608);
  bf16* vnX   = (bf16*)alloc(3145728);      // later alias: vn2X
  bf16* vmixX = (bf16*)alloc(3145728);
  bf16* vmixXT= (bf16*)alloc(3145728);      // (b, 192, 2048)
  float* v2X  = (float*)alloc(6291456);
  bf16* slab  = (bf16*)alloc(12582912);     // 4 x 8192 x 192
  bf16* h1    = (bf16*)alloc(16777216);     // 8192 x 1024
  bf16* vn2X  = vnX;
  bf16* hv    = qkv;                        // qkv dead after attention
  if (o > ws_size) return;

  // --- prep (weights + pos + bias concat in one launch) ---
  WTPack pk;
  pk.d[0] = {Wq,   WqkvT,          256, 256};
  pk.d[1] = {Wk,   WqkvT + 65536,  256, 256};
  pk.d[2] = {Wv,   WqkvT + 131072, 256, 256};
  pk.d[3] = {Wo,   WoT,            256, 256};
  pk.d[4] = {Wf1,  Wf1T,           256, 1024};
  pk.d[5] = {Wf2,  Wf2T,           1024, 256};
  pk.d[6] = {Wvv,  WvvT,           64, 64};
  pk.d[7] = {Wvo,  WvoT,           64, 64};
  pk.d[8] = {Wfv1, Wfv1T,          64, 256};
  pk.d[9] = {Wfv2, Wfv2T,          256, 64};
  wtrans_kernel<<<dim3(32,32,11), 256, 0, stream>>>(pk, pos, posf, bq, bk, bv, bqkv, kmax);

  // --- norm1 (scalar + vector, fused) ---
  lnvn_kernel<1><<<16384, 256, 0, stream>>>(s, g1, be1, sn, v, vs1, vnX);

  // --- vmixX = vnX @ WvvT, then per-b transpose -> vmixXT ---
  gemm_kernel<2,4,0,0,0,0,0><<<dim3(1,768,1), 64, 0, stream>>>(vnX,64,0,0, WvvT,64,0,0,
      nullptr, nullptr,0,0,0, vmixX,64,0,0, 64, 1, 1);
  transpose_kernel<bf16><<<dim3(6,64,4), 256, 0, stream>>>(vmixX, 192, 393216,0,
      vmixXT, 2048, 393216,0, 1);

  // --- fused QKV projection (64x128 tiles) ---
  tgemm64_kernel<0,0,128><<<dim3(6,128), 256, 0, stream>>>(sn,256, WqkvT,256,
      bqkv, nullptr, qkv,768, 256);

  // --- vsT transpose + knorm (fused, both read qkv) ---
  trk_kernel<<<dim3(2,64,17), 256, 0, stream>>>(qkv, vsT, kmax);

  // --- fully fused attention ---
  attn_kernel<<<dim3(16,16), 512, 0, stream>>>(qkv, vsT, vmixXT, posf, kmax,
      w_d, b_d, sA, slab);

  // --- s2 = s + sA@Wo + bo  (64x64 tiles, 512 blocks, fused epilogue) ---
  tgemm64_kernel<0,1,64><<<dim3(4,128), 256, 0, stream>>>(sA,256, WoT,256,
      bo, s, s2,256, 256);

  // --- v2X = v (interleaved resid) + (sum_h slab) @ WvoT  (hred folded) ---
  gemm_kernel<2,4,0,1,1,0,1><<<dim3(1,768,1), 64, 0, stream>>>(slab,64,0,0, WvoT,64,0,0,
      nullptr, v,0,0,0, v2X,64,0,0, 64, 1, 1);

  // --- norm2 (scalar + vector, fused) ---
  lnvn_kernel<2><<<16384, 256, 0, stream>>>(s2, g2, be2, sn, v2X, vs2, vn2X);

  // --- FFN ---
  tgemm64_kernel<1,0,128><<<dim3(8,128), 256, 0, stream>>>(sn,256, Wf1T,256,
      bf1, nullptr, h1,1024, 256);
  tgemm64_kernel<0,1,64><<<dim3(4,128), 256, 0, stream>>>(h1,1024, Wf2T,1024,
      bf2, s2, outS,256, 1024);

  // --- vector FFN ---
  tgemm64_kernel<0,0,64><<<dim3(4,384), 256, 0, stream>>>(vn2X,64, Wfv1T,64,
      nullptr, nullptr, hv,256, 64);
  gemm_kernel<2,4,0,1,0,1,0><<<dim3(1,768,1), 64, 0, stream>>>(hv,256,0,0, Wfv2T,256,0,0,
      nullptr, v2X,64,0,0, outV,0,0,0, 256, 1, 1);
}

// Round 11
// 340.193 us; speedup vs baseline: 3.2308x; 1.0641x over previous
//
#include <hip/hip_runtime.h>
#include <hip/hip_bf16.h>

using bf16 = __hip_bfloat16;
typedef __attribute__((ext_vector_type(8))) short short8;
typedef __attribute__((ext_vector_type(4))) float float4v;
typedef __attribute__((ext_vector_type(16))) float f32x16;
typedef __attribute__((ext_vector_type(4))) unsigned uint4v;

__device__ __forceinline__ float b2f(bf16 x){ return __bfloat162float(x); }
__device__ __forceinline__ bf16  f2b(float x){ return __float2bfloat16(x); }
__device__ __forceinline__ bf16  tob(float x){ return f2b(x); }
__device__ __forceinline__ bf16  tob(bf16 x){ return x; }
__device__ __forceinline__ float frcp(float x){ return __builtin_amdgcn_rcpf(x); }
__device__ __forceinline__ float fexp2(float x){
  float r; asm("v_exp_f32 %0, %1" : "=v"(r) : "v"(x)); return r;
}
__device__ __forceinline__ float bs2f(short s){
  unsigned u = ((unsigned)(unsigned short)s) << 16;
  return __builtin_bit_cast(float, u);
}
__device__ __forceinline__ unsigned cvt_pk_bf16(float lo, float hi){
  unsigned r; asm("v_cvt_pk_bf16_f32 %0, %1, %2" : "=v"(r) : "v"(lo), "v"(hi)); return r;
}
__device__ __forceinline__ void plswap(unsigned &a, unsigned &b){
  asm("v_permlane32_swap_b32 %0, %1" : "+v"(a), "+v"(b));
}

#define EPSV 1e-5f
#define L2E  1.44269504f
#define Z16 {0.f,0.f,0.f,0.f,0.f,0.f,0.f,0.f,0.f,0.f,0.f,0.f,0.f,0.f,0.f,0.f}

// ------------------------------------------------------------------
// all 10 weight transposes (fp32 -> bf16) + pos prep + bias concat
// in ONE launch (z==10 handles pos/bcat/kmax-zero).
// ------------------------------------------------------------------
struct WTDesc { const float* src; bf16* dst; int rows, cols; };
struct WTPack { WTDesc d[10]; };

__global__ __launch_bounds__(256) void wtrans_kernel(WTPack p,
    const float* __restrict__ pos, float* __restrict__ posf,
    const float* __restrict__ bq, const float* __restrict__ bk,
    const float* __restrict__ bv, float* __restrict__ bqkv,
    float* __restrict__ kmax){
  const int t = threadIdx.x;
  if (blockIdx.z == 10){
    if (blockIdx.y == 0 && blockIdx.x < 32){
      int r = blockIdx.x*256 + t;
      float x = pos[3*r], y = pos[3*r+1], z = pos[3*r+2];
      posf[4*r] = x; posf[4*r+1] = y; posf[4*r+2] = z; posf[4*r+3] = x*x + y*y + z*z;
    } else if (blockIdx.y == 1 && blockIdx.x < 3){
      int j = blockIdx.x*256 + t;
      if (blockIdx.x == 0 && t < 16) kmax[t] = 0.f;
      bqkv[j] = (j < 256) ? bq[j] : (j < 512) ? bk[j-256] : bv[j-512];
    }
    return;
  }
  WTDesc w = p.d[blockIdx.z];
  long r0 = (long)blockIdx.y*32, c0 = (long)blockIdx.x*32;
  if (r0 >= w.rows || c0 >= w.cols) return;
  __shared__ bf16 tile[32][33];
  int tx = t & 31, ty = t >> 5;
#pragma unroll
  for (int i = ty; i < 32; i += 8) tile[i][tx] = f2b(w.src[(r0+i)*w.cols + c0 + tx]);
  __syncthreads();
#pragma unroll
  for (int i = ty; i < 32; i += 8) w.dst[(c0+i)*w.rows + r0 + tx] = tile[tx][i];
}

// ------------------------------------------------------------------
// batched 32x32-tiled transpose (+ cast to bf16)
// ------------------------------------------------------------------
template<typename TI>
__global__ __launch_bounds__(256) void transpose_kernel(
    const TI* __restrict__ in, long ldin, long is1, long is2,
    bf16* __restrict__ out, long ldout, long os1, long os2, int Z2)
{
  int z = blockIdx.z, z1 = z / Z2, z2 = z - z1*Z2;
  in  += (long)z1*is1 + (long)z2*is2;
  out += (long)z1*os1 + (long)z2*os2;
  __shared__ bf16 tile[32][33];
  int tx = threadIdx.x & 31, ty = threadIdx.x >> 5;
  long r0 = (long)blockIdx.y*32, c0 = (long)blockIdx.x*32;
#pragma unroll
  for (int i = ty; i < 32; i += 8) tile[i][tx] = tob(in[(r0+i)*ldin + c0 + tx]);
  __syncthreads();
#pragma unroll
  for (int i = ty; i < 32; i += 8) out[(c0+i)*ldout + r0 + tx] = tile[tx][i];
}

// ------------------------------------------------------------------
// fused vsT transpose (z<16) + knorm (z==16): both consume qkv.
// ------------------------------------------------------------------
__global__ __launch_bounds__(256) void trk_kernel(const bf16* __restrict__ qkv,
                                                  bf16* __restrict__ vsT,
                                                  float* __restrict__ kmax){
  const int t = threadIdx.x;
  if (blockIdx.z < 16){
    int z = blockIdx.z, z1 = z >> 2, z2 = z & 3;   // b, h
    const bf16* in = qkv + 512 + (long)z1*1572864 + (long)z2*64;
    bf16* out = vsT + (long)z1*524288 + (long)z2*131072;
    __shared__ bf16 tile[32][33];
    int tx = t & 31, ty = t >> 5;
    long r0 = (long)blockIdx.y*32, c0 = (long)blockIdx.x*32;
#pragma unroll
    for (int i = ty; i < 32; i += 8) tile[i][tx] = in[(r0+i)*768 + c0 + tx];
    __syncthreads();
#pragma unroll
    for (int i = ty; i < 32; i += 8) out[(c0+i)*2048 + r0 + tx] = tile[tx][i];
  } else {
    const int idx = blockIdx.y*2 + blockIdx.x;     // 0..127
    const int bh = idx >> 3, chunk = idx & 7;
    const int b = bh >> 2, h = bh & 3;
    const int lane = t & 63, wv = t >> 6;
    __shared__ float red[4];
    long row = (long)b*2048 + (long)chunk*256 + t;
    const short8* kp = (const short8*)(qkv + row*768 + 256 + h*64);
    float ss = 0.f;
#pragma unroll
    for (int c=0;c<8;c++){
      short8 v = kp[c];
#pragma unroll
      for (int j=0;j<8;j++){ float f = bs2f(v[j]); ss = fmaf(f,f,ss); }
    }
#pragma unroll
    for (int off=32; off; off>>=1) ss = fmaxf(ss, __shfl_xor(ss, off));
    if (lane == 0) red[wv] = ss;
    __syncthreads();
    if (t == 0){
      float m = fmaxf(fmaxf(red[0],red[1]), fmaxf(red[2],red[3]));
      atomicMax((unsigned*)&kmax[bh], __float_as_uint(m));
    }
  }
}

// ------------------------------------------------------------------
// fused LayerNorm + eq-norm: block r does LN on row r AND eq-norm on
// row r (one launch, 8192 blocks).
// VN=1: v (b,n,c,x) -> vnX[(b,n,x),c]; VN=2: [x*64+c] -> same layout.
// ------------------------------------------------------------------
template<int VN>
__global__ __launch_bounds__(256) void lnvn_kernel(
    const float* __restrict__ x, const float* __restrict__ g,
    const float* __restrict__ be, bf16* __restrict__ outln,
    const float* __restrict__ vin, const float* __restrict__ vs,
    bf16* __restrict__ outvn)
{
  const int t = threadIdx.x;
  const long row = blockIdx.x;
  const int lane = t & 63, wv = t >> 6;
  __shared__ float ws1[4], ws2[4];
  __shared__ float vv[192], nrm[64];
  __shared__ float smean;
  // load both inputs up-front (independent streams)
  float v = x[(row<<8) + t];
  if (t < 192) vv[t] = vin[row*192 + t];
  // LN reduce
  float s1 = v, s2 = v*v;
#pragma unroll
  for (int off=32; off; off>>=1){
    s1 += __shfl_xor(s1, off);
    s2 += __shfl_xor(s2, off);
  }
  if (lane == 0){ ws1[wv] = s1; ws2[wv] = s2; }
  __syncthreads();
  const float r1 = ws1[0]+ws1[1]+ws1[2]+ws1[3];
  const float r2 = ws2[0]+ws2[1]+ws2[2]+ws2[3];
  const float mu = r1 * (1.f/256.f);
  const float var = r2 * (1.f/256.f) - mu*mu;
  const float rstd = rsqrtf(fmaxf(var, 0.f) + EPSV);
  outln[(row<<8)+t] = f2b((v-mu)*rstd*g[t] + be[t]);
  // VN (vv already loaded & visible after the sync above)
  if (t < 64){
    float a, b, c;
    if (VN == 1){ a = vv[3*t]; b = vv[3*t+1]; c = vv[3*t+2]; }
    else        { a = vv[t]; b = vv[t+64]; c = vv[t+128]; }
    float nv = sqrtf(a*a + b*b + c*c);
    nrm[t] = nv;
    float s = nv;
#pragma unroll
    for (int off=32; off; off>>=1) s += __shfl_xor(s, off);
    if (t == 0) smean = s*(1.f/64.f);
  }
  __syncthreads();
  if (t < 192){
    if (VN == 1){
      const int c = t/3, xx = t - 3*c;
      outvn[row*192 + xx*64 + c] = f2b(vv[t] / (nrm[c] + EPSV) * smean * vs[c]);
    } else {
      const int c = t & 63;
      outvn[row*192 + t] = f2b(vv[t] / (nrm[c] + EPSV) * smean * vs[c]);
    }
  }
}

// ------------------------------------------------------------------
// FUSED ATTENTION, 8-wave m-split (2 groups x 4 q-waves, 2 waves/SIMD):
//   round-5 benched structure (116.7 us) + exp2 prescale. Occupancy is
//   register-pinned: 128 VGPR + 128 AGPR acc = 256/wave = 2/SIMD hard
//   cap. DO NOT raise occupancy (rounds 4 & 6 spilled, ~8x slower).
// ------------------------------------------------------------------
#define ATT_K_OFF   0
#define ATT_V_OFF   4096
#define ATT_X_OFF   9216
#define ATT_P_OFF   24576
#define ATT_TILE    25088
#define ATT_GRP     50176          // 2 dbuf per group
#define ATT_LACC    98304          // 8*64 floats = 2048 B
#define ATT_SMEM    100352

__global__ __launch_bounds__(512, 2) void attn_kernel(
    const bf16* __restrict__ qkv,    // [8192][768] (Q|K|V, 4 heads x 64)
    const bf16* __restrict__ vsT,    // [b][h][64][2048]
    const bf16* __restrict__ vmixT,  // [b][192][2048]
    const float* __restrict__ posf,  // [b][2048][4]
    const float* __restrict__ kmaxA, // [16] max ||k||^2
    const float* __restrict__ w_dist, const float* __restrict__ b_dist,
    bf16* __restrict__ sA,           // [8192][256]
    bf16* __restrict__ slab)         // [4][8192][192]
{
  __shared__ __align__(16) char smem[ATT_SMEM];
  const int qb = blockIdx.x;         // 0..15
  const int bh = blockIdx.y;         // 0..15
  const int b  = bh >> 2, h = bh & 3;
  const int tid = threadIdx.x;
  const int w = tid >> 6, lane = tid & 63;
  const int g = w >> 2, qw = w & 3;
  const int lq = lane & 31, hi = lane >> 5;
  const int gtid = tid & 255;

  const int qloc = qb*128 + qw*32 + lq;
  const long rowQ = (long)b*2048 + qloc;

  // Q fragments (B operand): col=q (lane&31), k=d = kc*16 + hi*8 + j
  short8 qf[4];
  {
    const bf16* qp = qkv + rowQ*768 + h*64 + hi*8;
#pragma unroll
    for (int kc=0;kc<4;kc++) qf[kc] = *(const short8*)(qp + kc*16);
  }
  // stabilizer (exp2 domain)
  float q2 = 0.f;
#pragma unroll
  for (int kc=0;kc<4;kc++)
#pragma unroll
    for (int j=0;j<8;j++){ float qv = bs2f(qf[kc][j]); q2 = fmaf(qv,qv,q2); }
  q2 += __shfl_xor(q2, 32);
  const float mxs2 = sqrtf(q2 * kmaxA[bh]) * (0.125f * L2E);
  const float wh2 = w_dist[h] * L2E, bhd2 = b_dist[h] * L2E;
  const float4v pn = *(const float4v*)(posf + (long)b*8192 + (long)qloc*4);
  const float m2x = -2.f*pn[0], m2y = -2.f*pn[1], m2z = -2.f*pn[2], pnw = pn[3];

  f32x16 O[2]  = {Z16, Z16};
  f32x16 VM[6] = {Z16, Z16, Z16, Z16, Z16, Z16};
  float lacc = 0.f;

  // per-group staging (256 threads, 20.5 KB/tile)
  short8 stK, stV, stX0, stX1, stX2; float4v stP;
  const int sm = gtid >> 3, sc = gtid & 7;   // K: row(32) x chunk(8)
  const int vd = gtid >> 2, vc = gtid & 3;   // V/X: row x chunk(4)
  const bf16* Kg = qkv + (long)b*2048*768 + 256 + h*64;
  const bf16* Vg = vsT + (long)b*524288 + (long)h*131072;
  const bf16* Xg = vmixT + (long)b*393216;
  const float* Pg = posf + (long)b*8192;
  char* gbase = smem + g*ATT_GRP;

  auto LOADT = [&](int m0){
    stK  = *(const short8*)(Kg + (long)(m0+sm)*768 + sc*8);
    stV  = *(const short8*)(Vg + (long)vd*2048 + m0 + vc*8);
    stX0 = *(const short8*)(Xg + (long)vd*2048 + m0 + vc*8);
    stX1 = *(const short8*)(Xg + (long)(64+vd)*2048 + m0 + vc*8);
    stX2 = *(const short8*)(Xg + (long)(128+vd)*2048 + m0 + vc*8);
    if (gtid < 32) stP = *(const float4v*)(Pg + (long)(m0+gtid)*4);
  };
  auto WRITET = [&](char* buf){
    *(short8*)(buf + ATT_K_OFF + sm*128 + ((sc ^ (sm&7))<<4)) = stK;   // XOR-swizzle
    *(short8*)(buf + ATT_V_OFF + vd*80 + vc*16) = stV;
    *(short8*)(buf + ATT_X_OFF + vd*80 + vc*16) = stX0;
    *(short8*)(buf + ATT_X_OFF + (64+vd)*80 + vc*16) = stX1;
    *(short8*)(buf + ATT_X_OFF + (128+vd)*80 + vc*16) = stX2;
    if (gtid < 32) *(float4v*)(buf + ATT_P_OFF + gtid*16) = stP;
  };

  auto COMPUTE = [&](const char* buf){
    const char* Kb = buf + ATT_K_OFF;
    const char* Vb = buf + ATT_V_OFF;
    const char* Xb = buf + ATT_X_OFF;
    const float4v* pmb = (const float4v*)(buf + ATT_P_OFF);
    // swapped QK^T: S[m][q], col = lane&31 = q
    f32x16 S = Z16;
#pragma unroll
    for (int kc=0;kc<4;kc++){
      short8 kf = *(const short8*)(Kb + lq*128 + (((kc*2+hi) ^ (lq&7))<<4));
      S = __builtin_amdgcn_mfma_f32_32x32x16_bf16(kf, qf[kc], S, 0, 0, 0);
    }
    // dist bias + exp2 (unnormalized, fixed stabilizer); m = i + 8gg + 4hi
    float P[16];
#pragma unroll
    for (int gg=0; gg<4; gg++){
#pragma unroll
      for (int i=0;i<4;i++){
        float4v pm = pmb[gg*8 + hi*4 + i];
        float d2 = fmaf(m2x, pm[0], fmaf(m2y, pm[1], fmaf(m2z, pm[2], pnw + pm[3])));
        float dist = sqrtf(fmaxf(d2, 1e-12f));
        float sig = frcp(1.f + fexp2(fmaf(dist, wh2, bhd2)));
        float p = fexp2(fmaf(S[gg*4+i], 0.125f*L2E, -mxs2)) * sig;
        lacc += p;
        P[gg*4+i] = p;
      }
    }
    // P -> bf16 B-operand (col=q, k=m) via cvt_pk + permlane32_swap
    unsigned pk[8];
#pragma unroll
    for (int t=0;t<8;t++) pk[t] = cvt_pk_bf16(P[2*t], P[2*t+1]);
    plswap(pk[0], pk[2]); plswap(pk[1], pk[3]);   // chunk0: m 0..15
    plswap(pk[4], pk[6]); plswap(pk[5], pk[7]);   // chunk1: m 16..31
    uint4v y0v = {pk[0], pk[1], pk[2], pk[3]};
    uint4v y1v = {pk[4], pk[5], pk[6], pk[7]};
    short8 Y0 = __builtin_bit_cast(short8, y0v);
    short8 Y1 = __builtin_bit_cast(short8, y1v);
    // PV: O^T[d][q] += V^T[d][m] * P[q][m]
#pragma unroll
    for (int dblk=0; dblk<2; dblk++){
      short8 v0 = *(const short8*)(Vb + (dblk*32+lq)*80 + hi*16);
      short8 v1 = *(const short8*)(Vb + (dblk*32+lq)*80 + 32 + hi*16);
      O[dblk] = __builtin_amdgcn_mfma_f32_32x32x16_bf16(v0, Y0, O[dblk], 0,0,0);
      O[dblk] = __builtin_amdgcn_mfma_f32_32x32x16_bf16(v1, Y1, O[dblk], 0,0,0);
    }
    // vmix: VM^T[e][q] += vmix^T[e][m] * P[q][m]
#pragma unroll
    for (int eblk=0; eblk<6; eblk++){
      short8 x0 = *(const short8*)(Xb + (eblk*32+lq)*80 + hi*16);
      short8 x1 = *(const short8*)(Xb + (eblk*32+lq)*80 + 32 + hi*16);
      VM[eblk] = __builtin_amdgcn_mfma_f32_32x32x16_bf16(x0, Y0, VM[eblk], 0,0,0);
      VM[eblk] = __builtin_amdgcn_mfma_f32_32x32x16_bf16(x1, Y1, VM[eblk], 0,0,0);
    }
  };

  // group g computes tiles g, g+2, ..., g+62 (32 tiles each)
  LOADT(g*32);
  WRITET(gbase);
  __syncthreads();
#pragma unroll 1
  for (int i=0; i<32; ++i){
    if (i < 31) LOADT((2*(i+1)+g)*32);
    COMPUTE(gbase + (i&1)*ATT_TILE);
    if (i < 31) WRITET(gbase + ((i+1)&1)*ATT_TILE);
    __syncthreads();
  }

  // ---------------- cross-group combine (odd strides: conflict-free) ----------------
  float* laccT = (float*)(smem + ATT_LACC);
  laccT[w*64 + lane] = lacc;
  if (g == 1){                       // group 1 exports O (stride 33 floats)
    float* Od = (float*)(smem + ATT_GRP) + (qw*64+lane)*33;
#pragma unroll
    for (int r=0;r<16;r++){ Od[r] = O[0][r]; Od[16+r] = O[1][r]; }
  }
  __syncthreads();
  const float lsum = laccT[qw*64+lq] + laccT[qw*64+32+lq]
                   + laccT[(4+qw)*64+lq] + laccT[(4+qw)*64+32+lq];
  if (g == 0){                       // group 0 accumulates full O
    const float* Od = (const float*)(smem + ATT_GRP) + (qw*64+lane)*33;
#pragma unroll
    for (int r=0;r<16;r++){ O[0][r] += Od[r]; O[1][r] += Od[16+r]; }
  }
  __syncthreads();
  // VM in two halves (stride 49 floats; each half fits the 50176 B group-0 area)
#pragma unroll
  for (int hf=0; hf<2; hf++){
    if (g == 0){                     // group 0 exports VM half
      float* Vd = (float*)smem + (qw*64+lane)*49;
#pragma unroll
      for (int e=0;e<3;e++)
#pragma unroll
        for (int r=0;r<16;r++) Vd[e*16+r] = VM[hf*3+e][r];
    }
    __syncthreads();
    if (g == 1){                     // group 1 accumulates full VM
      const float* Vd = (const float*)smem + (qw*64+lane)*49;
#pragma unroll
      for (int e=0;e<3;e++)
#pragma unroll
        for (int r=0;r<16;r++) VM[hf*3+e][r] += Vd[e*16+r];
    }
    __syncthreads();
  }

  // ---------------- parallel epilogue ----------------
  const float sinv = frcp(lsum);
  if (g == 0){
    // s_attn: transpose O^T[d][q] -> [q][64d] via LDS (pitch 136B)
    char* scr = smem + qw*12544;
#pragma unroll
    for (int dblk=0; dblk<2; dblk++)
#pragma unroll
      for (int pp=0; pp<8; pp++){
        const int r = 2*pp;
        const int d = dblk*32 + (r&3) + 8*(r>>2) + 4*hi;
        unsigned u = cvt_pk_bf16(O[dblk][r]*sinv, O[dblk][r+1]*sinv);
        *(unsigned*)(scr + lq*136 + d*2) = u;
      }
  } else {
    // vmix: transpose VM^T[e][q] -> [q][192e] via LDS (pitch 392B)
    const float vinv = 0.25f * sinv;
    char* scr = smem + ATT_GRP + qw*12544;
#pragma unroll
    for (int eblk=0; eblk<6; eblk++)
#pragma unroll
      for (int pp=0; pp<8; pp++){
        const int r = 2*pp;
        const int e = eblk*32 + (r&3) + 8*(r>>2) + 4*hi;
        unsigned u = cvt_pk_bf16(VM[eblk][r]*vinv, VM[eblk][r+1]*vinv);
        *(unsigned*)(scr + lq*392 + e*2) = u;
      }
  }
  __syncthreads();
  if (g == 0){
    const char* scr = smem + qw*12544;
    const int q = lane >> 1, half = lane & 1;
    const char* src = scr + q*136 + half*64;
    char* dst = (char*)(sA + (long)(b*2048 + qb*128 + qw*32 + q)*256 + h*64 + half*32);
#pragma unroll
    for (int i=0;i<8;i++)
      *(unsigned long long*)(dst + i*8) = *(const unsigned long long*)(src + i*8);
  } else {
    const char* scr = smem + ATT_GRP + qw*12544;
    const int q = lane >> 1, half = lane & 1;
    const char* src = scr + q*392 + half*192;
    char* dst = (char*)(slab + (long)h*1572864
                        + (long)(b*2048 + qb*128 + qw*32 + q)*192 + half*96);
#pragma unroll
    for (int i=0;i<24;i++)
      *(unsigned long long*)(dst + i*8) = *(const unsigned long long*)(src + i*8);
  }
}

// ------------------------------------------------------------------
// TILED GEMM 64xBN (BN = 128 or 64): 256 thr = 4 waves side-by-side.
// BK=32 double-buffered LDS, linear conflict-free layouts.
// HS=1: A-load sums the 4 head slabs (fp32) -> bf16 (hred fold).
// RXIL/CXIL: x-interleaved resid read / C store for (b,n,c,x) tensors:
//   addr = (ci/3)*192 + cj*3 + ci%3.
// OUTM: 0 bf16 store, 1 fp32 store.
// ------------------------------------------------------------------
template<int ACT, int OUTM, int BN, int HS, int RXIL, int CXIL>
__global__ __launch_bounds__(256) void tgemm64_kernel(
    const bf16* __restrict__ A, long lda,
    const bf16* __restrict__ BT, long ldb,
    const float* __restrict__ bias,
    const float* __restrict__ resid,
    void* __restrict__ Cv, long ldc,
    int K)
{
  constexpr int NF = BN/64;            // n-frags per wave (2 or 1)
  __shared__ __align__(16) bf16 As[2][64*32];
  __shared__ __align__(16) bf16 Bs[2][BN*32];
  const int tid = threadIdx.x;
  const int wc = tid >> 6, lane = tid & 63;
  const int col = lane & 15, quad = lane >> 4;
  const long rowA0 = (long)blockIdx.y*64;
  const long colB0 = (long)blockIdx.x*BN;

  const int tr = tid >> 2, tc = tid & 3;
  const bf16* Ag = A + (rowA0 + tr)*lda + tc*8;
  const bf16* Bg = BT + (colB0 + tr)*ldb + tc*8;

  short8 sa, sb[NF];
  auto LOAD = [&](int k0){
    if (HS){
      const bf16* a0 = Ag + k0;
      short8 x0 = *(const short8*)a0;
      short8 x1 = *(const short8*)(a0 + 1572864);
      short8 x2 = *(const short8*)(a0 + 3145728);
      short8 x3 = *(const short8*)(a0 + 4718592);
      short8 r;
#pragma unroll
      for (int j=0;j<8;j++){
        float f = bs2f(x0[j]) + bs2f(x1[j]) + bs2f(x2[j]) + bs2f(x3[j]);
        bf16 hb = f2b(f); r[j] = *(short*)&hb;
      }
      sa = r;
    } else {
      sa = *(const short8*)(Ag + k0);
    }
    sb[0] = *(const short8*)(Bg + k0);
    if (NF == 2) sb[NF-1] = *(const short8*)(Bg + (long)64*ldb + k0);
  };
  auto STORE = [&](int buf){
    *(short8*)(&As[buf][tr*32 + tc*8]) = sa;
    *(short8*)(&Bs[buf][tr*32 + tc*8]) = sb[0];
    if (NF == 2) *(short8*)(&Bs[buf][(tr+64)*32 + tc*8]) = sb[NF-1];
  };

  float4v acc[4][NF];
#pragma unroll
  for (int m=0;m<4;m++)
#pragma unroll
    for (int n=0;n<NF;n++) acc[m][n] = (float4v){0.f,0.f,0.f,0.f};

  LOAD(0); STORE(0);
  __syncthreads();
  const int nk = K >> 5;
#pragma unroll 1
  for (int ks=0; ks<nk; ++ks){
    if (ks+1 < nk) LOAD((ks+1)*32);
    const bf16* Ab = &As[ks&1][col*32 + quad*8];
    const bf16* Bb = &Bs[ks&1][(wc*(16*NF) + col)*32 + quad*8];
    short8 af[4], bfv[NF];
#pragma unroll
    for (int m=0;m<4;m++) af[m] = *(const short8*)(Ab + m*16*32);
#pragma unroll
    for (int n=0;n<NF;n++) bfv[n] = *(const short8*)(Bb + n*16*32);
#pragma unroll
    for (int m=0;m<4;m++)
#pragma unroll
      for (int n=0;n<NF;n++)
        acc[m][n] = __builtin_amdgcn_mfma_f32_16x16x32_bf16(af[m], bfv[n], acc[m][n], 0, 0, 0);
    if (ks+1 < nk) STORE((ks+1)&1);
    __syncthreads();
  }

  // epilogue
#pragma unroll
  for (int m=0;m<4;m++){
    const long ci0 = rowA0 + m*16 + quad*4;
#pragma unroll
    for (int n=0;n<NF;n++){
      const long cj = colB0 + wc*(16*NF) + n*16 + col;
      const float bbias = bias ? bias[cj] : 0.f;
#pragma unroll
      for (int r=0;r<4;r++){
        const long ci = ci0 + r;
        float val = acc[m][n][r] + bbias;
        if (ACT == 1) val = 0.5f*val*(1.f + erff(val*0.70710678118654752f));
        if (resid){
          const long raddr = RXIL ? ((ci/3)*192 + cj*3 + (ci%3)) : (ci*ldc + cj);
          val += resid[raddr];
        }
        const long caddr = CXIL ? ((ci/3)*192 + cj*3 + (ci%3)) : (ci*ldc + cj);
        if (OUTM == 0) ((bf16*)Cv)[caddr] = f2b(val);
        else           ((float*)Cv)[caddr] = val;
      }
    }
  }
}

// ------------------------------------------------------------------
extern "C" void kernel_launch(void* const* d_in, const int* in_sizes, int n_in,
                              void* d_out, int out_size, void* d_ws, size_t ws_size,
                              hipStream_t stream)
{
  const float* s    = (const float*)d_in[0];
  const float* v    = (const float*)d_in[1];
  const float* pos  = (const float*)d_in[2];
  const float* Wq   = (const float*)d_in[3];
  const float* bq   = (const float*)d_in[4];
  const float* Wk   = (const float*)d_in[5];
  const float* bk   = (const float*)d_in[6];
  const float* Wv   = (const float*)d_in[7];
  const float* bv   = (const float*)d_in[8];
  const float* Wo   = (const float*)d_in[9];
  const float* bo   = (const float*)d_in[10];
  const float* w_d  = (const float*)d_in[11];
  const float* b_d  = (const float*)d_in[12];
  const float* Wvv  = (const float*)d_in[13];
  const float* Wvo  = (const float*)d_in[14];
  const float* g1   = (const float*)d_in[15];
  const float* be1  = (const float*)d_in[16];
  const float* vs1  = (const float*)d_in[17];
  const float* g2   = (const float*)d_in[18];
  const float* be2  = (const float*)d_in[19];
  const float* vs2  = (const float*)d_in[20];
  const float* Wf1  = (const float*)d_in[21];
  const float* bf1  = (const float*)d_in[22];
  const float* Wf2  = (const float*)d_in[23];
  const float* bf2  = (const float*)d_in[24];
  const float* Wfv1 = (const float*)d_in[25];
  const float* Wfv2 = (const float*)d_in[26];

  float* outS = (float*)d_out;
  float* outV = outS + (size_t)4*2048*256;

  char* w = (char*)d_ws;
  size_t o = 0;
  auto alloc = [&](size_t bytes)->char* {
    char* p = w + o;
    o = (o + bytes + 255) & ~(size_t)255;
    return p;
  };
  float* posf  = (float*)alloc(131072);
  bf16* WqkvT = (bf16*)alloc(393216);       // 768 x 256
  bf16* WoT   = (bf16*)alloc(131072);
  bf16* Wf1T  = (bf16*)alloc(524288);
  bf16* Wf2T  = (bf16*)alloc(524288);
  bf16* WvvT  = (bf16*)alloc(8192);
  bf16* WvoT  = (bf16*)alloc(8192);
  bf16* Wfv1T = (bf16*)alloc(32768);
  bf16* Wfv2T = (bf16*)alloc(32768);
  float* bqkv = (float*)alloc(3072);
  float* kmax = (float*)alloc(64);
  bf16* sn    = (bf16*)alloc(4194304);      // reused for sn2
  bf16* qkv   = (bf16*)alloc(12582912);     // 8192 x 768; later alias: hv
  bf16* vsT   = (bf16*)alloc(4194304);
  bf16* sA    = (bf16*)alloc(4194304);
  float* s2   = (float*)alloc(8388608);
  bf16* vnX   = (bf16*)alloc(3145728);      // later alias: vn2X
  bf16* vmixX = (bf16*)alloc(3145728);
  bf16* vmixXT= (bf16*)alloc(3145728);      // (b, 192, 2048)
  float* v2X  = (float*)alloc(6291456);
  bf16* slab  = (bf16*)alloc(12582912);     // 4 x 8192 x 192
  bf16* h1    = (bf16*)alloc(16777216);     // 8192 x 1024
  bf16* vn2X  = vnX;
  bf16* hv    = qkv;                        // qkv dead after attention
  if (o > ws_size) return;

  // --- prep (weights + pos + bias concat in one launch) ---
  WTPack pk;
  pk.d[0] = {Wq,   WqkvT,          256, 256};
  pk.d[1] = {Wk,   WqkvT + 65536,  256, 256};
  pk.d[2] = {Wv,   WqkvT + 131072, 256, 256};
  pk.d[3] = {Wo,   WoT,            256, 256};
  pk.d[4] = {Wf1,  Wf1T,           256, 1024};
  pk.d[5] = {Wf2,  Wf2T,           1024, 256};
  pk.d[6] = {Wvv,  WvvT,           64, 64};
  pk.d[7] = {Wvo,  WvoT,           64, 64};
  pk.d[8] = {Wfv1, Wfv1T,          64, 256};
  pk.d[9] = {Wfv2, Wfv2T,          256, 64};
  wtrans_kernel<<<dim3(32,32,11), 256, 0, stream>>>(pk, pos, posf, bq, bk, bv, bqkv, kmax);

  // --- norm1 (scalar + vector, one block per row pair) ---
  lnvn_kernel<1><<<8192, 256, 0, stream>>>(s, g1, be1, sn, v, vs1, vnX);

  // --- vmixX = vnX @ WvvT (4-wave tiles), then per-b transpose -> vmixXT ---
  tgemm64_kernel<0,0,64,0,0,0><<<dim3(1,384), 256, 0, stream>>>(vnX,64, WvvT,64,
      nullptr, nullptr, vmixX,64, 64);
  transpose_kernel<bf16><<<dim3(6,64,4), 256, 0, stream>>>(vmixX, 192, 393216,0,
      vmixXT, 2048, 393216,0, 1);

  // --- fused QKV projection (64x128 tiles) ---
  tgemm64_kernel<0,0,128,0,0,0><<<dim3(6,128), 256, 0, stream>>>(sn,256, WqkvT,256,
      bqkv, nullptr, qkv,768, 256);

  // --- vsT transpose + knorm (fused, both read qkv) ---
  trk_kernel<<<dim3(2,64,17), 256, 0, stream>>>(qkv, vsT, kmax);

  // --- fully fused attention ---
  attn_kernel<<<dim3(16,16), 512, 0, stream>>>(qkv, vsT, vmixXT, posf, kmax,
      w_d, b_d, sA, slab);

  // --- s2 = s + sA@Wo + bo  (64x64 tiles, 512 blocks, fused epilogue) ---
  tgemm64_kernel<0,1,64,0,0,0><<<dim3(4,128), 256, 0, stream>>>(sA,256, WoT,256,
      bo, s, s2,256, 256);

  // --- v2X = v (interleaved resid) + (sum_h slab) @ WvoT  (hred folded, 4-wave) ---
  tgemm64_kernel<0,1,64,1,1,0><<<dim3(1,384), 256, 0, stream>>>(slab,64, WvoT,64,
      nullptr, v, v2X,64, 64);

  // --- norm2 (scalar + vector) ---
  lnvn_kernel<2><<<8192, 256, 0, stream>>>(s2, g2, be2, sn, v2X, vs2, vn2X);

  // --- FFN ---
  tgemm64_kernel<1,0,128,0,0,0><<<dim3(8,128), 256, 0, stream>>>(sn,256, Wf1T,256,
      bf1, nullptr, h1,1024, 256);
  tgemm64_kernel<0,1,64,0,0,0><<<dim3(4,128), 256, 0, stream>>>(h1,1024, Wf2T,1024,
      bf2, s2, outS,256, 1024);

  // --- vector FFN ---
  tgemm64_kernel<0,0,64,0,0,0><<<dim3(4,384), 256, 0, stream>>>(vn2X,64, Wfv1T,64,
      nullptr, nullptr, hv,256, 64);
  tgemm64_kernel<0,1,64,0,0,1><<<dim3(1,384), 256, 0, stream>>>(hv,256, Wfv2T,256,
      nullptr, v2X, outV,64, 256);
}